// Round 4
// baseline (358.401 us; speedup 1.0000x reference)
//
#include <hip/hip_runtime.h>
#include <hip/hip_bf16.h>
#include <stdint.h>

#define B_ 128
#define N_ 512
#define S_ 8
#define H_ 64
#define M_ (B_*N_)          // 65536 rows
#define L2E 1.442695041f

typedef __attribute__((ext_vector_type(8))) short bf16x8;
typedef __attribute__((ext_vector_type(4))) float f32x4;

__device__ __forceinline__ float exp2f_(float x) { return __builtin_amdgcn_exp2f(x); }
__device__ __forceinline__ float rcpf_(float x)  { return __builtin_amdgcn_rcpf(x); }
// x pre-scaled by log2(e):  sig2(x) == sigmoid(x / L2E)   (v_exp + v_rcp only)
__device__ __forceinline__ float sig2(float x)  { return rcpf_(1.f + exp2f_(-x)); }
// x pre-scaled by 2*log2(e): tanh2(x) == tanh(x / (2*L2E))
__device__ __forceinline__ float tanh2(float x) { return 1.f - 2.f*rcpf_(exp2f_(x) + 1.f); }
__device__ __forceinline__ float dot4(float4 a, float4 b) {
  return a.x*b.x + a.y*b.y + a.z*b.z + a.w*b.w;
}
// fp32 -> bf16 round-to-nearest-even
__device__ __forceinline__ unsigned short f2bf(float x) {
  unsigned int u = __float_as_uint(x);
  u += 0x7fffu + ((u >> 16) & 1u);
  return (unsigned short)(u >> 16);
}

// ---------------------------------------------------------------------------
// MFMA LSTM v6: occupancy-targeted restructure of v5b.
//  - 512 threads = 8 waves; 128 rows/block (16 rows/wave); grid = 512 = 2/CU.
//  - __launch_bounds__(512,4): VGPR cap 128 -> 4 waves/SIMD (was 3 @160).
//  - Gate tiles processed in 4 column-groups {cc, cc+4, cc+8, cc+12} so only
//    4 f32x4 accumulators are live at a time (was 16 -> 64 VGPRs).
//    sched_barrier(0) between groups pins register lifetime.
//  - x pre-packed to bf16 pairs in LDS once (x_pk[t][row]), conflict-free;
//    per-lane load/kill logic (no divergent tid<64 section).
//  - Same math/layout as v5b otherwise: compact Wxc (all lanes read an
//    initialized entry; non-quad0 lanes zero the fragment by cndmask on the
//    VALUE), h bf16 in LDS stride 72, single barrier, rcp-based sig/tanh.
__global__ __launch_bounds__(512, 4) void lstm_kernel(
    const float* __restrict__ obs, const float* __restrict__ nhm,
    const float* __restrict__ Wih, const float* __restrict__ Whh,
    const float* __restrict__ bih, const float* __restrict__ bhh,
    unsigned short* __restrict__ he)
{
  __shared__ short    Wfrag[32*512];   // 32 KB  Whh B-frags (bf16, gate-scaled)
  __shared__ short    Wxc[1024];       // 2 KB   compact [Wih0,Wih1,bias,0] per n
  __shared__ short    h_s[128*72];     // 18 KB  bf16, stride 72
  __shared__ uint32_t x_pk[8][128];    // 4 KB   packed bf16 (x0,x1) per (t,row)
  __shared__ int      len_s[128];      // 0.5 KB

  const int tid  = threadIdx.x;
  const int lane = tid & 63;
  const int wv   = tid >> 6;           // 0..7
  const int w16  = wv * 16;
  const int quad = lane >> 4;
  const int col  = lane & 15;
  const int row0 = blockIdx.x * 128;

  // ---- stage Whh as bf16 B-fragments (gate-scaled), 2048 (frag,lane) entries
  #pragma unroll
  for (int i = 0; i < 4; ++i) {
    int p = i*512 + tid;
    int f = p >> 6, l = p & 63;
    int t16 = f >> 1, s = f & 1;
    int lq = l >> 4, lc = l & 15;
    const float sc = (t16 >= 8 && t16 < 12) ? (2.f*L2E) : L2E;
    const float* src = Whh + (size_t)(t16*16 + lc)*64 + s*32 + lq*8;
    short* dst = Wfrag + f*512 + l*8;
    #pragma unroll
    for (int j = 0; j < 8; ++j) dst[j] = (short)f2bf(src[j] * sc);
  }
  // ---- stage compact Wx: Wxc[t16*64 + cc*4 + k], k: 0=Wih0 1=Wih1 2=bias ----
  if (tid < 256) {
    int t16 = tid >> 4, cc = tid & 15;
    int n = t16*16 + cc;
    const float sc = (t16 >= 8 && t16 < 12) ? (2.f*L2E) : L2E;
    short* d = Wxc + t16*64 + cc*4;
    d[0] = (short)f2bf(Wih[2*n + 0] * sc);
    d[1] = (short)f2bf(Wih[2*n + 1] * sc);
    d[2] = (short)f2bf((bih[n] + bhh[n]) * sc);
    d[3] = 0;
  }

  // zero h_s (4608 dwords)
  #pragma unroll
  for (int i = 0; i < 9; ++i) ((uint32_t*)h_s)[i*512 + tid] = 0u;

  // ---- per-lane x prep for row (w16+col); quads redundant, quad0 publishes
  {
    const int grow = row0 + w16 + col;
    float xv0[8], xv1[8];
    int lzi = -1;
    #pragma unroll
    for (int t = 0; t < 8; ++t) {
      float m = nhm[(size_t)grow*8 + t];
      float a = obs[((size_t)grow*8 + t)*2 + 0] * m;
      float b = obs[((size_t)grow*8 + t)*2 + 1] * m;
      xv0[t] = a; xv1[t] = b;
      if (a == 0.f) lzi = t;
    }
    if (quad == 0) {
      #pragma unroll
      for (int t = 0; t < 8; ++t) {
        bool kill = (t < lzi);
        float a = kill ? 0.f : xv0[t];
        float b = kill ? 0.f : xv1[t];
        x_pk[t][w16 + col] = (uint32_t)f2bf(a) | ((uint32_t)f2bf(b) << 16);
      }
      int len = 7 - lzi; if (len < 1) len = 1;
      len_s[w16 + col] = len;
    }
  }
  __syncthreads();     // the ONLY barrier

  int lenr[4];
  #pragma unroll
  for (int r = 0; r < 4; ++r) lenr[r] = len_s[w16 + quad*4 + r];

  float c_[16];
  #pragma unroll
  for (int i = 0; i < 16; ++i) c_[i] = 0.f;

  const f32x4 zero4 = {0.f, 0.f, 0.f, 0.f};
  const bool q0 = (quad == 0);

  #pragma unroll 1
  for (int t = 0; t < 8; ++t) {
    // ---- A-frag for the x/bias MFMA: [x0, x1, 1, 0...] on quad 0 ----
    uint32_t xw = x_pk[t][w16 + col];
    union { bf16x8 v; uint32_t u[4]; } ax;
    ax.u[0] = q0 ? xw : 0u;
    ax.u[1] = q0 ? 0x00003f80u : 0u;    // bf16(1.0) at k==2
    ax.u[2] = 0u; ax.u[3] = 0u;

    // A-frags of h (bf16, no converts)
    bf16x8 a0 = *(const bf16x8*)(h_s + (w16 + col)*72 + quad*8);
    bf16x8 a1 = *(const bf16x8*)(h_s + (w16 + col)*72 + 32 + quad*8);

    // 4 column-groups: tiles {cc, cc+4, cc+8, cc+12} = i,f,g,o for cells
    // n = cc*16+col. Only 4 accumulators live at a time.
    #pragma unroll
    for (int cc = 0; cc < 4; ++cc) {
      f32x4 acc[4];
      #pragma unroll
      for (int g = 0; g < 4; ++g) {
        const int t16 = g*4 + cc;
        union { bf16x8 v; uint32_t u[4]; } wx;
        uint2 d = *(const uint2*)(Wxc + t16*64 + col*4);  // always initialized
        wx.u[0] = q0 ? d.x : 0u;        // zero fragment on non-quad0 lanes
        wx.u[1] = q0 ? d.y : 0u;
        wx.u[2] = 0u; wx.u[3] = 0u;
        bf16x8 b0 = *(const bf16x8*)(Wfrag + (t16*2+0)*512 + lane*8);
        bf16x8 b1 = *(const bf16x8*)(Wfrag + (t16*2+1)*512 + lane*8);
        acc[g] = __builtin_amdgcn_mfma_f32_16x16x32_bf16(ax.v, wx.v, zero4, 0, 0, 0);
        acc[g] = __builtin_amdgcn_mfma_f32_16x16x32_bf16(a0, b0, acc[g], 0, 0, 0);
        acc[g] = __builtin_amdgcn_mfma_f32_16x16x32_bf16(a1, b1, acc[g], 0, 0, 0);
      }
      #pragma unroll
      for (int r = 0; r < 4; ++r) {
        if (t < lenr[r]) {
          float gi = acc[0][r];
          float gf = acc[1][r];
          float gg = acc[2][r];
          float go = acc[3][r];
          float cn = sig2(gf)*c_[cc*4+r] + sig2(gi)*tanh2(gg);
          c_[cc*4+r] = cn;
          h_s[(w16 + quad*4 + r)*72 + cc*16 + col] =
              (short)f2bf(sig2(go)*tanh2(cn*(2.f*L2E)));
        }
      }
      __builtin_amdgcn_sched_barrier(0);  // pin group: keep acc lifetime short
    }
    // no per-step barrier: each wave owns its 16 h rows
  }

  // he = relu(h) bf16, wave-local b128 stores
  #pragma unroll
  for (int s = 0; s < 2; ++s) {
    int chunk = s*64 + lane;          // 128 chunks of 8 shorts per wave
    int rl = chunk >> 3, c8 = chunk & 7;
    bf16x8 v = *(const bf16x8*)(h_s + (w16 + rl)*72 + c8*8);
    #pragma unroll
    for (int j = 0; j < 8; ++j) {
      short sv = v[j];
      v[j] = (sv & (short)0x8000) ? (short)0 : sv;   // relu (handles -0.0)
    }
    *(bf16x8*)(he + (size_t)(row0 + w16 + rl)*64 + c8*8) = v;
  }
}

// ---------------------------------------------------------------------------
// MFMA MLP (unchanged)
__global__ __launch_bounds__(256) void mlp_kernel(
    const unsigned short* __restrict__ he,
    const float* __restrict__ W1, const float* __restrict__ b1,
    const float* __restrict__ W2, const float* __restrict__ b2,
    const float* __restrict__ Wh, const float* __restrict__ bh,
    const float* __restrict__ Wq, const float* __restrict__ bq,
    const float* __restrict__ Wk, const float* __restrict__ bk,
    const float* __restrict__ Wv, const float* __restrict__ bv,
    unsigned short* __restrict__ qb, unsigned short* __restrict__ kb,
    unsigned short* __restrict__ vt, float* __restrict__ feat)
{
  __shared__ short Wm[3][8*512];       // 24 KB B-frags
  __shared__ float bias_s[6*64];       // 1.5 KB
  __shared__ short Atile[4][16*76];    // 9.5 KB per-wave relayout tiles

  const int tid  = threadIdx.x;
  const int lane = tid & 63;
  const int wv   = tid >> 6;
  const int quad = lane >> 4;
  const int col  = lane & 15;
  const int rowb = blockIdx.x*64 + wv*16;

  const float* m1[3] = {W1, W2, Wh};
  const float* m2[3] = {Wq, Wk, Wv};
  auto stage3 = [&](const float* const* mats, float sc0) {
    #pragma unroll
    for (int i = 0; i < 6; ++i) {
      int p = i*256 + tid;
      int m = p >> 9, rem = p & 511;
      int f = rem >> 6, l = rem & 63;
      int nt = f >> 1, s = f & 1;
      int lq = l >> 4, lc = l & 15;
      float sc = (m == 0) ? sc0 : 1.f;
      const float* src = mats[m] + (size_t)(nt*16 + lc)*64 + s*32 + lq*8;
      short* dst = &Wm[m][f*512 + l*8];
      #pragma unroll
      for (int j = 0; j < 8; ++j) dst[j] = (short)f2bf(src[j] * sc);
    }
  };
  stage3(m1, 1.f);
  {
    const float* bs[6] = {b1, b2, bh, bq, bk, bv};
    for (int i = tid; i < 384; i += 256) {
      float sc = ((i >> 6) == 3) ? L2E : 1.f;      // bq scaled by log2(e)
      bias_s[i] = bs[i>>6][i & 63] * sc;
    }
  }
  __syncthreads();

  bf16x8 a0 = *(const bf16x8*)(he + (size_t)(rowb + col)*64 + quad*8);
  bf16x8 a1 = *(const bf16x8*)(he + (size_t)(rowb + col)*64 + quad*8 + 32);

  f32x4 acc[4];
  auto runL = [&](int m, int bidx) {
    #pragma unroll
    for (int nt = 0; nt < 4; ++nt) {
      float bb = bias_s[bidx*64 + nt*16 + col];
      acc[nt][0] = bb; acc[nt][1] = bb; acc[nt][2] = bb; acc[nt][3] = bb;
    }
    #pragma unroll
    for (int nt = 0; nt < 4; ++nt) {
      bf16x8 bf0 = *(const bf16x8*)(&Wm[m][(nt*2+0)*512 + lane*8]);
      bf16x8 bf1 = *(const bf16x8*)(&Wm[m][(nt*2+1)*512 + lane*8]);
      acc[nt] = __builtin_amdgcn_mfma_f32_16x16x32_bf16(a0, bf0, acc[nt], 0,0,0);
      acc[nt] = __builtin_amdgcn_mfma_f32_16x16x32_bf16(a1, bf1, acc[nt], 0,0,0);
    }
  };
  auto tileWrite = [&](bool relu) {
    #pragma unroll
    for (int nt = 0; nt < 4; ++nt)
      #pragma unroll
      for (int r = 0; r < 4; ++r) {
        float v = relu ? fmaxf(acc[nt][r], 0.f) : acc[nt][r];
        Atile[wv][(quad*4+r)*76 + ((nt*16+col) ^ (r*16))] = (short)f2bf(v);
      }
  };
  auto tileReadA = [&]() {
    int sw = (col & 3) * 16;
    a0 = *(const bf16x8*)(&Atile[wv][col*76 + ((quad*8     ) ^ sw)]);
    a1 = *(const bf16x8*)(&Atile[wv][col*76 + ((quad*8 + 32) ^ sw)]);
  };
  auto storeBF = [&](unsigned short* dst) {
    #pragma unroll
    for (int s = 0; s < 2; ++s) {
      int chunk = s*64 + lane;
      int r = chunk >> 3, c8 = chunk & 7;
      bf16x8 v = *(const bf16x8*)(&Atile[wv][r*76 + ((c8*8) ^ ((r&3)*16))]);
      *(bf16x8*)(dst + (size_t)(rowb + r)*64 + c8*8) = v;
    }
  };

  runL(0, 0); tileWrite(true); tileReadA();
  runL(1, 1); tileWrite(true); tileReadA();
  runL(2, 2); tileWrite(true); tileReadA();      // a0/a1 = hidden A-frags
  __syncthreads();
  stage3(m2, L2E);                               // Wq scaled by log2(e)
  __syncthreads();

  runL(0, 3); tileWrite(false); storeBF(qb);     // q (bf16, L2E-scaled)
  runL(1, 4); tileWrite(false); storeBF(kb);     // k (bf16)
  runL(2, 5);                                    // v
  {
    const int bi   = rowb >> 9;                  // batch
    const int key0 = (rowb & 511) + quad*4;
    #pragma unroll
    for (int nt = 0; nt < 4; ++nt) {
      #pragma unroll
      for (int r = 0; r < 4; ++r)
        feat[(size_t)(rowb + quad*4 + r)*128 + nt*16 + col] = acc[nt][r];
      uint32_t lo = (uint32_t)f2bf(acc[nt][0]) | ((uint32_t)f2bf(acc[nt][1]) << 16);
      uint32_t hi = (uint32_t)f2bf(acc[nt][2]) | ((uint32_t)f2bf(acc[nt][3]) << 16);
      uint2 pk; pk.x = lo; pk.y = hi;
      *(uint2*)(vt + ((size_t)bi*64 + nt*16 + col)*512 + key0) = pk;
    }
  }
}

// ---------------------------------------------------------------------------
// MFMA attention v2: pad_mask packing FUSED into the prologue (maskpack
// kernel eliminated). Per wave: its 16 q-rows x 512 keys = 32KB of pm via 32
// fully-coalesced int4 loads; element L=k*64+lane covers keys 4L..4L+3 of the
// strip; word = k*8+(lane>>3), nibble shift (lane&7)*4; 3x shfl_xor-OR
// assembles each 32-key word; lane&7==0 writes Ms[wv][k*8+(lane>>3)].
// Bit layout identical to the old bm words — c-loop untouched. Ms is
// per-wave (same-wave write->read, like Pl): no extra barrier needed.
__global__ __launch_bounds__(256) void attn_kernel(
    const unsigned short* __restrict__ qg, const unsigned short* __restrict__ kg,
    const unsigned short* __restrict__ vt,
    const int4* __restrict__ pm4, float* __restrict__ feat)
{
  __shared__ short    Ks[128*72];      // 18.0 KB
  __shared__ short    Vt[64*136];      // 17.0 KB
  __shared__ short    Pl[4][16*32];    // 4 KB, per-wave
  __shared__ uint32_t Ms[4][256];      // 4 KB, per-wave mask words

  const int tid  = threadIdx.x;
  const int lane = tid & 63;
  const int wv   = tid >> 6;
  const int quad = lane >> 4;
  const int col  = lane & 15;

  const int b     = blockIdx.x >> 3;
  const int q0    = (blockIdx.x & 7) * 64;
  const int qbase = b*512 + q0 + wv*16;

  bf16x8 qa[2];
  qa[0] = *(const bf16x8*)(qg + (size_t)(qbase + col)*64 + quad*8);
  qa[1] = *(const bf16x8*)(qg + (size_t)(qbase + col)*64 + quad*8 + 32);

  // ---- fused mask pack: 16 rows x 512 keys for this wave ----
  {
    const int4* pw = pm4 + (size_t)qbase * 128;  // 128 int4 per q-row
    const int sh = (lane & 7) * 4;
    #pragma unroll 8
    for (int k = 0; k < 32; ++k) {
      int4 v = pw[k*64 + lane];                  // coalesced 1KB/instruction
      uint32_t nib = (v.x != 0 ? 1u : 0u)
                   | (v.y != 0 ? 2u : 0u)
                   | (v.z != 0 ? 4u : 0u)
                   | (v.w != 0 ? 8u : 0u);
      uint32_t x = nib << sh;
      x |= __shfl_xor(x, 1);
      x |= __shfl_xor(x, 2);
      x |= __shfl_xor(x, 4);
      if ((lane & 7) == 0)
        Ms[wv][k*8 + (lane >> 3)] = x;
    }
  }

  f32x4 o_acc[4];
  #pragma unroll
  for (int nt = 0; nt < 4; ++nt)
    #pragma unroll
    for (int r = 0; r < 4; ++r) o_acc[nt][r] = 0.f;
  float l_part[4] = {0.f, 0.f, 0.f, 0.f};

  const unsigned short* vtb = vt + (size_t)b*64*512;

  for (int c = 0; c < 4; ++c) {
    __syncthreads();
    {
      const int kb_ = b*512 + c*128;
      // K chunk: bf16 [key][dim] stride 72
      #pragma unroll
      for (int i = 0; i < 4; ++i) {
        int p = i*256 + tid;
        int key = p >> 3, c8 = p & 7;
        bf16x8 kv = *(const bf16x8*)(kg + (size_t)(kb_ + key)*64 + c8*8);
        *(bf16x8*)(Ks + key*72 + c8*8) = kv;
      }
      // V^T chunk: bf16 [dim][key] stride 136 — pure copies
      #pragma unroll
      for (int i = 0; i < 4; ++i) {
        int p = i*256 + tid;
        int dim = p >> 4, k8 = p & 15;
        bf16x8 vv = *(const bf16x8*)(vtb + (size_t)dim*512 + c*128 + k8*8);
        *(bf16x8*)(Vt + dim*136 + k8*8) = vv;
      }
    }
    __syncthreads();

    for (int kc = 0; kc < 4; ++kc) {
      #pragma unroll
      for (int t = 0; t < 2; ++t) {
        const int kt = kc*2 + t;
        f32x4 s_acc;
        #pragma unroll
        for (int r = 0; r < 4; ++r) s_acc[r] = 0.f;
        const short* kp = Ks + (kt*16 + col)*72 + quad*8;
        bf16x8 kb0 = *(const bf16x8*)(kp);
        bf16x8 kb1 = *(const bf16x8*)(kp + 32);
        s_acc = __builtin_amdgcn_mfma_f32_16x16x32_bf16(qa[0], kb0, s_acc, 0,0,0);
        s_acc = __builtin_amdgcn_mfma_f32_16x16x32_bf16(qa[1], kb1, s_acc, 0,0,0);
        const int kcol = ((t*16 + col) ^ (quad*8));
        #pragma unroll
        for (int r = 0; r < 4; ++r) {
          uint32_t mw = Ms[wv][(quad*4+r)*16 + c*4 + (kt>>1)];
          float p = ((mw >> ((kt&1)*16 + col)) & 1u)
                      ? exp2f_(fminf(s_acc[r], 43.f)) : 0.f;   // s pre-scaled
          l_part[r] += p;
          Pl[wv][(quad*4+r)*32 + kcol] = (short)f2bf(p);
        }
      }
      bf16x8 pa = *(const bf16x8*)(&Pl[wv][col*32 + ((quad*8) ^ (((col)>>2)*8))]);
      #pragma unroll
      for (int nt = 0; nt < 4; ++nt) {
        bf16x8 vb = *(const bf16x8*)(&Vt[(nt*16+col)*136 + kc*32 + quad*8]);
        o_acc[nt] = __builtin_amdgcn_mfma_f32_16x16x32_bf16(pa, vb, o_acc[nt], 0,0,0);
      }
    }
  }

  float inv[4];
  #pragma unroll
  for (int r = 0; r < 4; ++r) {
    float v = l_part[r];
    v += __shfl_xor(v, 1);
    v += __shfl_xor(v, 2);
    v += __shfl_xor(v, 4);
    v += __shfl_xor(v, 8);
    inv[r] = rcpf_(fmaxf(v, 1e-20f));
  }

  #pragma unroll
  for (int nt = 0; nt < 4; ++nt)
    #pragma unroll
    for (int r = 0; r < 4; ++r)
      feat[(size_t)(qbase + quad*4 + r)*128 + 64 + nt*16 + col] = o_acc[nt][r]*inv[r];
}

// ---------------------------------------------------------------------------
// MFMA forecast: out[16rows][24] = feat[16x128]@Wf^T + bf per wave.
__global__ __launch_bounds__(256) void forecast_kernel(
    const float* __restrict__ feat, const float* __restrict__ Wf,
    const float* __restrict__ bf, float* __restrict__ out)
{
  __shared__ short Wfr[8*512];         // 8 KB B-frags
  __shared__ float bl[32];

  const int tid  = threadIdx.x;
  const int lane = tid & 63;
  const int wv   = tid >> 6;
  const int quad = lane >> 4;
  const int col  = lane & 15;
  const int rowb = blockIdx.x*64 + wv*16;

  #pragma unroll
  for (int i = 0; i < 2; ++i) {
    int p = i*256 + tid;               // 512 (frag,lane) entries
    int f = p >> 6, l = p & 63;
    int kc = f >> 1, nt = f & 1;
    int lq = l >> 4, lc = l & 15;
    int n = nt*16 + lc;
    bf16x8 v;
    #pragma unroll
    for (int j = 0; j < 8; ++j) v[j] = 0;
    if (n < 24) {
      const float* src = Wf + (size_t)n*128 + kc*32 + lq*8;
      #pragma unroll
      for (int j = 0; j < 8; ++j) v[j] = (short)f2bf(src[j]);
    }
    *(bf16x8*)(Wfr + f*512 + l*8) = v;
  }
  if (tid < 32) bl[tid] = (tid < 24) ? bf[tid] : 0.f;
  __syncthreads();

  // A-frags: my row (rowb+col), 4 k32 chunks
  bf16x8 af[4];
  const float* fr = feat + (size_t)(rowb + col)*128;
  #pragma unroll
  for (int kc = 0; kc < 4; ++kc) {
    float4 f0 = *(const float4*)(fr + kc*32 + quad*8);
    float4 f1 = *(const float4*)(fr + kc*32 + quad*8 + 4);
    af[kc][0]=(short)f2bf(f0.x); af[kc][1]=(short)f2bf(f0.y);
    af[kc][2]=(short)f2bf(f0.z); af[kc][3]=(short)f2bf(f0.w);
    af[kc][4]=(short)f2bf(f1.x); af[kc][5]=(short)f2bf(f1.y);
    af[kc][6]=(short)f2bf(f1.z); af[kc][7]=(short)f2bf(f1.w);
  }

  f32x4 acc[2];
  #pragma unroll
  for (int nt = 0; nt < 2; ++nt) {
    float bb = bl[nt*16 + col];
    acc[nt][0] = bb; acc[nt][1] = bb; acc[nt][2] = bb; acc[nt][3] = bb;
  }
  #pragma unroll
  for (int kc = 0; kc < 4; ++kc) {
    #pragma unroll
    for (int nt = 0; nt < 2; ++nt) {
      bf16x8 b = *(const bf16x8*)(Wfr + (kc*2+nt)*512 + lane*8);
      acc[nt] = __builtin_amdgcn_mfma_f32_16x16x32_bf16(af[kc], b, acc[nt], 0,0,0);
    }
  }

  #pragma unroll
  for (int nt = 0; nt < 2; ++nt) {
    int n = nt*16 + col;
    if (n < 24) {
      #pragma unroll
      for (int r = 0; r < 4; ++r)
        out[(size_t)(rowb + quad*4 + r)*24 + n] = acc[nt][r];
    }
  }
}

// ---------------------------------------------------------------------------
extern "C" void kernel_launch(void* const* d_in, const int* in_sizes, int n_in,
                              void* d_out, int out_size, void* d_ws, size_t ws_size,
                              hipStream_t stream)
{
  const float* obs = (const float*)d_in[0];
  const int*   pm  = (const int*)  d_in[1];
  const float* nhm = (const float*)d_in[2];
  const float* Wih = (const float*)d_in[3];
  const float* Whh = (const float*)d_in[4];
  const float* bih = (const float*)d_in[5];
  const float* bhh = (const float*)d_in[6];
  const float* W1  = (const float*)d_in[7];
  const float* b1  = (const float*)d_in[8];
  const float* W2  = (const float*)d_in[9];
  const float* b2  = (const float*)d_in[10];
  const float* Wh  = (const float*)d_in[11];
  const float* bh  = (const float*)d_in[12];
  const float* Wq  = (const float*)d_in[13];
  const float* bq  = (const float*)d_in[14];
  const float* Wk  = (const float*)d_in[15];
  const float* bk  = (const float*)d_in[16];
  const float* Wv  = (const float*)d_in[17];
  const float* bv  = (const float*)d_in[18];
  const float* Wf  = (const float*)d_in[19];
  const float* bf  = (const float*)d_in[20];

  float* out  = (float*)d_out;                 // forecast: 65536*24
  float* feat = out + (size_t)M_*24;           // feat:     65536*128

  // workspace: he(8MB) | qb(8MB) | kb(8MB) | vt(8MB)
  char* ws = (char*)d_ws;
  unsigned short* he  = (unsigned short*)(ws);
  unsigned short* qbf = (unsigned short*)(ws + (size_t) 8*1024*1024);
  unsigned short* kbf = (unsigned short*)(ws + (size_t)16*1024*1024);
  unsigned short* vtb = (unsigned short*)(ws + (size_t)24*1024*1024);

  lstm_kernel<<<M_/128, 512, 0, stream>>>(obs, nhm, Wih, Whh, bih, bhh, he);
  mlp_kernel<<<M_/64, 256, 0, stream>>>(he, W1,b1, W2,b2, Wh,bh, Wq,bq, Wk,bk, Wv,bv,
                                        qbf, kbf, vtb, feat);
  attn_kernel<<<M_/64, 256, 0, stream>>>(qbf, kbf, vtb, (const int4*)pm, feat);
  forecast_kernel<<<M_/64, 256, 0, stream>>>(feat, Wf, bf, out);
}

// Round 5
// 320.275 us; speedup vs baseline: 1.1190x; 1.1190x over previous
//
#include <hip/hip_runtime.h>
#include <hip/hip_bf16.h>
#include <stdint.h>

#define B_ 128
#define N_ 512
#define S_ 8
#define H_ 64
#define M_ (B_*N_)          // 65536 rows
#define L2E 1.442695041f

typedef __attribute__((ext_vector_type(8))) short bf16x8;
typedef __attribute__((ext_vector_type(4))) float f32x4;

__device__ __forceinline__ float exp2f_(float x) { return __builtin_amdgcn_exp2f(x); }
__device__ __forceinline__ float rcpf_(float x)  { return __builtin_amdgcn_rcpf(x); }
// x pre-scaled by log2(e):  sig2(x) == sigmoid(x / L2E)   (v_exp + v_rcp only)
__device__ __forceinline__ float sig2(float x)  { return rcpf_(1.f + exp2f_(-x)); }
// x pre-scaled by 2*log2(e): tanh2(x) == tanh(x / (2*L2E))
__device__ __forceinline__ float tanh2(float x) { return 1.f - 2.f*rcpf_(exp2f_(x) + 1.f); }
// fp32 -> bf16 round-to-nearest-even
__device__ __forceinline__ unsigned short f2bf(float x) {
  unsigned int u = __float_as_uint(x);
  u += 0x7fffu + ((u >> 16) & 1u);
  return (unsigned short)(u >> 16);
}

// ---------------------------------------------------------------------------
// MFMA LSTM v7 = v6 + pad_mask bit-packing fused into the t-loop.
//  - Each of the 4096 waves owns a 256-word strip of bm (nwords = 4096*256).
//  - Per t-step (8 steps): 4 coalesced int4 loads (1KB/instruction) issued
//    AFTER the MFMA/gate phase; nibble-pack + 3x shfl_xor OR; lane&7==0
//    stores the word. The ~900cy load stall of one wave is hidden by the
//    other 3 waves/SIMD doing MFMA (TLP hiding — what the standalone /
//    prologue variants lacked). 16 transient VGPRs reuse freed acc space.
//  - Bit layout identical to the ballot version (attn unchanged).
__global__ __launch_bounds__(512, 4) void lstm_kernel(
    const float* __restrict__ obs, const float* __restrict__ nhm,
    const float* __restrict__ Wih, const float* __restrict__ Whh,
    const float* __restrict__ bih, const float* __restrict__ bhh,
    unsigned short* __restrict__ he,
    const int4* __restrict__ pm4, uint32_t* __restrict__ bm)
{
  __shared__ short    Wfrag[32*512];   // 32 KB  Whh B-frags (bf16, gate-scaled)
  __shared__ short    Wxc[1024];       // 2 KB   compact [Wih0,Wih1,bias,0] per n
  __shared__ short    h_s[128*72];     // 18 KB  bf16, stride 72
  __shared__ uint32_t x_pk[8][128];    // 4 KB   packed bf16 (x0,x1) per (t,row)
  __shared__ int      len_s[128];      // 0.5 KB

  const int tid  = threadIdx.x;
  const int lane = tid & 63;
  const int wv   = tid >> 6;           // 0..7
  const int w16  = wv * 16;
  const int quad = lane >> 4;
  const int col  = lane & 15;
  const int row0 = blockIdx.x * 128;

  // pm strip for this wave: 256 words = 2048 int4
  const int     wb  = (blockIdx.x*8 + wv) * 256;       // word base
  const int4*   pw  = pm4 + (size_t)wb * 8;            // int4 base
  const int     shp = (lane & 7) * 4;                  // nibble shift

  // ---- stage Whh as bf16 B-fragments (gate-scaled), 2048 (frag,lane) entries
  #pragma unroll
  for (int i = 0; i < 4; ++i) {
    int p = i*512 + tid;
    int f = p >> 6, l = p & 63;
    int t16 = f >> 1, s = f & 1;
    int lq = l >> 4, lc = l & 15;
    const float sc = (t16 >= 8 && t16 < 12) ? (2.f*L2E) : L2E;
    const float* src = Whh + (size_t)(t16*16 + lc)*64 + s*32 + lq*8;
    short* dst = Wfrag + f*512 + l*8;
    #pragma unroll
    for (int j = 0; j < 8; ++j) dst[j] = (short)f2bf(src[j] * sc);
  }
  // ---- stage compact Wx: Wxc[t16*64 + cc*4 + k], k: 0=Wih0 1=Wih1 2=bias ----
  if (tid < 256) {
    int t16 = tid >> 4, cc = tid & 15;
    int n = t16*16 + cc;
    const float sc = (t16 >= 8 && t16 < 12) ? (2.f*L2E) : L2E;
    short* d = Wxc + t16*64 + cc*4;
    d[0] = (short)f2bf(Wih[2*n + 0] * sc);
    d[1] = (short)f2bf(Wih[2*n + 1] * sc);
    d[2] = (short)f2bf((bih[n] + bhh[n]) * sc);
    d[3] = 0;
  }

  // zero h_s (4608 dwords)
  #pragma unroll
  for (int i = 0; i < 9; ++i) ((uint32_t*)h_s)[i*512 + tid] = 0u;

  // ---- per-lane x prep for row (w16+col); quads redundant, quad0 publishes
  {
    const int grow = row0 + w16 + col;
    float xv0[8], xv1[8];
    int lzi = -1;
    #pragma unroll
    for (int t = 0; t < 8; ++t) {
      float m = nhm[(size_t)grow*8 + t];
      float a = obs[((size_t)grow*8 + t)*2 + 0] * m;
      float b = obs[((size_t)grow*8 + t)*2 + 1] * m;
      xv0[t] = a; xv1[t] = b;
      if (a == 0.f) lzi = t;
    }
    if (quad == 0) {
      #pragma unroll
      for (int t = 0; t < 8; ++t) {
        bool kill = (t < lzi);
        float a = kill ? 0.f : xv0[t];
        float b = kill ? 0.f : xv1[t];
        x_pk[t][w16 + col] = (uint32_t)f2bf(a) | ((uint32_t)f2bf(b) << 16);
      }
      int len = 7 - lzi; if (len < 1) len = 1;
      len_s[w16 + col] = len;
    }
  }
  __syncthreads();     // the ONLY barrier

  int lenr[4];
  #pragma unroll
  for (int r = 0; r < 4; ++r) lenr[r] = len_s[w16 + quad*4 + r];

  float c_[16];
  #pragma unroll
  for (int i = 0; i < 16; ++i) c_[i] = 0.f;

  const f32x4 zero4 = {0.f, 0.f, 0.f, 0.f};
  const bool q0 = (quad == 0);

  #pragma unroll 1
  for (int t = 0; t < 8; ++t) {
    // ---- A-frag for the x/bias MFMA: [x0, x1, 1, 0...] on quad 0 ----
    uint32_t xw = x_pk[t][w16 + col];
    union { bf16x8 v; uint32_t u[4]; } ax;
    ax.u[0] = q0 ? xw : 0u;
    ax.u[1] = q0 ? 0x00003f80u : 0u;    // bf16(1.0) at k==2
    ax.u[2] = 0u; ax.u[3] = 0u;

    // A-frags of h (bf16, no converts)
    bf16x8 a0 = *(const bf16x8*)(h_s + (w16 + col)*72 + quad*8);
    bf16x8 a1 = *(const bf16x8*)(h_s + (w16 + col)*72 + 32 + quad*8);

    // 4 column-groups: tiles {cc, cc+4, cc+8, cc+12} = i,f,g,o for cells
    // n = cc*16+col. Only 4 accumulators live at a time.
    #pragma unroll
    for (int cc = 0; cc < 4; ++cc) {
      f32x4 acc[4];
      #pragma unroll
      for (int g = 0; g < 4; ++g) {
        const int t16 = g*4 + cc;
        union { bf16x8 v; uint32_t u[4]; } wx;
        uint2 d = *(const uint2*)(Wxc + t16*64 + col*4);  // always initialized
        wx.u[0] = q0 ? d.x : 0u;        // zero fragment on non-quad0 lanes
        wx.u[1] = q0 ? d.y : 0u;
        wx.u[2] = 0u; wx.u[3] = 0u;
        bf16x8 b0 = *(const bf16x8*)(Wfrag + (t16*2+0)*512 + lane*8);
        bf16x8 b1 = *(const bf16x8*)(Wfrag + (t16*2+1)*512 + lane*8);
        acc[g] = __builtin_amdgcn_mfma_f32_16x16x32_bf16(ax.v, wx.v, zero4, 0, 0, 0);
        acc[g] = __builtin_amdgcn_mfma_f32_16x16x32_bf16(a0, b0, acc[g], 0, 0, 0);
        acc[g] = __builtin_amdgcn_mfma_f32_16x16x32_bf16(a1, b1, acc[g], 0, 0, 0);
      }
      #pragma unroll
      for (int r = 0; r < 4; ++r) {
        if (t < lenr[r]) {
          float gi = acc[0][r];
          float gf = acc[1][r];
          float gg = acc[2][r];
          float go = acc[3][r];
          float cn = sig2(gf)*c_[cc*4+r] + sig2(gi)*tanh2(gg);
          c_[cc*4+r] = cn;
          h_s[(w16 + quad*4 + r)*72 + cc*16 + col] =
              (short)f2bf(sig2(go)*tanh2(cn*(2.f*L2E)));
        }
      }
      __builtin_amdgcn_sched_barrier(0);  // pin group: keep acc lifetime short
    }

    // ---- fused pad_mask pack: 4 coalesced int4 loads per step ----
    // int4 idx = t*256 + jj*64 + lane; word = wb + t*32 + jj*8 + lane/8.
    {
      const int4* ps = pw + t*256 + lane;
      int4 v0 = ps[0];
      int4 v1 = ps[64];
      int4 v2 = ps[128];
      int4 v3 = ps[192];
      int4 vv[4] = {v0, v1, v2, v3};
      #pragma unroll
      for (int jj = 0; jj < 4; ++jj) {
        int4 v = vv[jj];
        uint32_t nib = (v.x != 0 ? 1u : 0u)
                     | (v.y != 0 ? 2u : 0u)
                     | (v.z != 0 ? 4u : 0u)
                     | (v.w != 0 ? 8u : 0u);
        uint32_t x = nib << shp;
        x |= __shfl_xor(x, 1);
        x |= __shfl_xor(x, 2);
        x |= __shfl_xor(x, 4);
        if ((lane & 7) == 0)
          bm[wb + t*32 + jj*8 + (lane >> 3)] = x;
      }
      __builtin_amdgcn_sched_barrier(0);  // keep pm block out of next step's MFMA region
    }
    // no per-step barrier: each wave owns its 16 h rows
  }

  // he = relu(h) bf16, wave-local b128 stores
  #pragma unroll
  for (int s = 0; s < 2; ++s) {
    int chunk = s*64 + lane;          // 128 chunks of 8 shorts per wave
    int rl = chunk >> 3, c8 = chunk & 7;
    bf16x8 v = *(const bf16x8*)(h_s + (w16 + rl)*72 + c8*8);
    #pragma unroll
    for (int j = 0; j < 8; ++j) {
      short sv = v[j];
      v[j] = (sv & (short)0x8000) ? (short)0 : sv;   // relu (handles -0.0)
    }
    *(bf16x8*)(he + (size_t)(row0 + w16 + rl)*64 + c8*8) = v;
  }
}

// ---------------------------------------------------------------------------
// MFMA MLP (unchanged)
__global__ __launch_bounds__(256) void mlp_kernel(
    const unsigned short* __restrict__ he,
    const float* __restrict__ W1, const float* __restrict__ b1,
    const float* __restrict__ W2, const float* __restrict__ b2,
    const float* __restrict__ Wh, const float* __restrict__ bh,
    const float* __restrict__ Wq, const float* __restrict__ bq,
    const float* __restrict__ Wk, const float* __restrict__ bk,
    const float* __restrict__ Wv, const float* __restrict__ bv,
    unsigned short* __restrict__ qb, unsigned short* __restrict__ kb,
    unsigned short* __restrict__ vt, float* __restrict__ feat)
{
  __shared__ short Wm[3][8*512];       // 24 KB B-frags
  __shared__ float bias_s[6*64];       // 1.5 KB
  __shared__ short Atile[4][16*76];    // 9.5 KB per-wave relayout tiles

  const int tid  = threadIdx.x;
  const int lane = tid & 63;
  const int wv   = tid >> 6;
  const int quad = lane >> 4;
  const int col  = lane & 15;
  const int rowb = blockIdx.x*64 + wv*16;

  const float* m1[3] = {W1, W2, Wh};
  const float* m2[3] = {Wq, Wk, Wv};
  auto stage3 = [&](const float* const* mats, float sc0) {
    #pragma unroll
    for (int i = 0; i < 6; ++i) {
      int p = i*256 + tid;
      int m = p >> 9, rem = p & 511;
      int f = rem >> 6, l = rem & 63;
      int nt = f >> 1, s = f & 1;
      int lq = l >> 4, lc = l & 15;
      float sc = (m == 0) ? sc0 : 1.f;
      const float* src = mats[m] + (size_t)(nt*16 + lc)*64 + s*32 + lq*8;
      short* dst = &Wm[m][f*512 + l*8];
      #pragma unroll
      for (int j = 0; j < 8; ++j) dst[j] = (short)f2bf(src[j] * sc);
    }
  };
  stage3(m1, 1.f);
  {
    const float* bs[6] = {b1, b2, bh, bq, bk, bv};
    for (int i = tid; i < 384; i += 256) {
      float sc = ((i >> 6) == 3) ? L2E : 1.f;      // bq scaled by log2(e)
      bias_s[i] = bs[i>>6][i & 63] * sc;
    }
  }
  __syncthreads();

  bf16x8 a0 = *(const bf16x8*)(he + (size_t)(rowb + col)*64 + quad*8);
  bf16x8 a1 = *(const bf16x8*)(he + (size_t)(rowb + col)*64 + quad*8 + 32);

  f32x4 acc[4];
  auto runL = [&](int m, int bidx) {
    #pragma unroll
    for (int nt = 0; nt < 4; ++nt) {
      float bb = bias_s[bidx*64 + nt*16 + col];
      acc[nt][0] = bb; acc[nt][1] = bb; acc[nt][2] = bb; acc[nt][3] = bb;
    }
    #pragma unroll
    for (int nt = 0; nt < 4; ++nt) {
      bf16x8 bf0 = *(const bf16x8*)(&Wm[m][(nt*2+0)*512 + lane*8]);
      bf16x8 bf1 = *(const bf16x8*)(&Wm[m][(nt*2+1)*512 + lane*8]);
      acc[nt] = __builtin_amdgcn_mfma_f32_16x16x32_bf16(a0, bf0, acc[nt], 0,0,0);
      acc[nt] = __builtin_amdgcn_mfma_f32_16x16x32_bf16(a1, bf1, acc[nt], 0,0,0);
    }
  };
  auto tileWrite = [&](bool relu) {
    #pragma unroll
    for (int nt = 0; nt < 4; ++nt)
      #pragma unroll
      for (int r = 0; r < 4; ++r) {
        float v = relu ? fmaxf(acc[nt][r], 0.f) : acc[nt][r];
        Atile[wv][(quad*4+r)*76 + ((nt*16+col) ^ (r*16))] = (short)f2bf(v);
      }
  };
  auto tileReadA = [&]() {
    int sw = (col & 3) * 16;
    a0 = *(const bf16x8*)(&Atile[wv][col*76 + ((quad*8     ) ^ sw)]);
    a1 = *(const bf16x8*)(&Atile[wv][col*76 + ((quad*8 + 32) ^ sw)]);
  };
  auto storeBF = [&](unsigned short* dst) {
    #pragma unroll
    for (int s = 0; s < 2; ++s) {
      int chunk = s*64 + lane;
      int r = chunk >> 3, c8 = chunk & 7;
      bf16x8 v = *(const bf16x8*)(&Atile[wv][r*76 + ((c8*8) ^ ((r&3)*16))]);
      *(bf16x8*)(dst + (size_t)(rowb + r)*64 + c8*8) = v;
    }
  };

  runL(0, 0); tileWrite(true); tileReadA();
  runL(1, 1); tileWrite(true); tileReadA();
  runL(2, 2); tileWrite(true); tileReadA();      // a0/a1 = hidden A-frags
  __syncthreads();
  stage3(m2, L2E);                               // Wq scaled by log2(e)
  __syncthreads();

  runL(0, 3); tileWrite(false); storeBF(qb);     // q (bf16, L2E-scaled)
  runL(1, 4); tileWrite(false); storeBF(kb);     // k (bf16)
  runL(2, 5);                                    // v
  {
    const int bi   = rowb >> 9;                  // batch
    const int key0 = (rowb & 511) + quad*4;
    #pragma unroll
    for (int nt = 0; nt < 4; ++nt) {
      #pragma unroll
      for (int r = 0; r < 4; ++r)
        feat[(size_t)(rowb + quad*4 + r)*128 + nt*16 + col] = acc[nt][r];
      uint32_t lo = (uint32_t)f2bf(acc[nt][0]) | ((uint32_t)f2bf(acc[nt][1]) << 16);
      uint32_t hi = (uint32_t)f2bf(acc[nt][2]) | ((uint32_t)f2bf(acc[nt][3]) << 16);
      uint2 pk; pk.x = lo; pk.y = hi;
      *(uint2*)(vt + ((size_t)bi*64 + nt*16 + col)*512 + key0) = pk;
    }
  }
}

// ---------------------------------------------------------------------------
// MFMA attention (reverted to bm-reading version — R4 fusion regressed)
__global__ __launch_bounds__(256) void attn_kernel(
    const unsigned short* __restrict__ qg, const unsigned short* __restrict__ kg,
    const unsigned short* __restrict__ vt,
    const uint32_t* __restrict__ bm, float* __restrict__ feat)
{
  __shared__ short    Ks[128*72];      // 18.0 KB
  __shared__ short    Vt[64*136];      // 17.0 KB
  __shared__ short    Pl[4][16*32];    // 4 KB, per-wave
  __shared__ uint32_t Ms[4][256];      // 4 KB, per-wave mask words

  const int tid  = threadIdx.x;
  const int lane = tid & 63;
  const int wv   = tid >> 6;
  const int quad = lane >> 4;
  const int col  = lane & 15;

  const int b     = blockIdx.x >> 3;
  const int q0    = (blockIdx.x & 7) * 64;
  const int qbase = b*512 + q0 + wv*16;

  bf16x8 qa[2];
  qa[0] = *(const bf16x8*)(qg + (size_t)(qbase + col)*64 + quad*8);
  qa[1] = *(const bf16x8*)(qg + (size_t)(qbase + col)*64 + quad*8 + 32);

  #pragma unroll
  for (int w = 0; w < 4; ++w)
    Ms[wv][w*64 + lane] = bm[(size_t)qbase*16 + w*64 + lane];

  f32x4 o_acc[4];
  #pragma unroll
  for (int nt = 0; nt < 4; ++nt)
    #pragma unroll
    for (int r = 0; r < 4; ++r) o_acc[nt][r] = 0.f;
  float l_part[4] = {0.f, 0.f, 0.f, 0.f};

  const unsigned short* vtb = vt + (size_t)b*64*512;

  for (int c = 0; c < 4; ++c) {
    __syncthreads();
    {
      const int kb_ = b*512 + c*128;
      // K chunk: bf16 [key][dim] stride 72
      #pragma unroll
      for (int i = 0; i < 4; ++i) {
        int p = i*256 + tid;
        int key = p >> 3, c8 = p & 7;
        bf16x8 kv = *(const bf16x8*)(kg + (size_t)(kb_ + key)*64 + c8*8);
        *(bf16x8*)(Ks + key*72 + c8*8) = kv;
      }
      // V^T chunk: bf16 [dim][key] stride 136 — pure copies
      #pragma unroll
      for (int i = 0; i < 4; ++i) {
        int p = i*256 + tid;
        int dim = p >> 4, k8 = p & 15;
        bf16x8 vv = *(const bf16x8*)(vtb + (size_t)dim*512 + c*128 + k8*8);
        *(bf16x8*)(Vt + dim*136 + k8*8) = vv;
      }
    }
    __syncthreads();

    for (int kc = 0; kc < 4; ++kc) {
      #pragma unroll
      for (int t = 0; t < 2; ++t) {
        const int kt = kc*2 + t;
        f32x4 s_acc;
        #pragma unroll
        for (int r = 0; r < 4; ++r) s_acc[r] = 0.f;
        const short* kp = Ks + (kt*16 + col)*72 + quad*8;
        bf16x8 kb0 = *(const bf16x8*)(kp);
        bf16x8 kb1 = *(const bf16x8*)(kp + 32);
        s_acc = __builtin_amdgcn_mfma_f32_16x16x32_bf16(qa[0], kb0, s_acc, 0,0,0);
        s_acc = __builtin_amdgcn_mfma_f32_16x16x32_bf16(qa[1], kb1, s_acc, 0,0,0);
        const int kcol = ((t*16 + col) ^ (quad*8));
        #pragma unroll
        for (int r = 0; r < 4; ++r) {
          uint32_t mw = Ms[wv][(quad*4+r)*16 + c*4 + (kt>>1)];
          float p = ((mw >> ((kt&1)*16 + col)) & 1u)
                      ? exp2f_(fminf(s_acc[r], 43.f)) : 0.f;   // s pre-scaled
          l_part[r] += p;
          Pl[wv][(quad*4+r)*32 + kcol] = (short)f2bf(p);
        }
      }
      bf16x8 pa = *(const bf16x8*)(&Pl[wv][col*32 + ((quad*8) ^ (((col)>>2)*8))]);
      #pragma unroll
      for (int nt = 0; nt < 4; ++nt) {
        bf16x8 vb = *(const bf16x8*)(&Vt[(nt*16+col)*136 + kc*32 + quad*8]);
        o_acc[nt] = __builtin_amdgcn_mfma_f32_16x16x32_bf16(pa, vb, o_acc[nt], 0,0,0);
      }
    }
  }

  float inv[4];
  #pragma unroll
  for (int r = 0; r < 4; ++r) {
    float v = l_part[r];
    v += __shfl_xor(v, 1);
    v += __shfl_xor(v, 2);
    v += __shfl_xor(v, 4);
    v += __shfl_xor(v, 8);
    inv[r] = rcpf_(fmaxf(v, 1e-20f));
  }

  #pragma unroll
  for (int nt = 0; nt < 4; ++nt)
    #pragma unroll
    for (int r = 0; r < 4; ++r)
      feat[(size_t)(qbase + quad*4 + r)*128 + 64 + nt*16 + col] = o_acc[nt][r]*inv[r];
}

// ---------------------------------------------------------------------------
// MFMA forecast: out[16rows][24] = feat[16x128]@Wf^T + bf per wave.
__global__ __launch_bounds__(256) void forecast_kernel(
    const float* __restrict__ feat, const float* __restrict__ Wf,
    const float* __restrict__ bf, float* __restrict__ out)
{
  __shared__ short Wfr[8*512];         // 8 KB B-frags
  __shared__ float bl[32];

  const int tid  = threadIdx.x;
  const int lane = tid & 63;
  const int wv   = tid >> 6;
  const int quad = lane >> 4;
  const int col  = lane & 15;
  const int rowb = blockIdx.x*64 + wv*16;

  #pragma unroll
  for (int i = 0; i < 2; ++i) {
    int p = i*256 + tid;               // 512 (frag,lane) entries
    int f = p >> 6, l = p & 63;
    int kc = f >> 1, nt = f & 1;
    int lq = l >> 4, lc = l & 15;
    int n = nt*16 + lc;
    bf16x8 v;
    #pragma unroll
    for (int j = 0; j < 8; ++j) v[j] = 0;
    if (n < 24) {
      const float* src = Wf + (size_t)n*128 + kc*32 + lq*8;
      #pragma unroll
      for (int j = 0; j < 8; ++j) v[j] = (short)f2bf(src[j]);
    }
    *(bf16x8*)(Wfr + f*512 + l*8) = v;
  }
  if (tid < 32) bl[tid] = (tid < 24) ? bf[tid] : 0.f;
  __syncthreads();

  // A-frags: my row (rowb+col), 4 k32 chunks
  bf16x8 af[4];
  const float* fr = feat + (size_t)(rowb + col)*128;
  #pragma unroll
  for (int kc = 0; kc < 4; ++kc) {
    float4 f0 = *(const float4*)(fr + kc*32 + quad*8);
    float4 f1 = *(const float4*)(fr + kc*32 + quad*8 + 4);
    af[kc][0]=(short)f2bf(f0.x); af[kc][1]=(short)f2bf(f0.y);
    af[kc][2]=(short)f2bf(f0.z); af[kc][3]=(short)f2bf(f0.w);
    af[kc][4]=(short)f2bf(f1.x); af[kc][5]=(short)f2bf(f1.y);
    af[kc][6]=(short)f2bf(f1.z); af[kc][7]=(short)f2bf(f1.w);
  }

  f32x4 acc[2];
  #pragma unroll
  for (int nt = 0; nt < 2; ++nt) {
    float bb = bl[nt*16 + col];
    acc[nt][0] = bb; acc[nt][1] = bb; acc[nt][2] = bb; acc[nt][3] = bb;
  }
  #pragma unroll
  for (int kc = 0; kc < 4; ++kc) {
    #pragma unroll
    for (int nt = 0; nt < 2; ++nt) {
      bf16x8 b = *(const bf16x8*)(Wfr + (kc*2+nt)*512 + lane*8);
      acc[nt] = __builtin_amdgcn_mfma_f32_16x16x32_bf16(af[kc], b, acc[nt], 0,0,0);
    }
  }

  #pragma unroll
  for (int nt = 0; nt < 2; ++nt) {
    int n = nt*16 + col;
    if (n < 24) {
      #pragma unroll
      for (int r = 0; r < 4; ++r)
        out[(size_t)(rowb + quad*4 + r)*24 + n] = acc[nt][r];
    }
  }
}

// ---------------------------------------------------------------------------
extern "C" void kernel_launch(void* const* d_in, const int* in_sizes, int n_in,
                              void* d_out, int out_size, void* d_ws, size_t ws_size,
                              hipStream_t stream)
{
  const float* obs = (const float*)d_in[0];
  const int*   pm  = (const int*)  d_in[1];
  const float* nhm = (const float*)d_in[2];
  const float* Wih = (const float*)d_in[3];
  const float* Whh = (const float*)d_in[4];
  const float* bih = (const float*)d_in[5];
  const float* bhh = (const float*)d_in[6];
  const float* W1  = (const float*)d_in[7];
  const float* b1  = (const float*)d_in[8];
  const float* W2  = (const float*)d_in[9];
  const float* b2  = (const float*)d_in[10];
  const float* Wh  = (const float*)d_in[11];
  const float* bh  = (const float*)d_in[12];
  const float* Wq  = (const float*)d_in[13];
  const float* bq  = (const float*)d_in[14];
  const float* Wk  = (const float*)d_in[15];
  const float* bk  = (const float*)d_in[16];
  const float* Wv  = (const float*)d_in[17];
  const float* bv  = (const float*)d_in[18];
  const float* Wf  = (const float*)d_in[19];
  const float* bf  = (const float*)d_in[20];

  float* out  = (float*)d_out;                 // forecast: 65536*24
  float* feat = out + (size_t)M_*24;           // feat:     65536*128

  // workspace: he(8MB) | qb(8MB) | kb(8MB) | vt(8MB) | bitmask(4.2MB)
  char* ws = (char*)d_ws;
  unsigned short* he  = (unsigned short*)(ws);
  unsigned short* qbf = (unsigned short*)(ws + (size_t) 8*1024*1024);
  unsigned short* kbf = (unsigned short*)(ws + (size_t)16*1024*1024);
  unsigned short* vtb = (unsigned short*)(ws + (size_t)24*1024*1024);
  uint32_t*       bmw = (uint32_t*)      (ws + (size_t)32*1024*1024);

  lstm_kernel<<<M_/128, 512, 0, stream>>>(obs, nhm, Wih, Whh, bih, bhh, he,
                                          (const int4*)pm, bmw);
  mlp_kernel<<<M_/64, 256, 0, stream>>>(he, W1,b1, W2,b2, Wh,bh, Wq,bq, Wk,bk, Wv,bv,
                                        qbf, kbf, vtb, feat);
  attn_kernel<<<M_/64, 256, 0, stream>>>(qbf, kbf, vtb, bmw, feat);
  forecast_kernel<<<M_/64, 256, 0, stream>>>(feat, Wf, bf, out);
}

// Round 6
// 318.742 us; speedup vs baseline: 1.1244x; 1.0048x over previous
//
#include <hip/hip_runtime.h>
#include <hip/hip_bf16.h>
#include <stdint.h>

#define B_ 128
#define N_ 512
#define S_ 8
#define H_ 64
#define M_ (B_*N_)          // 65536 rows
#define L2E 1.442695041f

typedef __attribute__((ext_vector_type(8))) short bf16x8;
typedef __attribute__((ext_vector_type(4))) float f32x4;

__device__ __forceinline__ float exp2f_(float x) { return __builtin_amdgcn_exp2f(x); }
__device__ __forceinline__ float rcpf_(float x)  { return __builtin_amdgcn_rcpf(x); }
// x pre-scaled by log2(e):  sig2(x) == sigmoid(x / L2E)   (v_exp + v_rcp only)
__device__ __forceinline__ float sig2(float x)  { return rcpf_(1.f + exp2f_(-x)); }
// x pre-scaled by 2*log2(e): tanh2(x) == tanh(x / (2*L2E))
__device__ __forceinline__ float tanh2(float x) { return 1.f - 2.f*rcpf_(exp2f_(x) + 1.f); }
// fp32 -> bf16 round-to-nearest-even
__device__ __forceinline__ unsigned short f2bf(float x) {
  unsigned int u = __float_as_uint(x);
  u += 0x7fffu + ((u >> 16) & 1u);
  return (unsigned short)(u >> 16);
}

// ---------------------------------------------------------------------------
// MFMA LSTM v8 = v7 + LDS diet for 3 blocks/CU.
//  - x_pk and len_s LDS buffers removed: every lane computes x/len for row
//    w16+(lane&15) redundantly across quads, so the quad0 consumer lane IS
//    the producer lane. x lives in an 8-register rotate queue (static
//    indices only); lenr comes from a wave-local __shfl(len, quad*4+r).
//  - LDS 57856 -> 53248 B: 3 blocks/CU (was 2) -> 24 waves/CU, +50% TLP
//    for the same VALU/trans/LDS/pm-load latency mix (VGPR=52, RF allows 8).
//  - pm bit-pack fused per t-step as in v7 (4 coalesced int4 loads after the
//    MFMA/gate phase; nibble-pack + 3x shfl_xor OR; lane&7==0 stores).
__global__ __launch_bounds__(512, 4) void lstm_kernel(
    const float* __restrict__ obs, const float* __restrict__ nhm,
    const float* __restrict__ Wih, const float* __restrict__ Whh,
    const float* __restrict__ bih, const float* __restrict__ bhh,
    unsigned short* __restrict__ he,
    const int4* __restrict__ pm4, uint32_t* __restrict__ bm)
{
  __shared__ short    Wfrag[32*512];   // 32 KB  Whh B-frags (bf16, gate-scaled)
  __shared__ short    Wxc[1024];       // 2 KB   compact [Wih0,Wih1,bias,0] per n
  __shared__ short    h_s[128*72];     // 18 KB  bf16, stride 72
  // total LDS = 53248 B -> 3 blocks/CU

  const int tid  = threadIdx.x;
  const int lane = tid & 63;
  const int wv   = tid >> 6;           // 0..7
  const int w16  = wv * 16;
  const int quad = lane >> 4;
  const int col  = lane & 15;
  const int row0 = blockIdx.x * 128;

  // pm strip for this wave: 256 words = 2048 int4
  const int     wb  = (blockIdx.x*8 + wv) * 256;       // word base
  const int4*   pw  = pm4 + (size_t)wb * 8;            // int4 base
  const int     shp = (lane & 7) * 4;                  // nibble shift

  // ---- stage Whh as bf16 B-fragments (gate-scaled), 2048 (frag,lane) entries
  #pragma unroll
  for (int i = 0; i < 4; ++i) {
    int p = i*512 + tid;
    int f = p >> 6, l = p & 63;
    int t16 = f >> 1, s = f & 1;
    int lq = l >> 4, lc = l & 15;
    const float sc = (t16 >= 8 && t16 < 12) ? (2.f*L2E) : L2E;
    const float* src = Whh + (size_t)(t16*16 + lc)*64 + s*32 + lq*8;
    short* dst = Wfrag + f*512 + l*8;
    #pragma unroll
    for (int j = 0; j < 8; ++j) dst[j] = (short)f2bf(src[j] * sc);
  }
  // ---- stage compact Wx: Wxc[t16*64 + cc*4 + k], k: 0=Wih0 1=Wih1 2=bias ----
  if (tid < 256) {
    int t16 = tid >> 4, cc = tid & 15;
    int n = t16*16 + cc;
    const float sc = (t16 >= 8 && t16 < 12) ? (2.f*L2E) : L2E;
    short* d = Wxc + t16*64 + cc*4;
    d[0] = (short)f2bf(Wih[2*n + 0] * sc);
    d[1] = (short)f2bf(Wih[2*n + 1] * sc);
    d[2] = (short)f2bf((bih[n] + bhh[n]) * sc);
    d[3] = 0;
  }

  // zero h_s (4608 dwords)
  #pragma unroll
  for (int i = 0; i < 9; ++i) ((uint32_t*)h_s)[i*512 + tid] = 0u;

  // ---- per-lane x prep for row (w16+col); all quads redundant, so each
  //      consumer lane already holds its own value. Registers, no LDS.
  uint32_t xq0, xq1, xq2, xq3, xq4, xq5, xq6, xq7;
  int len;
  {
    const int grow = row0 + w16 + col;
    float xv0[8], xv1[8];
    int lzi = -1;
    #pragma unroll
    for (int t = 0; t < 8; ++t) {
      float m = nhm[(size_t)grow*8 + t];
      float a = obs[((size_t)grow*8 + t)*2 + 0] * m;
      float b = obs[((size_t)grow*8 + t)*2 + 1] * m;
      xv0[t] = a; xv1[t] = b;
      if (a == 0.f) lzi = t;
    }
    uint32_t xr[8];
    #pragma unroll
    for (int t = 0; t < 8; ++t) {
      bool kill = (t < lzi);
      float a = kill ? 0.f : xv0[t];
      float b = kill ? 0.f : xv1[t];
      xr[t] = (uint32_t)f2bf(a) | ((uint32_t)f2bf(b) << 16);
    }
    xq0 = xr[0]; xq1 = xr[1]; xq2 = xr[2]; xq3 = xr[3];
    xq4 = xr[4]; xq5 = xr[5]; xq6 = xr[6]; xq7 = xr[7];
    len = 7 - lzi; if (len < 1) len = 1;
  }
  int lenr[4];
  #pragma unroll
  for (int r = 0; r < 4; ++r) lenr[r] = __shfl(len, quad*4 + r);

  __syncthreads();     // the ONLY barrier (covers Wfrag, Wxc, h_s zero)

  float c_[16];
  #pragma unroll
  for (int i = 0; i < 16; ++i) c_[i] = 0.f;

  const f32x4 zero4 = {0.f, 0.f, 0.f, 0.f};
  const bool q0 = (quad == 0);

  #pragma unroll 1
  for (int t = 0; t < 8; ++t) {
    // ---- A-frag for the x/bias MFMA: [x0, x1, 1, 0...] on quad 0 ----
    uint32_t xw = xq0;
    // rotate queue (static indices; stays in registers)
    xq0 = xq1; xq1 = xq2; xq2 = xq3; xq3 = xq4;
    xq4 = xq5; xq5 = xq6; xq6 = xq7;

    union { bf16x8 v; uint32_t u[4]; } ax;
    ax.u[0] = q0 ? xw : 0u;
    ax.u[1] = q0 ? 0x00003f80u : 0u;    // bf16(1.0) at k==2
    ax.u[2] = 0u; ax.u[3] = 0u;

    // A-frags of h (bf16, no converts)
    bf16x8 a0 = *(const bf16x8*)(h_s + (w16 + col)*72 + quad*8);
    bf16x8 a1 = *(const bf16x8*)(h_s + (w16 + col)*72 + 32 + quad*8);

    // 4 column-groups: tiles {cc, cc+4, cc+8, cc+12} = i,f,g,o for cells
    // n = cc*16+col. Only 4 accumulators live at a time.
    #pragma unroll
    for (int cc = 0; cc < 4; ++cc) {
      f32x4 acc[4];
      #pragma unroll
      for (int g = 0; g < 4; ++g) {
        const int t16 = g*4 + cc;
        union { bf16x8 v; uint32_t u[4]; } wx;
        uint2 d = *(const uint2*)(Wxc + t16*64 + col*4);  // always initialized
        wx.u[0] = q0 ? d.x : 0u;        // zero fragment on non-quad0 lanes
        wx.u[1] = q0 ? d.y : 0u;
        wx.u[2] = 0u; wx.u[3] = 0u;
        bf16x8 b0 = *(const bf16x8*)(Wfrag + (t16*2+0)*512 + lane*8);
        bf16x8 b1 = *(const bf16x8*)(Wfrag + (t16*2+1)*512 + lane*8);
        acc[g] = __builtin_amdgcn_mfma_f32_16x16x32_bf16(ax.v, wx.v, zero4, 0, 0, 0);
        acc[g] = __builtin_amdgcn_mfma_f32_16x16x32_bf16(a0, b0, acc[g], 0, 0, 0);
        acc[g] = __builtin_amdgcn_mfma_f32_16x16x32_bf16(a1, b1, acc[g], 0, 0, 0);
      }
      #pragma unroll
      for (int r = 0; r < 4; ++r) {
        if (t < lenr[r]) {
          float gi = acc[0][r];
          float gf = acc[1][r];
          float gg = acc[2][r];
          float go = acc[3][r];
          float cn = sig2(gf)*c_[cc*4+r] + sig2(gi)*tanh2(gg);
          c_[cc*4+r] = cn;
          h_s[(w16 + quad*4 + r)*72 + cc*16 + col] =
              (short)f2bf(sig2(go)*tanh2(cn*(2.f*L2E)));
        }
      }
      __builtin_amdgcn_sched_barrier(0);  // pin group: keep acc lifetime short
    }

    // ---- fused pad_mask pack: 4 coalesced int4 loads per step ----
    // int4 idx = t*256 + jj*64 + lane; word = wb + t*32 + jj*8 + lane/8.
    {
      const int4* ps = pw + t*256 + lane;
      int4 v0 = ps[0];
      int4 v1 = ps[64];
      int4 v2 = ps[128];
      int4 v3 = ps[192];
      int4 vv[4] = {v0, v1, v2, v3};
      #pragma unroll
      for (int jj = 0; jj < 4; ++jj) {
        int4 v = vv[jj];
        uint32_t nib = (v.x != 0 ? 1u : 0u)
                     | (v.y != 0 ? 2u : 0u)
                     | (v.z != 0 ? 4u : 0u)
                     | (v.w != 0 ? 8u : 0u);
        uint32_t x = nib << shp;
        x |= __shfl_xor(x, 1);
        x |= __shfl_xor(x, 2);
        x |= __shfl_xor(x, 4);
        if ((lane & 7) == 0)
          bm[wb + t*32 + jj*8 + (lane >> 3)] = x;
      }
      __builtin_amdgcn_sched_barrier(0);  // keep pm block out of next step's MFMA region
    }
    // no per-step barrier: each wave owns its 16 h rows
  }

  // he = relu(h) bf16, wave-local b128 stores
  #pragma unroll
  for (int s = 0; s < 2; ++s) {
    int chunk = s*64 + lane;          // 128 chunks of 8 shorts per wave
    int rl = chunk >> 3, c8 = chunk & 7;
    bf16x8 v = *(const bf16x8*)(h_s + (w16 + rl)*72 + c8*8);
    #pragma unroll
    for (int j = 0; j < 8; ++j) {
      short sv = v[j];
      v[j] = (sv & (short)0x8000) ? (short)0 : sv;   // relu (handles -0.0)
    }
    *(bf16x8*)(he + (size_t)(row0 + w16 + rl)*64 + c8*8) = v;
  }
}

// ---------------------------------------------------------------------------
// MFMA MLP (unchanged)
__global__ __launch_bounds__(256) void mlp_kernel(
    const unsigned short* __restrict__ he,
    const float* __restrict__ W1, const float* __restrict__ b1,
    const float* __restrict__ W2, const float* __restrict__ b2,
    const float* __restrict__ Wh, const float* __restrict__ bh,
    const float* __restrict__ Wq, const float* __restrict__ bq,
    const float* __restrict__ Wk, const float* __restrict__ bk,
    const float* __restrict__ Wv, const float* __restrict__ bv,
    unsigned short* __restrict__ qb, unsigned short* __restrict__ kb,
    unsigned short* __restrict__ vt, float* __restrict__ feat)
{
  __shared__ short Wm[3][8*512];       // 24 KB B-frags
  __shared__ float bias_s[6*64];       // 1.5 KB
  __shared__ short Atile[4][16*76];    // 9.5 KB per-wave relayout tiles

  const int tid  = threadIdx.x;
  const int lane = tid & 63;
  const int wv   = tid >> 6;
  const int quad = lane >> 4;
  const int col  = lane & 15;
  const int rowb = blockIdx.x*64 + wv*16;

  const float* m1[3] = {W1, W2, Wh};
  const float* m2[3] = {Wq, Wk, Wv};
  auto stage3 = [&](const float* const* mats, float sc0) {
    #pragma unroll
    for (int i = 0; i < 6; ++i) {
      int p = i*256 + tid;
      int m = p >> 9, rem = p & 511;
      int f = rem >> 6, l = rem & 63;
      int nt = f >> 1, s = f & 1;
      int lq = l >> 4, lc = l & 15;
      float sc = (m == 0) ? sc0 : 1.f;
      const float* src = mats[m] + (size_t)(nt*16 + lc)*64 + s*32 + lq*8;
      short* dst = &Wm[m][f*512 + l*8];
      #pragma unroll
      for (int j = 0; j < 8; ++j) dst[j] = (short)f2bf(src[j] * sc);
    }
  };
  stage3(m1, 1.f);
  {
    const float* bs[6] = {b1, b2, bh, bq, bk, bv};
    for (int i = tid; i < 384; i += 256) {
      float sc = ((i >> 6) == 3) ? L2E : 1.f;      // bq scaled by log2(e)
      bias_s[i] = bs[i>>6][i & 63] * sc;
    }
  }
  __syncthreads();

  bf16x8 a0 = *(const bf16x8*)(he + (size_t)(rowb + col)*64 + quad*8);
  bf16x8 a1 = *(const bf16x8*)(he + (size_t)(rowb + col)*64 + quad*8 + 32);

  f32x4 acc[4];
  auto runL = [&](int m, int bidx) {
    #pragma unroll
    for (int nt = 0; nt < 4; ++nt) {
      float bb = bias_s[bidx*64 + nt*16 + col];
      acc[nt][0] = bb; acc[nt][1] = bb; acc[nt][2] = bb; acc[nt][3] = bb;
    }
    #pragma unroll
    for (int nt = 0; nt < 4; ++nt) {
      bf16x8 bf0 = *(const bf16x8*)(&Wm[m][(nt*2+0)*512 + lane*8]);
      bf16x8 bf1 = *(const bf16x8*)(&Wm[m][(nt*2+1)*512 + lane*8]);
      acc[nt] = __builtin_amdgcn_mfma_f32_16x16x32_bf16(a0, bf0, acc[nt], 0,0,0);
      acc[nt] = __builtin_amdgcn_mfma_f32_16x16x32_bf16(a1, bf1, acc[nt], 0,0,0);
    }
  };
  auto tileWrite = [&](bool relu) {
    #pragma unroll
    for (int nt = 0; nt < 4; ++nt)
      #pragma unroll
      for (int r = 0; r < 4; ++r) {
        float v = relu ? fmaxf(acc[nt][r], 0.f) : acc[nt][r];
        Atile[wv][(quad*4+r)*76 + ((nt*16+col) ^ (r*16))] = (short)f2bf(v);
      }
  };
  auto tileReadA = [&]() {
    int sw = (col & 3) * 16;
    a0 = *(const bf16x8*)(&Atile[wv][col*76 + ((quad*8     ) ^ sw)]);
    a1 = *(const bf16x8*)(&Atile[wv][col*76 + ((quad*8 + 32) ^ sw)]);
  };
  auto storeBF = [&](unsigned short* dst) {
    #pragma unroll
    for (int s = 0; s < 2; ++s) {
      int chunk = s*64 + lane;
      int r = chunk >> 3, c8 = chunk & 7;
      bf16x8 v = *(const bf16x8*)(&Atile[wv][r*76 + ((c8*8) ^ ((r&3)*16))]);
      *(bf16x8*)(dst + (size_t)(rowb + r)*64 + c8*8) = v;
    }
  };

  runL(0, 0); tileWrite(true); tileReadA();
  runL(1, 1); tileWrite(true); tileReadA();
  runL(2, 2); tileWrite(true); tileReadA();      // a0/a1 = hidden A-frags
  __syncthreads();
  stage3(m2, L2E);                               // Wq scaled by log2(e)
  __syncthreads();

  runL(0, 3); tileWrite(false); storeBF(qb);     // q (bf16, L2E-scaled)
  runL(1, 4); tileWrite(false); storeBF(kb);     // k (bf16)
  runL(2, 5);                                    // v
  {
    const int bi   = rowb >> 9;                  // batch
    const int key0 = (rowb & 511) + quad*4;
    #pragma unroll
    for (int nt = 0; nt < 4; ++nt) {
      #pragma unroll
      for (int r = 0; r < 4; ++r)
        feat[(size_t)(rowb + quad*4 + r)*128 + nt*16 + col] = acc[nt][r];
      uint32_t lo = (uint32_t)f2bf(acc[nt][0]) | ((uint32_t)f2bf(acc[nt][1]) << 16);
      uint32_t hi = (uint32_t)f2bf(acc[nt][2]) | ((uint32_t)f2bf(acc[nt][3]) << 16);
      uint2 pk; pk.x = lo; pk.y = hi;
      *(uint2*)(vt + ((size_t)bi*64 + nt*16 + col)*512 + key0) = pk;
    }
  }
}

// ---------------------------------------------------------------------------
// MFMA attention (unchanged)
__global__ __launch_bounds__(256) void attn_kernel(
    const unsigned short* __restrict__ qg, const unsigned short* __restrict__ kg,
    const unsigned short* __restrict__ vt,
    const uint32_t* __restrict__ bm, float* __restrict__ feat)
{
  __shared__ short    Ks[128*72];      // 18.0 KB
  __shared__ short    Vt[64*136];      // 17.0 KB
  __shared__ short    Pl[4][16*32];    // 4 KB, per-wave
  __shared__ uint32_t Ms[4][256];      // 4 KB, per-wave mask words

  const int tid  = threadIdx.x;
  const int lane = tid & 63;
  const int wv   = tid >> 6;
  const int quad = lane >> 4;
  const int col  = lane & 15;

  const int b     = blockIdx.x >> 3;
  const int q0    = (blockIdx.x & 7) * 64;
  const int qbase = b*512 + q0 + wv*16;

  bf16x8 qa[2];
  qa[0] = *(const bf16x8*)(qg + (size_t)(qbase + col)*64 + quad*8);
  qa[1] = *(const bf16x8*)(qg + (size_t)(qbase + col)*64 + quad*8 + 32);

  #pragma unroll
  for (int w = 0; w < 4; ++w)
    Ms[wv][w*64 + lane] = bm[(size_t)qbase*16 + w*64 + lane];

  f32x4 o_acc[4];
  #pragma unroll
  for (int nt = 0; nt < 4; ++nt)
    #pragma unroll
    for (int r = 0; r < 4; ++r) o_acc[nt][r] = 0.f;
  float l_part[4] = {0.f, 0.f, 0.f, 0.f};

  const unsigned short* vtb = vt + (size_t)b*64*512;

  for (int c = 0; c < 4; ++c) {
    __syncthreads();
    {
      const int kb_ = b*512 + c*128;
      // K chunk: bf16 [key][dim] stride 72
      #pragma unroll
      for (int i = 0; i < 4; ++i) {
        int p = i*256 + tid;
        int key = p >> 3, c8 = p & 7;
        bf16x8 kv = *(const bf16x8*)(kg + (size_t)(kb_ + key)*64 + c8*8);
        *(bf16x8*)(Ks + key*72 + c8*8) = kv;
      }
      // V^T chunk: bf16 [dim][key] stride 136 — pure copies
      #pragma unroll
      for (int i = 0; i < 4; ++i) {
        int p = i*256 + tid;
        int dim = p >> 4, k8 = p & 15;
        bf16x8 vv = *(const bf16x8*)(vtb + (size_t)dim*512 + c*128 + k8*8);
        *(bf16x8*)(Vt + dim*136 + k8*8) = vv;
      }
    }
    __syncthreads();

    for (int kc = 0; kc < 4; ++kc) {
      #pragma unroll
      for (int t = 0; t < 2; ++t) {
        const int kt = kc*2 + t;
        f32x4 s_acc;
        #pragma unroll
        for (int r = 0; r < 4; ++r) s_acc[r] = 0.f;
        const short* kp = Ks + (kt*16 + col)*72 + quad*8;
        bf16x8 kb0 = *(const bf16x8*)(kp);
        bf16x8 kb1 = *(const bf16x8*)(kp + 32);
        s_acc = __builtin_amdgcn_mfma_f32_16x16x32_bf16(qa[0], kb0, s_acc, 0,0,0);
        s_acc = __builtin_amdgcn_mfma_f32_16x16x32_bf16(qa[1], kb1, s_acc, 0,0,0);
        const int kcol = ((t*16 + col) ^ (quad*8));
        #pragma unroll
        for (int r = 0; r < 4; ++r) {
          uint32_t mw = Ms[wv][(quad*4+r)*16 + c*4 + (kt>>1)];
          float p = ((mw >> ((kt&1)*16 + col)) & 1u)
                      ? exp2f_(fminf(s_acc[r], 43.f)) : 0.f;   // s pre-scaled
          l_part[r] += p;
          Pl[wv][(quad*4+r)*32 + kcol] = (short)f2bf(p);
        }
      }
      bf16x8 pa = *(const bf16x8*)(&Pl[wv][col*32 + ((quad*8) ^ (((col)>>2)*8))]);
      #pragma unroll
      for (int nt = 0; nt < 4; ++nt) {
        bf16x8 vb = *(const bf16x8*)(&Vt[(nt*16+col)*136 + kc*32 + quad*8]);
        o_acc[nt] = __builtin_amdgcn_mfma_f32_16x16x32_bf16(pa, vb, o_acc[nt], 0,0,0);
      }
    }
  }

  float inv[4];
  #pragma unroll
  for (int r = 0; r < 4; ++r) {
    float v = l_part[r];
    v += __shfl_xor(v, 1);
    v += __shfl_xor(v, 2);
    v += __shfl_xor(v, 4);
    v += __shfl_xor(v, 8);
    inv[r] = rcpf_(fmaxf(v, 1e-20f));
  }

  #pragma unroll
  for (int nt = 0; nt < 4; ++nt)
    #pragma unroll
    for (int r = 0; r < 4; ++r)
      feat[(size_t)(qbase + quad*4 + r)*128 + 64 + nt*16 + col] = o_acc[nt][r]*inv[r];
}

// ---------------------------------------------------------------------------
// MFMA forecast: out[16rows][24] = feat[16x128]@Wf^T + bf per wave.
__global__ __launch_bounds__(256) void forecast_kernel(
    const float* __restrict__ feat, const float* __restrict__ Wf,
    const float* __restrict__ bf, float* __restrict__ out)
{
  __shared__ short Wfr[8*512];         // 8 KB B-frags
  __shared__ float bl[32];

  const int tid  = threadIdx.x;
  const int lane = tid & 63;
  const int wv   = tid >> 6;
  const int quad = lane >> 4;
  const int col  = lane & 15;
  const int rowb = blockIdx.x*64 + wv*16;

  #pragma unroll
  for (int i = 0; i < 2; ++i) {
    int p = i*256 + tid;               // 512 (frag,lane) entries
    int f = p >> 6, l = p & 63;
    int kc = f >> 1, nt = f & 1;
    int lq = l >> 4, lc = l & 15;
    int n = nt*16 + lc;
    bf16x8 v;
    #pragma unroll
    for (int j = 0; j < 8; ++j) v[j] = 0;
    if (n < 24) {
      const float* src = Wf + (size_t)n*128 + kc*32 + lq*8;
      #pragma unroll
      for (int j = 0; j < 8; ++j) v[j] = (short)f2bf(src[j]);
    }
    *(bf16x8*)(Wfr + f*512 + l*8) = v;
  }
  if (tid < 32) bl[tid] = (tid < 24) ? bf[tid] : 0.f;
  __syncthreads();

  // A-frags: my row (rowb+col), 4 k32 chunks
  bf16x8 af[4];
  const float* fr = feat + (size_t)(rowb + col)*128;
  #pragma unroll
  for (int kc = 0; kc < 4; ++kc) {
    float4 f0 = *(const float4*)(fr + kc*32 + quad*8);
    float4 f1 = *(const float4*)(fr + kc*32 + quad*8 + 4);
    af[kc][0]=(short)f2bf(f0.x); af[kc][1]=(short)f2bf(f0.y);
    af[kc][2]=(short)f2bf(f0.z); af[kc][3]=(short)f2bf(f0.w);
    af[kc][4]=(short)f2bf(f1.x); af[kc][5]=(short)f2bf(f1.y);
    af[kc][6]=(short)f2bf(f1.z); af[kc][7]=(short)f2bf(f1.w);
  }

  f32x4 acc[2];
  #pragma unroll
  for (int nt = 0; nt < 2; ++nt) {
    float bb = bl[nt*16 + col];
    acc[nt][0] = bb; acc[nt][1] = bb; acc[nt][2] = bb; acc[nt][3] = bb;
  }
  #pragma unroll
  for (int kc = 0; kc < 4; ++kc) {
    #pragma unroll
    for (int nt = 0; nt < 2; ++nt) {
      bf16x8 b = *(const bf16x8*)(Wfr + (kc*2+nt)*512 + lane*8);
      acc[nt] = __builtin_amdgcn_mfma_f32_16x16x32_bf16(af[kc], b, acc[nt], 0,0,0);
    }
  }

  #pragma unroll
  for (int nt = 0; nt < 2; ++nt) {
    int n = nt*16 + col;
    if (n < 24) {
      #pragma unroll
      for (int r = 0; r < 4; ++r)
        out[(size_t)(rowb + quad*4 + r)*24 + n] = acc[nt][r];
    }
  }
}

// ---------------------------------------------------------------------------
extern "C" void kernel_launch(void* const* d_in, const int* in_sizes, int n_in,
                              void* d_out, int out_size, void* d_ws, size_t ws_size,
                              hipStream_t stream)
{
  const float* obs = (const float*)d_in[0];
  const int*   pm  = (const int*)  d_in[1];
  const float* nhm = (const float*)d_in[2];
  const float* Wih = (const float*)d_in[3];
  const float* Whh = (const float*)d_in[4];
  const float* bih = (const float*)d_in[5];
  const float* bhh = (const float*)d_in[6];
  const float* W1  = (const float*)d_in[7];
  const float* b1  = (const float*)d_in[8];
  const float* W2  = (const float*)d_in[9];
  const float* b2  = (const float*)d_in[10];
  const float* Wh  = (const float*)d_in[11];
  const float* bh  = (const float*)d_in[12];
  const float* Wq  = (const float*)d_in[13];
  const float* bq  = (const float*)d_in[14];
  const float* Wk  = (const float*)d_in[15];
  const float* bk  = (const float*)d_in[16];
  const float* Wv  = (const float*)d_in[17];
  const float* bv  = (const float*)d_in[18];
  const float* Wf  = (const float*)d_in[19];
  const float* bf  = (const float*)d_in[20];

  float* out  = (float*)d_out;                 // forecast: 65536*24
  float* feat = out + (size_t)M_*24;           // feat:     65536*128

  // workspace: he(8MB) | qb(8MB) | kb(8MB) | vt(8MB) | bitmask(4.2MB)
  char* ws = (char*)d_ws;
  unsigned short* he  = (unsigned short*)(ws);
  unsigned short* qbf = (unsigned short*)(ws + (size_t) 8*1024*1024);
  unsigned short* kbf = (unsigned short*)(ws + (size_t)16*1024*1024);
  unsigned short* vtb = (unsigned short*)(ws + (size_t)24*1024*1024);
  uint32_t*       bmw = (uint32_t*)      (ws + (size_t)32*1024*1024);

  lstm_kernel<<<M_/128, 512, 0, stream>>>(obs, nhm, Wih, Whh, bih, bhh, he,
                                          (const int4*)pm, bmw);
  mlp_kernel<<<M_/64, 256, 0, stream>>>(he, W1,b1, W2,b2, Wh,bh, Wq,bq, Wk,bk, Wv,bv,
                                        qbf, kbf, vtb, feat);
  attn_kernel<<<M_/64, 256, 0, stream>>>(qbf, kbf, vtb, bmw, feat);
  forecast_kernel<<<M_/64, 256, 0, stream>>>(feat, Wf, bf, out);
}

// Round 7
// 315.489 us; speedup vs baseline: 1.1360x; 1.0103x over previous
//
#include <hip/hip_runtime.h>
#include <hip/hip_bf16.h>
#include <stdint.h>

#define B_ 128
#define N_ 512
#define S_ 8
#define H_ 64
#define M_ (B_*N_)          // 65536 rows
#define L2E 1.442695041f

typedef __attribute__((ext_vector_type(8))) short bf16x8;
typedef __attribute__((ext_vector_type(4))) float f32x4;

__device__ __forceinline__ float exp2f_(float x) { return __builtin_amdgcn_exp2f(x); }
__device__ __forceinline__ float rcpf_(float x)  { return __builtin_amdgcn_rcpf(x); }
// x pre-scaled by log2(e):  sig2(x) == sigmoid(x / L2E)   (v_exp + v_rcp only)
__device__ __forceinline__ float sig2(float x)  { return rcpf_(1.f + exp2f_(-x)); }
// x pre-scaled by 2*log2(e): tanh2(x) == tanh(x / (2*L2E))
__device__ __forceinline__ float tanh2(float x) { return 1.f - 2.f*rcpf_(exp2f_(x) + 1.f); }
// fp32 -> bf16 round-to-nearest-even
__device__ __forceinline__ unsigned short f2bf(float x) {
  unsigned int u = __float_as_uint(x);
  u += 0x7fffu + ((u >> 16) & 1u);
  return (unsigned short)(u >> 16);
}

// ---------------------------------------------------------------------------
// MFMA LSTM v8 (unchanged from R6): pm bit-pack fused per t-step; x/len in
// registers; LDS 53248 B. Occupancy structurally capped at 2 blocks/CU by
// grid geometry (512 blocks / 256 CUs) — LDS diet kept for latency reasons.
__global__ __launch_bounds__(512, 4) void lstm_kernel(
    const float* __restrict__ obs, const float* __restrict__ nhm,
    const float* __restrict__ Wih, const float* __restrict__ Whh,
    const float* __restrict__ bih, const float* __restrict__ bhh,
    unsigned short* __restrict__ he,
    const int4* __restrict__ pm4, uint32_t* __restrict__ bm)
{
  __shared__ short    Wfrag[32*512];   // 32 KB  Whh B-frags (bf16, gate-scaled)
  __shared__ short    Wxc[1024];       // 2 KB   compact [Wih0,Wih1,bias,0] per n
  __shared__ short    h_s[128*72];     // 18 KB  bf16, stride 72

  const int tid  = threadIdx.x;
  const int lane = tid & 63;
  const int wv   = tid >> 6;           // 0..7
  const int w16  = wv * 16;
  const int quad = lane >> 4;
  const int col  = lane & 15;
  const int row0 = blockIdx.x * 128;

  // pm strip for this wave: 256 words = 2048 int4
  const int     wb  = (blockIdx.x*8 + wv) * 256;       // word base
  const int4*   pw  = pm4 + (size_t)wb * 8;            // int4 base
  const int     shp = (lane & 7) * 4;                  // nibble shift

  // ---- stage Whh as bf16 B-fragments (gate-scaled), 2048 (frag,lane) entries
  #pragma unroll
  for (int i = 0; i < 4; ++i) {
    int p = i*512 + tid;
    int f = p >> 6, l = p & 63;
    int t16 = f >> 1, s = f & 1;
    int lq = l >> 4, lc = l & 15;
    const float sc = (t16 >= 8 && t16 < 12) ? (2.f*L2E) : L2E;
    const float* src = Whh + (size_t)(t16*16 + lc)*64 + s*32 + lq*8;
    short* dst = Wfrag + f*512 + l*8;
    #pragma unroll
    for (int j = 0; j < 8; ++j) dst[j] = (short)f2bf(src[j] * sc);
  }
  // ---- stage compact Wx: Wxc[t16*64 + cc*4 + k], k: 0=Wih0 1=Wih1 2=bias ----
  if (tid < 256) {
    int t16 = tid >> 4, cc = tid & 15;
    int n = t16*16 + cc;
    const float sc = (t16 >= 8 && t16 < 12) ? (2.f*L2E) : L2E;
    short* d = Wxc + t16*64 + cc*4;
    d[0] = (short)f2bf(Wih[2*n + 0] * sc);
    d[1] = (short)f2bf(Wih[2*n + 1] * sc);
    d[2] = (short)f2bf((bih[n] + bhh[n]) * sc);
    d[3] = 0;
  }

  // zero h_s (4608 dwords)
  #pragma unroll
  for (int i = 0; i < 9; ++i) ((uint32_t*)h_s)[i*512 + tid] = 0u;

  // ---- per-lane x prep for row (w16+col); all quads redundant, so each
  //      consumer lane already holds its own value. Registers, no LDS.
  uint32_t xq0, xq1, xq2, xq3, xq4, xq5, xq6, xq7;
  int len;
  {
    const int grow = row0 + w16 + col;
    float xv0[8], xv1[8];
    int lzi = -1;
    #pragma unroll
    for (int t = 0; t < 8; ++t) {
      float m = nhm[(size_t)grow*8 + t];
      float a = obs[((size_t)grow*8 + t)*2 + 0] * m;
      float b = obs[((size_t)grow*8 + t)*2 + 1] * m;
      xv0[t] = a; xv1[t] = b;
      if (a == 0.f) lzi = t;
    }
    uint32_t xr[8];
    #pragma unroll
    for (int t = 0; t < 8; ++t) {
      bool kill = (t < lzi);
      float a = kill ? 0.f : xv0[t];
      float b = kill ? 0.f : xv1[t];
      xr[t] = (uint32_t)f2bf(a) | ((uint32_t)f2bf(b) << 16);
    }
    xq0 = xr[0]; xq1 = xr[1]; xq2 = xr[2]; xq3 = xr[3];
    xq4 = xr[4]; xq5 = xr[5]; xq6 = xr[6]; xq7 = xr[7];
    len = 7 - lzi; if (len < 1) len = 1;
  }
  int lenr[4];
  #pragma unroll
  for (int r = 0; r < 4; ++r) lenr[r] = __shfl(len, quad*4 + r);

  __syncthreads();     // the ONLY barrier (covers Wfrag, Wxc, h_s zero)

  float c_[16];
  #pragma unroll
  for (int i = 0; i < 16; ++i) c_[i] = 0.f;

  const f32x4 zero4 = {0.f, 0.f, 0.f, 0.f};
  const bool q0 = (quad == 0);

  #pragma unroll 1
  for (int t = 0; t < 8; ++t) {
    // ---- A-frag for the x/bias MFMA: [x0, x1, 1, 0...] on quad 0 ----
    uint32_t xw = xq0;
    // rotate queue (static indices; stays in registers)
    xq0 = xq1; xq1 = xq2; xq2 = xq3; xq3 = xq4;
    xq4 = xq5; xq5 = xq6; xq6 = xq7;

    union { bf16x8 v; uint32_t u[4]; } ax;
    ax.u[0] = q0 ? xw : 0u;
    ax.u[1] = q0 ? 0x00003f80u : 0u;    // bf16(1.0) at k==2
    ax.u[2] = 0u; ax.u[3] = 0u;

    // A-frags of h (bf16, no converts)
    bf16x8 a0 = *(const bf16x8*)(h_s + (w16 + col)*72 + quad*8);
    bf16x8 a1 = *(const bf16x8*)(h_s + (w16 + col)*72 + 32 + quad*8);

    // 4 column-groups: tiles {cc, cc+4, cc+8, cc+12} = i,f,g,o for cells
    // n = cc*16+col. Only 4 accumulators live at a time.
    #pragma unroll
    for (int cc = 0; cc < 4; ++cc) {
      f32x4 acc[4];
      #pragma unroll
      for (int g = 0; g < 4; ++g) {
        const int t16 = g*4 + cc;
        union { bf16x8 v; uint32_t u[4]; } wx;
        uint2 d = *(const uint2*)(Wxc + t16*64 + col*4);  // always initialized
        wx.u[0] = q0 ? d.x : 0u;        // zero fragment on non-quad0 lanes
        wx.u[1] = q0 ? d.y : 0u;
        wx.u[2] = 0u; wx.u[3] = 0u;
        bf16x8 b0 = *(const bf16x8*)(Wfrag + (t16*2+0)*512 + lane*8);
        bf16x8 b1 = *(const bf16x8*)(Wfrag + (t16*2+1)*512 + lane*8);
        acc[g] = __builtin_amdgcn_mfma_f32_16x16x32_bf16(ax.v, wx.v, zero4, 0, 0, 0);
        acc[g] = __builtin_amdgcn_mfma_f32_16x16x32_bf16(a0, b0, acc[g], 0, 0, 0);
        acc[g] = __builtin_amdgcn_mfma_f32_16x16x32_bf16(a1, b1, acc[g], 0, 0, 0);
      }
      #pragma unroll
      for (int r = 0; r < 4; ++r) {
        if (t < lenr[r]) {
          float gi = acc[0][r];
          float gf = acc[1][r];
          float gg = acc[2][r];
          float go = acc[3][r];
          float cn = sig2(gf)*c_[cc*4+r] + sig2(gi)*tanh2(gg);
          c_[cc*4+r] = cn;
          h_s[(w16 + quad*4 + r)*72 + cc*16 + col] =
              (short)f2bf(sig2(go)*tanh2(cn*(2.f*L2E)));
        }
      }
      __builtin_amdgcn_sched_barrier(0);  // pin group: keep acc lifetime short
    }

    // ---- fused pad_mask pack: 4 coalesced int4 loads per step ----
    // int4 idx = t*256 + jj*64 + lane; word = wb + t*32 + jj*8 + lane/8.
    {
      const int4* ps = pw + t*256 + lane;
      int4 v0 = ps[0];
      int4 v1 = ps[64];
      int4 v2 = ps[128];
      int4 v3 = ps[192];
      int4 vv[4] = {v0, v1, v2, v3};
      #pragma unroll
      for (int jj = 0; jj < 4; ++jj) {
        int4 v = vv[jj];
        uint32_t nib = (v.x != 0 ? 1u : 0u)
                     | (v.y != 0 ? 2u : 0u)
                     | (v.z != 0 ? 4u : 0u)
                     | (v.w != 0 ? 8u : 0u);
        uint32_t x = nib << shp;
        x |= __shfl_xor(x, 1);
        x |= __shfl_xor(x, 2);
        x |= __shfl_xor(x, 4);
        if ((lane & 7) == 0)
          bm[wb + t*32 + jj*8 + (lane >> 3)] = x;
      }
      __builtin_amdgcn_sched_barrier(0);  // keep pm block out of next step's MFMA region
    }
    // no per-step barrier: each wave owns its 16 h rows
  }

  // he = relu(h) bf16, wave-local b128 stores
  #pragma unroll
  for (int s = 0; s < 2; ++s) {
    int chunk = s*64 + lane;          // 128 chunks of 8 shorts per wave
    int rl = chunk >> 3, c8 = chunk & 7;
    bf16x8 v = *(const bf16x8*)(h_s + (w16 + rl)*72 + c8*8);
    #pragma unroll
    for (int j = 0; j < 8; ++j) {
      short sv = v[j];
      v[j] = (sv & (short)0x8000) ? (short)0 : sv;   // relu (handles -0.0)
    }
    *(bf16x8*)(he + (size_t)(row0 + w16 + rl)*64 + c8*8) = v;
  }
}

// ---------------------------------------------------------------------------
// MFMA MLP (unchanged)
__global__ __launch_bounds__(256) void mlp_kernel(
    const unsigned short* __restrict__ he,
    const float* __restrict__ W1, const float* __restrict__ b1,
    const float* __restrict__ W2, const float* __restrict__ b2,
    const float* __restrict__ Wh, const float* __restrict__ bh,
    const float* __restrict__ Wq, const float* __restrict__ bq,
    const float* __restrict__ Wk, const float* __restrict__ bk,
    const float* __restrict__ Wv, const float* __restrict__ bv,
    unsigned short* __restrict__ qb, unsigned short* __restrict__ kb,
    unsigned short* __restrict__ vt, float* __restrict__ feat)
{
  __shared__ short Wm[3][8*512];       // 24 KB B-frags
  __shared__ float bias_s[6*64];       // 1.5 KB
  __shared__ short Atile[4][16*76];    // 9.5 KB per-wave relayout tiles

  const int tid  = threadIdx.x;
  const int lane = tid & 63;
  const int wv   = tid >> 6;
  const int quad = lane >> 4;
  const int col  = lane & 15;
  const int rowb = blockIdx.x*64 + wv*16;

  const float* m1[3] = {W1, W2, Wh};
  const float* m2[3] = {Wq, Wk, Wv};
  auto stage3 = [&](const float* const* mats, float sc0) {
    #pragma unroll
    for (int i = 0; i < 6; ++i) {
      int p = i*256 + tid;
      int m = p >> 9, rem = p & 511;
      int f = rem >> 6, l = rem & 63;
      int nt = f >> 1, s = f & 1;
      int lq = l >> 4, lc = l & 15;
      float sc = (m == 0) ? sc0 : 1.f;
      const float* src = mats[m] + (size_t)(nt*16 + lc)*64 + s*32 + lq*8;
      short* dst = &Wm[m][f*512 + l*8];
      #pragma unroll
      for (int j = 0; j < 8; ++j) dst[j] = (short)f2bf(src[j] * sc);
    }
  };
  stage3(m1, 1.f);
  {
    const float* bs[6] = {b1, b2, bh, bq, bk, bv};
    for (int i = tid; i < 384; i += 256) {
      float sc = ((i >> 6) == 3) ? L2E : 1.f;      // bq scaled by log2(e)
      bias_s[i] = bs[i>>6][i & 63] * sc;
    }
  }
  __syncthreads();

  bf16x8 a0 = *(const bf16x8*)(he + (size_t)(rowb + col)*64 + quad*8);
  bf16x8 a1 = *(const bf16x8*)(he + (size_t)(rowb + col)*64 + quad*8 + 32);

  f32x4 acc[4];
  auto runL = [&](int m, int bidx) {
    #pragma unroll
    for (int nt = 0; nt < 4; ++nt) {
      float bb = bias_s[bidx*64 + nt*16 + col];
      acc[nt][0] = bb; acc[nt][1] = bb; acc[nt][2] = bb; acc[nt][3] = bb;
    }
    #pragma unroll
    for (int nt = 0; nt < 4; ++nt) {
      bf16x8 bf0 = *(const bf16x8*)(&Wm[m][(nt*2+0)*512 + lane*8]);
      bf16x8 bf1 = *(const bf16x8*)(&Wm[m][(nt*2+1)*512 + lane*8]);
      acc[nt] = __builtin_amdgcn_mfma_f32_16x16x32_bf16(a0, bf0, acc[nt], 0,0,0);
      acc[nt] = __builtin_amdgcn_mfma_f32_16x16x32_bf16(a1, bf1, acc[nt], 0,0,0);
    }
  };
  auto tileWrite = [&](bool relu) {
    #pragma unroll
    for (int nt = 0; nt < 4; ++nt)
      #pragma unroll
      for (int r = 0; r < 4; ++r) {
        float v = relu ? fmaxf(acc[nt][r], 0.f) : acc[nt][r];
        Atile[wv][(quad*4+r)*76 + ((nt*16+col) ^ (r*16))] = (short)f2bf(v);
      }
  };
  auto tileReadA = [&]() {
    int sw = (col & 3) * 16;
    a0 = *(const bf16x8*)(&Atile[wv][col*76 + ((quad*8     ) ^ sw)]);
    a1 = *(const bf16x8*)(&Atile[wv][col*76 + ((quad*8 + 32) ^ sw)]);
  };
  auto storeBF = [&](unsigned short* dst) {
    #pragma unroll
    for (int s = 0; s < 2; ++s) {
      int chunk = s*64 + lane;
      int r = chunk >> 3, c8 = chunk & 7;
      bf16x8 v = *(const bf16x8*)(&Atile[wv][r*76 + ((c8*8) ^ ((r&3)*16))]);
      *(bf16x8*)(dst + (size_t)(rowb + r)*64 + c8*8) = v;
    }
  };

  runL(0, 0); tileWrite(true); tileReadA();
  runL(1, 1); tileWrite(true); tileReadA();
  runL(2, 2); tileWrite(true); tileReadA();      // a0/a1 = hidden A-frags
  __syncthreads();
  stage3(m2, L2E);                               // Wq scaled by log2(e)
  __syncthreads();

  runL(0, 3); tileWrite(false); storeBF(qb);     // q (bf16, L2E-scaled)
  runL(1, 4); tileWrite(false); storeBF(kb);     // k (bf16)
  runL(2, 5);                                    // v
  {
    const int bi   = rowb >> 9;                  // batch
    const int key0 = (rowb & 511) + quad*4;
    #pragma unroll
    for (int nt = 0; nt < 4; ++nt) {
      #pragma unroll
      for (int r = 0; r < 4; ++r)
        feat[(size_t)(rowb + quad*4 + r)*128 + nt*16 + col] = acc[nt][r];
      uint32_t lo = (uint32_t)f2bf(acc[nt][0]) | ((uint32_t)f2bf(acc[nt][1]) << 16);
      uint32_t hi = (uint32_t)f2bf(acc[nt][2]) | ((uint32_t)f2bf(acc[nt][3]) << 16);
      uint2 pk; pk.x = lo; pk.y = hi;
      *(uint2*)(vt + ((size_t)bi*64 + nt*16 + col)*512 + key0) = pk;
    }
  }
}

// ---------------------------------------------------------------------------
// MFMA attention v3 = attn + FUSED forecast epilogue (forecast_kernel gone).
//  - Wf B-frags + bias staged in prologue (+8.25 KB LDS -> 52.4 KB total,
//    still 3 blocks/CU); first c-loop barrier makes them visible.
//  - After the c-loop: one __syncthreads (all waves done reading Ks), then
//    each wave transposes o_acc*inv into its private 16-row slice of the
//    REUSED Ks buffer (stride 72, wave-local, per-wave DS in-order => no
//    extra barrier), loads v A-frags from feat fp32 (written by mlp, same
//    f2bf path as old forecast_kernel => bit-identical numerics), and runs
//    the same 8 MFMAs -> out. Saves a full feat re-read (33.5 MB) + launch.
__global__ __launch_bounds__(256) void attn_kernel(
    const unsigned short* __restrict__ qg, const unsigned short* __restrict__ kg,
    const unsigned short* __restrict__ vt,
    const uint32_t* __restrict__ bm, float* __restrict__ feat,
    const float* __restrict__ Wf, const float* __restrict__ bfv,
    float* __restrict__ out)
{
  __shared__ short    Ks[128*72];      // 18.0 KB (reused as o-tile in epilogue)
  __shared__ short    Vt[64*136];      // 17.0 KB
  __shared__ short    Pl[4][16*32];    // 4 KB, per-wave
  __shared__ uint32_t Ms[4][256];      // 4 KB, per-wave mask words
  __shared__ short    Wfr[8*512];      // 8 KB Wf B-frags
  __shared__ float    bl[32];

  const int tid  = threadIdx.x;
  const int lane = tid & 63;
  const int wv   = tid >> 6;
  const int w16  = wv * 16;
  const int quad = lane >> 4;
  const int col  = lane & 15;

  const int b     = blockIdx.x >> 3;
  const int q0    = (blockIdx.x & 7) * 64;
  const int qbase = b*512 + q0 + wv*16;

  bf16x8 qa[2];
  qa[0] = *(const bf16x8*)(qg + (size_t)(qbase + col)*64 + quad*8);
  qa[1] = *(const bf16x8*)(qg + (size_t)(qbase + col)*64 + quad*8 + 32);

  #pragma unroll
  for (int w = 0; w < 4; ++w)
    Ms[wv][w*64 + lane] = bm[(size_t)qbase*16 + w*64 + lane];

  // ---- stage Wf B-frags + bias (visible after first c-loop barrier) ----
  #pragma unroll
  for (int i = 0; i < 2; ++i) {
    int p = i*256 + tid;               // 512 (frag,lane) entries
    int f = p >> 6, l = p & 63;
    int kc = f >> 1, nt = f & 1;
    int lq = l >> 4, lc = l & 15;
    int n = nt*16 + lc;
    bf16x8 v;
    #pragma unroll
    for (int j = 0; j < 8; ++j) v[j] = 0;
    if (n < 24) {
      const float* src = Wf + (size_t)n*128 + kc*32 + lq*8;
      #pragma unroll
      for (int j = 0; j < 8; ++j) v[j] = (short)f2bf(src[j]);
    }
    *(bf16x8*)(Wfr + f*512 + l*8) = v;
  }
  if (tid < 32) bl[tid] = (tid < 24) ? bfv[tid] : 0.f;

  f32x4 o_acc[4];
  #pragma unroll
  for (int nt = 0; nt < 4; ++nt)
    #pragma unroll
    for (int r = 0; r < 4; ++r) o_acc[nt][r] = 0.f;
  float l_part[4] = {0.f, 0.f, 0.f, 0.f};

  const unsigned short* vtb = vt + (size_t)b*64*512;

  for (int c = 0; c < 4; ++c) {
    __syncthreads();
    {
      const int kb_ = b*512 + c*128;
      // K chunk: bf16 [key][dim] stride 72
      #pragma unroll
      for (int i = 0; i < 4; ++i) {
        int p = i*256 + tid;
        int key = p >> 3, c8 = p & 7;
        bf16x8 kv = *(const bf16x8*)(kg + (size_t)(kb_ + key)*64 + c8*8);
        *(bf16x8*)(Ks + key*72 + c8*8) = kv;
      }
      // V^T chunk: bf16 [dim][key] stride 136 — pure copies
      #pragma unroll
      for (int i = 0; i < 4; ++i) {
        int p = i*256 + tid;
        int dim = p >> 4, k8 = p & 15;
        bf16x8 vv = *(const bf16x8*)(vtb + (size_t)dim*512 + c*128 + k8*8);
        *(bf16x8*)(Vt + dim*136 + k8*8) = vv;
      }
    }
    __syncthreads();

    for (int kc = 0; kc < 4; ++kc) {
      #pragma unroll
      for (int t = 0; t < 2; ++t) {
        const int kt = kc*2 + t;
        f32x4 s_acc;
        #pragma unroll
        for (int r = 0; r < 4; ++r) s_acc[r] = 0.f;
        const short* kp = Ks + (kt*16 + col)*72 + quad*8;
        bf16x8 kb0 = *(const bf16x8*)(kp);
        bf16x8 kb1 = *(const bf16x8*)(kp + 32);
        s_acc = __builtin_amdgcn_mfma_f32_16x16x32_bf16(qa[0], kb0, s_acc, 0,0,0);
        s_acc = __builtin_amdgcn_mfma_f32_16x16x32_bf16(qa[1], kb1, s_acc, 0,0,0);
        const int kcol = ((t*16 + col) ^ (quad*8));
        #pragma unroll
        for (int r = 0; r < 4; ++r) {
          uint32_t mw = Ms[wv][(quad*4+r)*16 + c*4 + (kt>>1)];
          float p = ((mw >> ((kt&1)*16 + col)) & 1u)
                      ? exp2f_(fminf(s_acc[r], 43.f)) : 0.f;   // s pre-scaled
          l_part[r] += p;
          Pl[wv][(quad*4+r)*32 + kcol] = (short)f2bf(p);
        }
      }
      bf16x8 pa = *(const bf16x8*)(&Pl[wv][col*32 + ((quad*8) ^ (((col)>>2)*8))]);
      #pragma unroll
      for (int nt = 0; nt < 4; ++nt) {
        bf16x8 vb = *(const bf16x8*)(&Vt[(nt*16+col)*136 + kc*32 + quad*8]);
        o_acc[nt] = __builtin_amdgcn_mfma_f32_16x16x32_bf16(pa, vb, o_acc[nt], 0,0,0);
      }
    }
  }

  float inv[4];
  #pragma unroll
  for (int r = 0; r < 4; ++r) {
    float v = l_part[r];
    v += __shfl_xor(v, 1);
    v += __shfl_xor(v, 2);
    v += __shfl_xor(v, 4);
    v += __shfl_xor(v, 8);
    inv[r] = rcpf_(fmaxf(v, 1e-20f));
  }

  // feat attn-half write (required output)
  #pragma unroll
  for (int nt = 0; nt < 4; ++nt)
    #pragma unroll
    for (int r = 0; r < 4; ++r)
      feat[(size_t)(qbase + quad*4 + r)*128 + 64 + nt*16 + col] = o_acc[nt][r]*inv[r];

  // ---- fused forecast ----
  __syncthreads();   // all waves done reading Ks/Vt before Ks reuse

  // transpose o*inv (C-layout) into wave-private Ks slice (A-layout source)
  #pragma unroll
  for (int nt = 0; nt < 4; ++nt)
    #pragma unroll
    for (int r = 0; r < 4; ++r)
      Ks[(w16 + quad*4 + r)*72 + nt*16 + col] = (short)f2bf(o_acc[nt][r]*inv[r]);

  // A-frags: kc 0..1 from feat v-half (fp32, written by mlp); kc 2..3 from Ks
  bf16x8 af[4];
  const float* fr = feat + (size_t)(qbase + col)*128;
  #pragma unroll
  for (int kc = 0; kc < 2; ++kc) {
    float4 f0 = *(const float4*)(fr + kc*32 + quad*8);
    float4 f1 = *(const float4*)(fr + kc*32 + quad*8 + 4);
    af[kc][0]=(short)f2bf(f0.x); af[kc][1]=(short)f2bf(f0.y);
    af[kc][2]=(short)f2bf(f0.z); af[kc][3]=(short)f2bf(f0.w);
    af[kc][4]=(short)f2bf(f1.x); af[kc][5]=(short)f2bf(f1.y);
    af[kc][6]=(short)f2bf(f1.z); af[kc][7]=(short)f2bf(f1.w);
  }
  #pragma unroll
  for (int kc = 2; kc < 4; ++kc)
    af[kc] = *(const bf16x8*)(Ks + (w16 + col)*72 + (kc-2)*32 + quad*8);

  f32x4 facc[2];
  #pragma unroll
  for (int nt = 0; nt < 2; ++nt) {
    float bb = bl[nt*16 + col];
    facc[nt][0] = bb; facc[nt][1] = bb; facc[nt][2] = bb; facc[nt][3] = bb;
  }
  #pragma unroll
  for (int kc = 0; kc < 4; ++kc) {
    #pragma unroll
    for (int nt = 0; nt < 2; ++nt) {
      bf16x8 bfr = *(const bf16x8*)(Wfr + (kc*2+nt)*512 + lane*8);
      facc[nt] = __builtin_amdgcn_mfma_f32_16x16x32_bf16(af[kc], bfr, facc[nt], 0,0,0);
    }
  }

  #pragma unroll
  for (int nt = 0; nt < 2; ++nt) {
    int n = nt*16 + col;
    if (n < 24) {
      #pragma unroll
      for (int r = 0; r < 4; ++r)
        out[(size_t)(qbase + quad*4 + r)*24 + n] = facc[nt][r];
    }
  }
}

// ---------------------------------------------------------------------------
extern "C" void kernel_launch(void* const* d_in, const int* in_sizes, int n_in,
                              void* d_out, int out_size, void* d_ws, size_t ws_size,
                              hipStream_t stream)
{
  const float* obs = (const float*)d_in[0];
  const int*   pm  = (const int*)  d_in[1];
  const float* nhm = (const float*)d_in[2];
  const float* Wih = (const float*)d_in[3];
  const float* Whh = (const float*)d_in[4];
  const float* bih = (const float*)d_in[5];
  const float* bhh = (const float*)d_in[6];
  const float* W1  = (const float*)d_in[7];
  const float* b1  = (const float*)d_in[8];
  const float* W2  = (const float*)d_in[9];
  const float* b2  = (const float*)d_in[10];
  const float* Wh  = (const float*)d_in[11];
  const float* bh  = (const float*)d_in[12];
  const float* Wq  = (const float*)d_in[13];
  const float* bq  = (const float*)d_in[14];
  const float* Wk  = (const float*)d_in[15];
  const float* bk  = (const float*)d_in[16];
  const float* Wv  = (const float*)d_in[17];
  const float* bv  = (const float*)d_in[18];
  const float* Wf  = (const float*)d_in[19];
  const float* bf  = (const float*)d_in[20];

  float* out  = (float*)d_out;                 // forecast: 65536*24
  float* feat = out + (size_t)M_*24;           // feat:     65536*128

  // workspace: he(8MB) | qb(8MB) | kb(8MB) | vt(8MB) | bitmask(4.2MB)
  char* ws = (char*)d_ws;
  unsigned short* he  = (unsigned short*)(ws);
  unsigned short* qbf = (unsigned short*)(ws + (size_t) 8*1024*1024);
  unsigned short* kbf = (unsigned short*)(ws + (size_t)16*1024*1024);
  unsigned short* vtb = (unsigned short*)(ws + (size_t)24*1024*1024);
  uint32_t*       bmw = (uint32_t*)      (ws + (size_t)32*1024*1024);

  lstm_kernel<<<M_/128, 512, 0, stream>>>(obs, nhm, Wih, Whh, bih, bhh, he,
                                          (const int4*)pm, bmw);
  mlp_kernel<<<M_/64, 256, 0, stream>>>(he, W1,b1, W2,b2, Wh,bh, Wq,bq, Wk,bk, Wv,bv,
                                        qbf, kbf, vtb, feat);
  attn_kernel<<<M_/64, 256, 0, stream>>>(qbf, kbf, vtb, bmw, feat, Wf, bf, out);
}

// Round 8
// 308.988 us; speedup vs baseline: 1.1599x; 1.0210x over previous
//
#include <hip/hip_runtime.h>
#include <hip/hip_bf16.h>
#include <stdint.h>

#define B_ 128
#define N_ 512
#define S_ 8
#define H_ 64
#define M_ (B_*N_)          // 65536 rows
#define L2E 1.442695041f

typedef __attribute__((ext_vector_type(8))) short bf16x8;
typedef __attribute__((ext_vector_type(4))) float f32x4;

__device__ __forceinline__ float exp2f_(float x) { return __builtin_amdgcn_exp2f(x); }
__device__ __forceinline__ float rcpf_(float x)  { return __builtin_amdgcn_rcpf(x); }
// x pre-scaled by log2(e):  sig2(x) == sigmoid(x / L2E)   (v_exp + v_rcp only)
__device__ __forceinline__ float sig2(float x)  { return rcpf_(1.f + exp2f_(-x)); }
// x pre-scaled by 2*log2(e): tanh2(x) == tanh(x / (2*L2E))
__device__ __forceinline__ float tanh2(float x) { return 1.f - 2.f*rcpf_(exp2f_(x) + 1.f); }
// fp32 -> bf16 round-to-nearest-even
__device__ __forceinline__ unsigned short f2bf(float x) {
  unsigned int u = __float_as_uint(x);
  u += 0x7fffu + ((u >> 16) & 1u);
  return (unsigned short)(u >> 16);
}

// ---------------------------------------------------------------------------
// MFMA LSTM v9 = v8 + async-split pm pack (issue-early / consume-late).
//  - The 4 coalesced pm int4 loads now issue at the TOP of each t-step,
//    fenced by sched_barrier(0) so they can't sink; the nib/shfl/store
//    consume sits after the cc-loop. ~1300+ cycles of MFMA+gate work hide
//    the HBM/L2 latency instead of an immediate vmcnt(0) stall (G15).
//  - Costs 16 VGPRs live across the cc-loop (48 -> ~64, cap 128: residency
//    unchanged). Everything else identical to v8.
__global__ __launch_bounds__(512, 4) void lstm_kernel(
    const float* __restrict__ obs, const float* __restrict__ nhm,
    const float* __restrict__ Wih, const float* __restrict__ Whh,
    const float* __restrict__ bih, const float* __restrict__ bhh,
    unsigned short* __restrict__ he,
    const int4* __restrict__ pm4, uint32_t* __restrict__ bm)
{
  __shared__ short    Wfrag[32*512];   // 32 KB  Whh B-frags (bf16, gate-scaled)
  __shared__ short    Wxc[1024];       // 2 KB   compact [Wih0,Wih1,bias,0] per n
  __shared__ short    h_s[128*72];     // 18 KB  bf16, stride 72

  const int tid  = threadIdx.x;
  const int lane = tid & 63;
  const int wv   = tid >> 6;           // 0..7
  const int w16  = wv * 16;
  const int quad = lane >> 4;
  const int col  = lane & 15;
  const int row0 = blockIdx.x * 128;

  // pm strip for this wave: 256 words = 2048 int4
  const int     wb  = (blockIdx.x*8 + wv) * 256;       // word base
  const int4*   pw  = pm4 + (size_t)wb * 8;            // int4 base
  const int     shp = (lane & 7) * 4;                  // nibble shift

  // ---- stage Whh as bf16 B-fragments (gate-scaled), 2048 (frag,lane) entries
  #pragma unroll
  for (int i = 0; i < 4; ++i) {
    int p = i*512 + tid;
    int f = p >> 6, l = p & 63;
    int t16 = f >> 1, s = f & 1;
    int lq = l >> 4, lc = l & 15;
    const float sc = (t16 >= 8 && t16 < 12) ? (2.f*L2E) : L2E;
    const float* src = Whh + (size_t)(t16*16 + lc)*64 + s*32 + lq*8;
    short* dst = Wfrag + f*512 + l*8;
    #pragma unroll
    for (int j = 0; j < 8; ++j) dst[j] = (short)f2bf(src[j] * sc);
  }
  // ---- stage compact Wx: Wxc[t16*64 + cc*4 + k], k: 0=Wih0 1=Wih1 2=bias ----
  if (tid < 256) {
    int t16 = tid >> 4, cc = tid & 15;
    int n = t16*16 + cc;
    const float sc = (t16 >= 8 && t16 < 12) ? (2.f*L2E) : L2E;
    short* d = Wxc + t16*64 + cc*4;
    d[0] = (short)f2bf(Wih[2*n + 0] * sc);
    d[1] = (short)f2bf(Wih[2*n + 1] * sc);
    d[2] = (short)f2bf((bih[n] + bhh[n]) * sc);
    d[3] = 0;
  }

  // zero h_s (4608 dwords)
  #pragma unroll
  for (int i = 0; i < 9; ++i) ((uint32_t*)h_s)[i*512 + tid] = 0u;

  // ---- per-lane x prep for row (w16+col); all quads redundant, so each
  //      consumer lane already holds its own value. Registers, no LDS.
  uint32_t xq0, xq1, xq2, xq3, xq4, xq5, xq6, xq7;
  int len;
  {
    const int grow = row0 + w16 + col;
    float xv0[8], xv1[8];
    int lzi = -1;
    #pragma unroll
    for (int t = 0; t < 8; ++t) {
      float m = nhm[(size_t)grow*8 + t];
      float a = obs[((size_t)grow*8 + t)*2 + 0] * m;
      float b = obs[((size_t)grow*8 + t)*2 + 1] * m;
      xv0[t] = a; xv1[t] = b;
      if (a == 0.f) lzi = t;
    }
    uint32_t xr[8];
    #pragma unroll
    for (int t = 0; t < 8; ++t) {
      bool kill = (t < lzi);
      float a = kill ? 0.f : xv0[t];
      float b = kill ? 0.f : xv1[t];
      xr[t] = (uint32_t)f2bf(a) | ((uint32_t)f2bf(b) << 16);
    }
    xq0 = xr[0]; xq1 = xr[1]; xq2 = xr[2]; xq3 = xr[3];
    xq4 = xr[4]; xq5 = xr[5]; xq6 = xr[6]; xq7 = xr[7];
    len = 7 - lzi; if (len < 1) len = 1;
  }
  int lenr[4];
  #pragma unroll
  for (int r = 0; r < 4; ++r) lenr[r] = __shfl(len, quad*4 + r);

  __syncthreads();     // the ONLY barrier (covers Wfrag, Wxc, h_s zero)

  float c_[16];
  #pragma unroll
  for (int i = 0; i < 16; ++i) c_[i] = 0.f;

  const f32x4 zero4 = {0.f, 0.f, 0.f, 0.f};
  const bool q0 = (quad == 0);

  #pragma unroll 1
  for (int t = 0; t < 8; ++t) {
    // ---- ISSUE pm loads for this step early (consumed after cc-loop) ----
    const int4* ps = pw + t*256 + lane;
    int4 pv0 = ps[0];
    int4 pv1 = ps[64];
    int4 pv2 = ps[128];
    int4 pv3 = ps[192];
    __builtin_amdgcn_sched_barrier(0);   // loads stay issued before MFMA region

    // ---- A-frag for the x/bias MFMA: [x0, x1, 1, 0...] on quad 0 ----
    uint32_t xw = xq0;
    // rotate queue (static indices; stays in registers)
    xq0 = xq1; xq1 = xq2; xq2 = xq3; xq3 = xq4;
    xq4 = xq5; xq5 = xq6; xq6 = xq7;

    union { bf16x8 v; uint32_t u[4]; } ax;
    ax.u[0] = q0 ? xw : 0u;
    ax.u[1] = q0 ? 0x00003f80u : 0u;    // bf16(1.0) at k==2
    ax.u[2] = 0u; ax.u[3] = 0u;

    // A-frags of h (bf16, no converts)
    bf16x8 a0 = *(const bf16x8*)(h_s + (w16 + col)*72 + quad*8);
    bf16x8 a1 = *(const bf16x8*)(h_s + (w16 + col)*72 + 32 + quad*8);

    // 4 column-groups: tiles {cc, cc+4, cc+8, cc+12} = i,f,g,o for cells
    // n = cc*16+col. Only 4 accumulators live at a time.
    #pragma unroll
    for (int cc = 0; cc < 4; ++cc) {
      f32x4 acc[4];
      #pragma unroll
      for (int g = 0; g < 4; ++g) {
        const int t16 = g*4 + cc;
        union { bf16x8 v; uint32_t u[4]; } wx;
        uint2 d = *(const uint2*)(Wxc + t16*64 + col*4);  // always initialized
        wx.u[0] = q0 ? d.x : 0u;        // zero fragment on non-quad0 lanes
        wx.u[1] = q0 ? d.y : 0u;
        wx.u[2] = 0u; wx.u[3] = 0u;
        bf16x8 b0 = *(const bf16x8*)(Wfrag + (t16*2+0)*512 + lane*8);
        bf16x8 b1 = *(const bf16x8*)(Wfrag + (t16*2+1)*512 + lane*8);
        acc[g] = __builtin_amdgcn_mfma_f32_16x16x32_bf16(ax.v, wx.v, zero4, 0, 0, 0);
        acc[g] = __builtin_amdgcn_mfma_f32_16x16x32_bf16(a0, b0, acc[g], 0, 0, 0);
        acc[g] = __builtin_amdgcn_mfma_f32_16x16x32_bf16(a1, b1, acc[g], 0, 0, 0);
      }
      #pragma unroll
      for (int r = 0; r < 4; ++r) {
        if (t < lenr[r]) {
          float gi = acc[0][r];
          float gf = acc[1][r];
          float gg = acc[2][r];
          float go = acc[3][r];
          float cn = sig2(gf)*c_[cc*4+r] + sig2(gi)*tanh2(gg);
          c_[cc*4+r] = cn;
          h_s[(w16 + quad*4 + r)*72 + cc*16 + col] =
              (short)f2bf(sig2(go)*tanh2(cn*(2.f*L2E)));
        }
      }
      __builtin_amdgcn_sched_barrier(0);  // pin group: keep acc lifetime short
    }

    // ---- CONSUME pm loads (latency hidden under the cc-loop above) ----
    {
      int4 vv[4] = {pv0, pv1, pv2, pv3};
      #pragma unroll
      for (int jj = 0; jj < 4; ++jj) {
        int4 v = vv[jj];
        uint32_t nib = (v.x != 0 ? 1u : 0u)
                     | (v.y != 0 ? 2u : 0u)
                     | (v.z != 0 ? 4u : 0u)
                     | (v.w != 0 ? 8u : 0u);
        uint32_t x = nib << shp;
        x |= __shfl_xor(x, 1);
        x |= __shfl_xor(x, 2);
        x |= __shfl_xor(x, 4);
        if ((lane & 7) == 0)
          bm[wb + t*32 + jj*8 + (lane >> 3)] = x;
      }
      __builtin_amdgcn_sched_barrier(0);  // keep pm block out of next step's MFMA region
    }
    // no per-step barrier: each wave owns its 16 h rows
  }

  // he = relu(h) bf16, wave-local b128 stores
  #pragma unroll
  for (int s = 0; s < 2; ++s) {
    int chunk = s*64 + lane;          // 128 chunks of 8 shorts per wave
    int rl = chunk >> 3, c8 = chunk & 7;
    bf16x8 v = *(const bf16x8*)(h_s + (w16 + rl)*72 + c8*8);
    #pragma unroll
    for (int j = 0; j < 8; ++j) {
      short sv = v[j];
      v[j] = (sv & (short)0x8000) ? (short)0 : sv;   // relu (handles -0.0)
    }
    *(bf16x8*)(he + (size_t)(row0 + w16 + rl)*64 + c8*8) = v;
  }
}

// ---------------------------------------------------------------------------
// MFMA MLP (unchanged)
__global__ __launch_bounds__(256) void mlp_kernel(
    const unsigned short* __restrict__ he,
    const float* __restrict__ W1, const float* __restrict__ b1,
    const float* __restrict__ W2, const float* __restrict__ b2,
    const float* __restrict__ Wh, const float* __restrict__ bh,
    const float* __restrict__ Wq, const float* __restrict__ bq,
    const float* __restrict__ Wk, const float* __restrict__ bk,
    const float* __restrict__ Wv, const float* __restrict__ bv,
    unsigned short* __restrict__ qb, unsigned short* __restrict__ kb,
    unsigned short* __restrict__ vt, float* __restrict__ feat)
{
  __shared__ short Wm[3][8*512];       // 24 KB B-frags
  __shared__ float bias_s[6*64];       // 1.5 KB
  __shared__ short Atile[4][16*76];    // 9.5 KB per-wave relayout tiles

  const int tid  = threadIdx.x;
  const int lane = tid & 63;
  const int wv   = tid >> 6;
  const int quad = lane >> 4;
  const int col  = lane & 15;
  const int rowb = blockIdx.x*64 + wv*16;

  const float* m1[3] = {W1, W2, Wh};
  const float* m2[3] = {Wq, Wk, Wv};
  auto stage3 = [&](const float* const* mats, float sc0) {
    #pragma unroll
    for (int i = 0; i < 6; ++i) {
      int p = i*256 + tid;
      int m = p >> 9, rem = p & 511;
      int f = rem >> 6, l = rem & 63;
      int nt = f >> 1, s = f & 1;
      int lq = l >> 4, lc = l & 15;
      float sc = (m == 0) ? sc0 : 1.f;
      const float* src = mats[m] + (size_t)(nt*16 + lc)*64 + s*32 + lq*8;
      short* dst = &Wm[m][f*512 + l*8];
      #pragma unroll
      for (int j = 0; j < 8; ++j) dst[j] = (short)f2bf(src[j] * sc);
    }
  };
  stage3(m1, 1.f);
  {
    const float* bs[6] = {b1, b2, bh, bq, bk, bv};
    for (int i = tid; i < 384; i += 256) {
      float sc = ((i >> 6) == 3) ? L2E : 1.f;      // bq scaled by log2(e)
      bias_s[i] = bs[i>>6][i & 63] * sc;
    }
  }
  __syncthreads();

  bf16x8 a0 = *(const bf16x8*)(he + (size_t)(rowb + col)*64 + quad*8);
  bf16x8 a1 = *(const bf16x8*)(he + (size_t)(rowb + col)*64 + quad*8 + 32);

  f32x4 acc[4];
  auto runL = [&](int m, int bidx) {
    #pragma unroll
    for (int nt = 0; nt < 4; ++nt) {
      float bb = bias_s[bidx*64 + nt*16 + col];
      acc[nt][0] = bb; acc[nt][1] = bb; acc[nt][2] = bb; acc[nt][3] = bb;
    }
    #pragma unroll
    for (int nt = 0; nt < 4; ++nt) {
      bf16x8 bf0 = *(const bf16x8*)(&Wm[m][(nt*2+0)*512 + lane*8]);
      bf16x8 bf1 = *(const bf16x8*)(&Wm[m][(nt*2+1)*512 + lane*8]);
      acc[nt] = __builtin_amdgcn_mfma_f32_16x16x32_bf16(a0, bf0, acc[nt], 0,0,0);
      acc[nt] = __builtin_amdgcn_mfma_f32_16x16x32_bf16(a1, bf1, acc[nt], 0,0,0);
    }
  };
  auto tileWrite = [&](bool relu) {
    #pragma unroll
    for (int nt = 0; nt < 4; ++nt)
      #pragma unroll
      for (int r = 0; r < 4; ++r) {
        float v = relu ? fmaxf(acc[nt][r], 0.f) : acc[nt][r];
        Atile[wv][(quad*4+r)*76 + ((nt*16+col) ^ (r*16))] = (short)f2bf(v);
      }
  };
  auto tileReadA = [&]() {
    int sw = (col & 3) * 16;
    a0 = *(const bf16x8*)(&Atile[wv][col*76 + ((quad*8     ) ^ sw)]);
    a1 = *(const bf16x8*)(&Atile[wv][col*76 + ((quad*8 + 32) ^ sw)]);
  };
  auto storeBF = [&](unsigned short* dst) {
    #pragma unroll
    for (int s = 0; s < 2; ++s) {
      int chunk = s*64 + lane;
      int r = chunk >> 3, c8 = chunk & 7;
      bf16x8 v = *(const bf16x8*)(&Atile[wv][r*76 + ((c8*8) ^ ((r&3)*16))]);
      *(bf16x8*)(dst + (size_t)(rowb + r)*64 + c8*8) = v;
    }
  };

  runL(0, 0); tileWrite(true); tileReadA();
  runL(1, 1); tileWrite(true); tileReadA();
  runL(2, 2); tileWrite(true); tileReadA();      // a0/a1 = hidden A-frags
  __syncthreads();
  stage3(m2, L2E);                               // Wq scaled by log2(e)
  __syncthreads();

  runL(0, 3); tileWrite(false); storeBF(qb);     // q (bf16, L2E-scaled)
  runL(1, 4); tileWrite(false); storeBF(kb);     // k (bf16)
  runL(2, 5);                                    // v
  {
    const int bi   = rowb >> 9;                  // batch
    const int key0 = (rowb & 511) + quad*4;
    #pragma unroll
    for (int nt = 0; nt < 4; ++nt) {
      #pragma unroll
      for (int r = 0; r < 4; ++r)
        feat[(size_t)(rowb + quad*4 + r)*128 + nt*16 + col] = acc[nt][r];
      uint32_t lo = (uint32_t)f2bf(acc[nt][0]) | ((uint32_t)f2bf(acc[nt][1]) << 16);
      uint32_t hi = (uint32_t)f2bf(acc[nt][2]) | ((uint32_t)f2bf(acc[nt][3]) << 16);
      uint2 pk; pk.x = lo; pk.y = hi;
      *(uint2*)(vt + ((size_t)bi*64 + nt*16 + col)*512 + key0) = pk;
    }
  }
}

// ---------------------------------------------------------------------------
// MFMA attention v3 (unchanged from R7): fused forecast epilogue.
__global__ __launch_bounds__(256) void attn_kernel(
    const unsigned short* __restrict__ qg, const unsigned short* __restrict__ kg,
    const unsigned short* __restrict__ vt,
    const uint32_t* __restrict__ bm, float* __restrict__ feat,
    const float* __restrict__ Wf, const float* __restrict__ bfv,
    float* __restrict__ out)
{
  __shared__ short    Ks[128*72];      // 18.0 KB (reused as o-tile in epilogue)
  __shared__ short    Vt[64*136];      // 17.0 KB
  __shared__ short    Pl[4][16*32];    // 4 KB, per-wave
  __shared__ uint32_t Ms[4][256];      // 4 KB, per-wave mask words
  __shared__ short    Wfr[8*512];      // 8 KB Wf B-frags
  __shared__ float    bl[32];

  const int tid  = threadIdx.x;
  const int lane = tid & 63;
  const int wv   = tid >> 6;
  const int w16  = wv * 16;
  const int quad = lane >> 4;
  const int col  = lane & 15;

  const int b     = blockIdx.x >> 3;
  const int q0    = (blockIdx.x & 7) * 64;
  const int qbase = b*512 + q0 + wv*16;

  bf16x8 qa[2];
  qa[0] = *(const bf16x8*)(qg + (size_t)(qbase + col)*64 + quad*8);
  qa[1] = *(const bf16x8*)(qg + (size_t)(qbase + col)*64 + quad*8 + 32);

  #pragma unroll
  for (int w = 0; w < 4; ++w)
    Ms[wv][w*64 + lane] = bm[(size_t)qbase*16 + w*64 + lane];

  // ---- stage Wf B-frags + bias (visible after first c-loop barrier) ----
  #pragma unroll
  for (int i = 0; i < 2; ++i) {
    int p = i*256 + tid;               // 512 (frag,lane) entries
    int f = p >> 6, l = p & 63;
    int kc = f >> 1, nt = f & 1;
    int lq = l >> 4, lc = l & 15;
    int n = nt*16 + lc;
    bf16x8 v;
    #pragma unroll
    for (int j = 0; j < 8; ++j) v[j] = 0;
    if (n < 24) {
      const float* src = Wf + (size_t)n*128 + kc*32 + lq*8;
      #pragma unroll
      for (int j = 0; j < 8; ++j) v[j] = (short)f2bf(src[j]);
    }
    *(bf16x8*)(Wfr + f*512 + l*8) = v;
  }
  if (tid < 32) bl[tid] = (tid < 24) ? bfv[tid] : 0.f;

  f32x4 o_acc[4];
  #pragma unroll
  for (int nt = 0; nt < 4; ++nt)
    #pragma unroll
    for (int r = 0; r < 4; ++r) o_acc[nt][r] = 0.f;
  float l_part[4] = {0.f, 0.f, 0.f, 0.f};

  const unsigned short* vtb = vt + (size_t)b*64*512;

  for (int c = 0; c < 4; ++c) {
    __syncthreads();
    {
      const int kb_ = b*512 + c*128;
      // K chunk: bf16 [key][dim] stride 72
      #pragma unroll
      for (int i = 0; i < 4; ++i) {
        int p = i*256 + tid;
        int key = p >> 3, c8 = p & 7;
        bf16x8 kv = *(const bf16x8*)(kg + (size_t)(kb_ + key)*64 + c8*8);
        *(bf16x8*)(Ks + key*72 + c8*8) = kv;
      }
      // V^T chunk: bf16 [dim][key] stride 136 — pure copies
      #pragma unroll
      for (int i = 0; i < 4; ++i) {
        int p = i*256 + tid;
        int dim = p >> 4, k8 = p & 15;
        bf16x8 vv = *(const bf16x8*)(vtb + (size_t)dim*512 + c*128 + k8*8);
        *(bf16x8*)(Vt + dim*136 + k8*8) = vv;
      }
    }
    __syncthreads();

    for (int kc = 0; kc < 4; ++kc) {
      #pragma unroll
      for (int t = 0; t < 2; ++t) {
        const int kt = kc*2 + t;
        f32x4 s_acc;
        #pragma unroll
        for (int r = 0; r < 4; ++r) s_acc[r] = 0.f;
        const short* kp = Ks + (kt*16 + col)*72 + quad*8;
        bf16x8 kb0 = *(const bf16x8*)(kp);
        bf16x8 kb1 = *(const bf16x8*)(kp + 32);
        s_acc = __builtin_amdgcn_mfma_f32_16x16x32_bf16(qa[0], kb0, s_acc, 0,0,0);
        s_acc = __builtin_amdgcn_mfma_f32_16x16x32_bf16(qa[1], kb1, s_acc, 0,0,0);
        const int kcol = ((t*16 + col) ^ (quad*8));
        #pragma unroll
        for (int r = 0; r < 4; ++r) {
          uint32_t mw = Ms[wv][(quad*4+r)*16 + c*4 + (kt>>1)];
          float p = ((mw >> ((kt&1)*16 + col)) & 1u)
                      ? exp2f_(fminf(s_acc[r], 43.f)) : 0.f;   // s pre-scaled
          l_part[r] += p;
          Pl[wv][(quad*4+r)*32 + kcol] = (short)f2bf(p);
        }
      }
      bf16x8 pa = *(const bf16x8*)(&Pl[wv][col*32 + ((quad*8) ^ (((col)>>2)*8))]);
      #pragma unroll
      for (int nt = 0; nt < 4; ++nt) {
        bf16x8 vb = *(const bf16x8*)(&Vt[(nt*16+col)*136 + kc*32 + quad*8]);
        o_acc[nt] = __builtin_amdgcn_mfma_f32_16x16x32_bf16(pa, vb, o_acc[nt], 0,0,0);
      }
    }
  }

  float inv[4];
  #pragma unroll
  for (int r = 0; r < 4; ++r) {
    float v = l_part[r];
    v += __shfl_xor(v, 1);
    v += __shfl_xor(v, 2);
    v += __shfl_xor(v, 4);
    v += __shfl_xor(v, 8);
    inv[r] = rcpf_(fmaxf(v, 1e-20f));
  }

  // feat attn-half write (required output)
  #pragma unroll
  for (int nt = 0; nt < 4; ++nt)
    #pragma unroll
    for (int r = 0; r < 4; ++r)
      feat[(size_t)(qbase + quad*4 + r)*128 + 64 + nt*16 + col] = o_acc[nt][r]*inv[r];

  // ---- fused forecast ----
  __syncthreads();   // all waves done reading Ks/Vt before Ks reuse

  // transpose o*inv (C-layout) into wave-private Ks slice (A-layout source)
  #pragma unroll
  for (int nt = 0; nt < 4; ++nt)
    #pragma unroll
    for (int r = 0; r < 4; ++r)
      Ks[(w16 + quad*4 + r)*72 + nt*16 + col] = (short)f2bf(o_acc[nt][r]*inv[r]);

  // A-frags: kc 0..1 from feat v-half (fp32, written by mlp); kc 2..3 from Ks
  bf16x8 af[4];
  const float* fr = feat + (size_t)(qbase + col)*128;
  #pragma unroll
  for (int kc = 0; kc < 2; ++kc) {
    float4 f0 = *(const float4*)(fr + kc*32 + quad*8);
    float4 f1 = *(const float4*)(fr + kc*32 + quad*8 + 4);
    af[kc][0]=(short)f2bf(f0.x); af[kc][1]=(short)f2bf(f0.y);
    af[kc][2]=(short)f2bf(f0.z); af[kc][3]=(short)f2bf(f0.w);
    af[kc][4]=(short)f2bf(f1.x); af[kc][5]=(short)f2bf(f1.y);
    af[kc][6]=(short)f2bf(f1.z); af[kc][7]=(short)f2bf(f1.w);
  }
  #pragma unroll
  for (int kc = 2; kc < 4; ++kc)
    af[kc] = *(const bf16x8*)(Ks + (w16 + col)*72 + (kc-2)*32 + quad*8);

  f32x4 facc[2];
  #pragma unroll
  for (int nt = 0; nt < 2; ++nt) {
    float bb = bl[nt*16 + col];
    facc[nt][0] = bb; facc[nt][1] = bb; facc[nt][2] = bb; facc[nt][3] = bb;
  }
  #pragma unroll
  for (int kc = 0; kc < 4; ++kc) {
    #pragma unroll
    for (int nt = 0; nt < 2; ++nt) {
      bf16x8 bfr = *(const bf16x8*)(Wfr + (kc*2+nt)*512 + lane*8);
      facc[nt] = __builtin_amdgcn_mfma_f32_16x16x32_bf16(af[kc], bfr, facc[nt], 0,0,0);
    }
  }

  #pragma unroll
  for (int nt = 0; nt < 2; ++nt) {
    int n = nt*16 + col;
    if (n < 24) {
      #pragma unroll
      for (int r = 0; r < 4; ++r)
        out[(size_t)(qbase + quad*4 + r)*24 + n] = facc[nt][r];
    }
  }
}

// ---------------------------------------------------------------------------
extern "C" void kernel_launch(void* const* d_in, const int* in_sizes, int n_in,
                              void* d_out, int out_size, void* d_ws, size_t ws_size,
                              hipStream_t stream)
{
  const float* obs = (const float*)d_in[0];
  const int*   pm  = (const int*)  d_in[1];
  const float* nhm = (const float*)d_in[2];
  const float* Wih = (const float*)d_in[3];
  const float* Whh = (const float*)d_in[4];
  const float* bih = (const float*)d_in[5];
  const float* bhh = (const float*)d_in[6];
  const float* W1  = (const float*)d_in[7];
  const float* b1  = (const float*)d_in[8];
  const float* W2  = (const float*)d_in[9];
  const float* b2  = (const float*)d_in[10];
  const float* Wh  = (const float*)d_in[11];
  const float* bh  = (const float*)d_in[12];
  const float* Wq  = (const float*)d_in[13];
  const float* bq  = (const float*)d_in[14];
  const float* Wk  = (const float*)d_in[15];
  const float* bk  = (const float*)d_in[16];
  const float* Wv  = (const float*)d_in[17];
  const float* bv  = (const float*)d_in[18];
  const float* Wf  = (const float*)d_in[19];
  const float* bf  = (const float*)d_in[20];

  float* out  = (float*)d_out;                 // forecast: 65536*24
  float* feat = out + (size_t)M_*24;           // feat:     65536*128

  // workspace: he(8MB) | qb(8MB) | kb(8MB) | vt(8MB) | bitmask(4.2MB)
  char* ws = (char*)d_ws;
  unsigned short* he  = (unsigned short*)(ws);
  unsigned short* qbf = (unsigned short*)(ws + (size_t) 8*1024*1024);
  unsigned short* kbf = (unsigned short*)(ws + (size_t)16*1024*1024);
  unsigned short* vtb = (unsigned short*)(ws + (size_t)24*1024*1024);
  uint32_t*       bmw = (uint32_t*)      (ws + (size_t)32*1024*1024);

  lstm_kernel<<<M_/128, 512, 0, stream>>>(obs, nhm, Wih, Whh, bih, bhh, he,
                                          (const int4*)pm, bmw);
  mlp_kernel<<<M_/64, 256, 0, stream>>>(he, W1,b1, W2,b2, Wh,bh, Wq,bq, Wk,bk, Wv,bv,
                                        qbf, kbf, vtb, feat);
  attn_kernel<<<M_/64, 256, 0, stream>>>(qbf, kbf, vtb, bmw, feat, Wf, bf, out);
}

// Round 9
// 302.911 us; speedup vs baseline: 1.1832x; 1.0201x over previous
//
#include <hip/hip_runtime.h>
#include <hip/hip_bf16.h>
#include <stdint.h>

#define B_ 128
#define N_ 512
#define S_ 8
#define H_ 64
#define M_ (B_*N_)          // 65536 rows
#define L2E 1.442695041f

typedef __attribute__((ext_vector_type(8))) short bf16x8;
typedef __attribute__((ext_vector_type(4))) float f32x4;

__device__ __forceinline__ float exp2f_(float x) { return __builtin_amdgcn_exp2f(x); }
__device__ __forceinline__ float rcpf_(float x)  { return __builtin_amdgcn_rcpf(x); }
// x pre-scaled by log2(e):  sig2(x) == sigmoid(x / L2E)   (v_exp + v_rcp only)
__device__ __forceinline__ float sig2(float x)  { return rcpf_(1.f + exp2f_(-x)); }
// x pre-scaled by 2*log2(e): tanh2(x) == tanh(x / (2*L2E))
__device__ __forceinline__ float tanh2(float x) { return 1.f - 2.f*rcpf_(exp2f_(x) + 1.f); }
// fp32 -> bf16 round-to-nearest-even
__device__ __forceinline__ unsigned short f2bf(float x) {
  unsigned int u = __float_as_uint(x);
  u += 0x7fffu + ((u >> 16) & 1u);
  return (unsigned short)(u >> 16);
}

// ---------------------------------------------------------------------------
// MFMA LSTM v10 = v9 + one-shot weight frag conversion (blocks 0..6).
//  - v9 core unchanged: async-split pm pack (issue-early/consume-late),
//    x/len in registers, LDS 53248 B.
//  - NEW: blocks 0..6 convert {W1,W2,Wh,Wq,Wk,Wv,Wf} to bf16 B-frags in a
//    global buffer wg (7 x 4096 shorts). Wq scaled by L2E (matches old
//    stage3(m2,L2E)); Wf zero-padded to 32 cols. Stream order makes wg
//    visible to mlp/attn. Removes per-block weight staging storms there.
__global__ __launch_bounds__(512, 4) void lstm_kernel(
    const float* __restrict__ obs, const float* __restrict__ nhm,
    const float* __restrict__ Wih, const float* __restrict__ Whh,
    const float* __restrict__ bih, const float* __restrict__ bhh,
    unsigned short* __restrict__ he,
    const int4* __restrict__ pm4, uint32_t* __restrict__ bm,
    const float* __restrict__ W1, const float* __restrict__ W2,
    const float* __restrict__ Wh, const float* __restrict__ Wq,
    const float* __restrict__ Wk, const float* __restrict__ Wv,
    const float* __restrict__ Wf, unsigned short* __restrict__ wg)
{
  __shared__ short    Wfrag[32*512];   // 32 KB  Whh B-frags (bf16, gate-scaled)
  __shared__ short    Wxc[1024];       // 2 KB   compact [Wih0,Wih1,bias,0] per n
  __shared__ short    h_s[128*72];     // 18 KB  bf16, stride 72

  const int tid  = threadIdx.x;
  const int lane = tid & 63;
  const int wv   = tid >> 6;           // 0..7
  const int w16  = wv * 16;
  const int quad = lane >> 4;
  const int col  = lane & 15;
  const int row0 = blockIdx.x * 128;

  // pm strip for this wave: 256 words = 2048 int4
  const int     wb  = (blockIdx.x*8 + wv) * 256;       // word base
  const int4*   pw  = pm4 + (size_t)wb * 8;            // int4 base
  const int     shp = (lane & 7) * 4;                  // nibble shift

  // ---- stage Whh as bf16 B-fragments (gate-scaled), 2048 (frag,lane) entries
  #pragma unroll
  for (int i = 0; i < 4; ++i) {
    int p = i*512 + tid;
    int f = p >> 6, l = p & 63;
    int t16 = f >> 1, s = f & 1;
    int lq = l >> 4, lc = l & 15;
    const float sc = (t16 >= 8 && t16 < 12) ? (2.f*L2E) : L2E;
    const float* src = Whh + (size_t)(t16*16 + lc)*64 + s*32 + lq*8;
    short* dst = Wfrag + f*512 + l*8;
    #pragma unroll
    for (int j = 0; j < 8; ++j) dst[j] = (short)f2bf(src[j] * sc);
  }
  // ---- stage compact Wx: Wxc[t16*64 + cc*4 + k], k: 0=Wih0 1=Wih1 2=bias ----
  if (tid < 256) {
    int t16 = tid >> 4, cc = tid & 15;
    int n = t16*16 + cc;
    const float sc = (t16 >= 8 && t16 < 12) ? (2.f*L2E) : L2E;
    short* d = Wxc + t16*64 + cc*4;
    d[0] = (short)f2bf(Wih[2*n + 0] * sc);
    d[1] = (short)f2bf(Wih[2*n + 1] * sc);
    d[2] = (short)f2bf((bih[n] + bhh[n]) * sc);
    d[3] = 0;
  }

  // zero h_s (4608 dwords)
  #pragma unroll
  for (int i = 0; i < 9; ++i) ((uint32_t*)h_s)[i*512 + tid] = 0u;

  // ---- one-shot weight frag conversion (blocks 0..6, 512 entries each) ----
  if (blockIdx.x < 7) {
    const int m = blockIdx.x;
    const int p = tid;
    const int f = p >> 6, l = p & 63;
    const int lq = l >> 4, lc = l & 15;
    bf16x8 v;
    #pragma unroll
    for (int j = 0; j < 8; ++j) v[j] = 0;
    if (m < 6) {
      const float* mats[6] = {W1, W2, Wh, Wq, Wk, Wv};
      const float sc = (m == 3) ? L2E : 1.f;     // Wq pre-scaled by log2(e)
      const int nt = f >> 1, s = f & 1;
      const float* src = mats[m] + (size_t)(nt*16 + lc)*64 + s*32 + lq*8;
      #pragma unroll
      for (int j = 0; j < 8; ++j) v[j] = (short)f2bf(src[j]);
      if (m == 3) {
        #pragma unroll
        for (int j = 0; j < 8; ++j) v[j] = (short)f2bf(src[j] * sc);
      }
    } else {
      const int kc = f >> 1, nt = f & 1;
      const int n = nt*16 + lc;
      if (n < 24) {
        const float* src = Wf + (size_t)n*128 + kc*32 + lq*8;
        #pragma unroll
        for (int j = 0; j < 8; ++j) v[j] = (short)f2bf(src[j]);
      }
    }
    *(bf16x8*)(wg + (size_t)m*4096 + f*512 + l*8) = v;
  }

  // ---- per-lane x prep for row (w16+col); all quads redundant, so each
  //      consumer lane already holds its own value. Registers, no LDS.
  uint32_t xq0, xq1, xq2, xq3, xq4, xq5, xq6, xq7;
  int len;
  {
    const int grow = row0 + w16 + col;
    float xv0[8], xv1[8];
    int lzi = -1;
    #pragma unroll
    for (int t = 0; t < 8; ++t) {
      float m = nhm[(size_t)grow*8 + t];
      float a = obs[((size_t)grow*8 + t)*2 + 0] * m;
      float b = obs[((size_t)grow*8 + t)*2 + 1] * m;
      xv0[t] = a; xv1[t] = b;
      if (a == 0.f) lzi = t;
    }
    uint32_t xr[8];
    #pragma unroll
    for (int t = 0; t < 8; ++t) {
      bool kill = (t < lzi);
      float a = kill ? 0.f : xv0[t];
      float b = kill ? 0.f : xv1[t];
      xr[t] = (uint32_t)f2bf(a) | ((uint32_t)f2bf(b) << 16);
    }
    xq0 = xr[0]; xq1 = xr[1]; xq2 = xr[2]; xq3 = xr[3];
    xq4 = xr[4]; xq5 = xr[5]; xq6 = xr[6]; xq7 = xr[7];
    len = 7 - lzi; if (len < 1) len = 1;
  }
  int lenr[4];
  #pragma unroll
  for (int r = 0; r < 4; ++r) lenr[r] = __shfl(len, quad*4 + r);

  __syncthreads();     // the ONLY barrier (covers Wfrag, Wxc, h_s zero)

  float c_[16];
  #pragma unroll
  for (int i = 0; i < 16; ++i) c_[i] = 0.f;

  const f32x4 zero4 = {0.f, 0.f, 0.f, 0.f};
  const bool q0 = (quad == 0);

  #pragma unroll 1
  for (int t = 0; t < 8; ++t) {
    // ---- ISSUE pm loads for this step early (consumed after cc-loop) ----
    const int4* ps = pw + t*256 + lane;
    int4 pv0 = ps[0];
    int4 pv1 = ps[64];
    int4 pv2 = ps[128];
    int4 pv3 = ps[192];
    __builtin_amdgcn_sched_barrier(0);   // loads stay issued before MFMA region

    // ---- A-frag for the x/bias MFMA: [x0, x1, 1, 0...] on quad 0 ----
    uint32_t xw = xq0;
    // rotate queue (static indices; stays in registers)
    xq0 = xq1; xq1 = xq2; xq2 = xq3; xq3 = xq4;
    xq4 = xq5; xq5 = xq6; xq6 = xq7;

    union { bf16x8 v; uint32_t u[4]; } ax;
    ax.u[0] = q0 ? xw : 0u;
    ax.u[1] = q0 ? 0x00003f80u : 0u;    // bf16(1.0) at k==2
    ax.u[2] = 0u; ax.u[3] = 0u;

    // A-frags of h (bf16, no converts)
    bf16x8 a0 = *(const bf16x8*)(h_s + (w16 + col)*72 + quad*8);
    bf16x8 a1 = *(const bf16x8*)(h_s + (w16 + col)*72 + 32 + quad*8);

    // 4 column-groups: tiles {cc, cc+4, cc+8, cc+12} = i,f,g,o for cells
    // n = cc*16+col. Only 4 accumulators live at a time.
    #pragma unroll
    for (int cc = 0; cc < 4; ++cc) {
      f32x4 acc[4];
      #pragma unroll
      for (int g = 0; g < 4; ++g) {
        const int t16 = g*4 + cc;
        union { bf16x8 v; uint32_t u[4]; } wx;
        uint2 d = *(const uint2*)(Wxc + t16*64 + col*4);  // always initialized
        wx.u[0] = q0 ? d.x : 0u;        // zero fragment on non-quad0 lanes
        wx.u[1] = q0 ? d.y : 0u;
        wx.u[2] = 0u; wx.u[3] = 0u;
        bf16x8 b0 = *(const bf16x8*)(Wfrag + (t16*2+0)*512 + lane*8);
        bf16x8 b1 = *(const bf16x8*)(Wfrag + (t16*2+1)*512 + lane*8);
        acc[g] = __builtin_amdgcn_mfma_f32_16x16x32_bf16(ax.v, wx.v, zero4, 0, 0, 0);
        acc[g] = __builtin_amdgcn_mfma_f32_16x16x32_bf16(a0, b0, acc[g], 0, 0, 0);
        acc[g] = __builtin_amdgcn_mfma_f32_16x16x32_bf16(a1, b1, acc[g], 0, 0, 0);
      }
      #pragma unroll
      for (int r = 0; r < 4; ++r) {
        if (t < lenr[r]) {
          float gi = acc[0][r];
          float gf = acc[1][r];
          float gg = acc[2][r];
          float go = acc[3][r];
          float cn = sig2(gf)*c_[cc*4+r] + sig2(gi)*tanh2(gg);
          c_[cc*4+r] = cn;
          h_s[(w16 + quad*4 + r)*72 + cc*16 + col] =
              (short)f2bf(sig2(go)*tanh2(cn*(2.f*L2E)));
        }
      }
      __builtin_amdgcn_sched_barrier(0);  // pin group: keep acc lifetime short
    }

    // ---- CONSUME pm loads (latency hidden under the cc-loop above) ----
    {
      int4 vv[4] = {pv0, pv1, pv2, pv3};
      #pragma unroll
      for (int jj = 0; jj < 4; ++jj) {
        int4 v = vv[jj];
        uint32_t nib = (v.x != 0 ? 1u : 0u)
                     | (v.y != 0 ? 2u : 0u)
                     | (v.z != 0 ? 4u : 0u)
                     | (v.w != 0 ? 8u : 0u);
        uint32_t x = nib << shp;
        x |= __shfl_xor(x, 1);
        x |= __shfl_xor(x, 2);
        x |= __shfl_xor(x, 4);
        if ((lane & 7) == 0)
          bm[wb + t*32 + jj*8 + (lane >> 3)] = x;
      }
      __builtin_amdgcn_sched_barrier(0);  // keep pm block out of next step's MFMA region
    }
    // no per-step barrier: each wave owns its 16 h rows
  }

  // he = relu(h) bf16, wave-local b128 stores
  #pragma unroll
  for (int s = 0; s < 2; ++s) {
    int chunk = s*64 + lane;          // 128 chunks of 8 shorts per wave
    int rl = chunk >> 3, c8 = chunk & 7;
    bf16x8 v = *(const bf16x8*)(h_s + (w16 + rl)*72 + c8*8);
    #pragma unroll
    for (int j = 0; j < 8; ++j) {
      short sv = v[j];
      v[j] = (sv & (short)0x8000) ? (short)0 : sv;   // relu (handles -0.0)
    }
    *(bf16x8*)(he + (size_t)(row0 + w16 + rl)*64 + c8*8) = v;
  }
}

// ---------------------------------------------------------------------------
// MFMA MLP v2: ZERO barriers, no weight/bias LDS.
//  - B-frags read directly from the pre-converted global wg (L2-resident
//    56 KB, hoisted 8x b128 loads before each stage's MFMAs).
//  - Bias read inline (16 consecutive floats per wave, L2-hot).
//  - LDS = Atile only (9.5 KB). Waves fully independent -> latency
//    self-hides; removes the all-blocks-stage-simultaneously L2 storm and
//    3 __syncthreads of v1.
__global__ __launch_bounds__(256) void mlp_kernel(
    const unsigned short* __restrict__ he, const unsigned short* __restrict__ wg,
    const float* __restrict__ b1, const float* __restrict__ b2,
    const float* __restrict__ bh, const float* __restrict__ bq,
    const float* __restrict__ bk, const float* __restrict__ bv,
    unsigned short* __restrict__ qb, unsigned short* __restrict__ kb,
    unsigned short* __restrict__ vt, float* __restrict__ feat)
{
  __shared__ short Atile[4][16*76];    // 9.5 KB per-wave relayout tiles

  const int tid  = threadIdx.x;
  const int lane = tid & 63;
  const int wv   = tid >> 6;
  const int quad = lane >> 4;
  const int col  = lane & 15;
  const int rowb = blockIdx.x*64 + wv*16;

  bf16x8 a0 = *(const bf16x8*)(he + (size_t)(rowb + col)*64 + quad*8);
  bf16x8 a1 = *(const bf16x8*)(he + (size_t)(rowb + col)*64 + quad*8 + 32);

  f32x4 acc[4];
  auto runL = [&](int m, const float* __restrict__ bs, float bsc) {
    bf16x8 bf[8];
    #pragma unroll
    for (int f = 0; f < 8; ++f)
      bf[f] = *(const bf16x8*)(wg + (size_t)m*4096 + f*512 + lane*8);
    #pragma unroll
    for (int nt = 0; nt < 4; ++nt) {
      float bb = bs[nt*16 + col] * bsc;
      acc[nt][0] = bb; acc[nt][1] = bb; acc[nt][2] = bb; acc[nt][3] = bb;
      acc[nt] = __builtin_amdgcn_mfma_f32_16x16x32_bf16(a0, bf[nt*2+0], acc[nt], 0,0,0);
      acc[nt] = __builtin_amdgcn_mfma_f32_16x16x32_bf16(a1, bf[nt*2+1], acc[nt], 0,0,0);
    }
  };
  auto tileWrite = [&](bool relu) {
    #pragma unroll
    for (int nt = 0; nt < 4; ++nt)
      #pragma unroll
      for (int r = 0; r < 4; ++r) {
        float v = relu ? fmaxf(acc[nt][r], 0.f) : acc[nt][r];
        Atile[wv][(quad*4+r)*76 + ((nt*16+col) ^ (r*16))] = (short)f2bf(v);
      }
  };
  auto tileReadA = [&]() {
    int sw = (col & 3) * 16;
    a0 = *(const bf16x8*)(&Atile[wv][col*76 + ((quad*8     ) ^ sw)]);
    a1 = *(const bf16x8*)(&Atile[wv][col*76 + ((quad*8 + 32) ^ sw)]);
  };
  auto storeBF = [&](unsigned short* dst) {
    #pragma unroll
    for (int s = 0; s < 2; ++s) {
      int chunk = s*64 + lane;
      int r = chunk >> 3, c8 = chunk & 7;
      bf16x8 v = *(const bf16x8*)(&Atile[wv][r*76 + ((c8*8) ^ ((r&3)*16))]);
      *(bf16x8*)(dst + (size_t)(rowb + r)*64 + c8*8) = v;
    }
  };

  runL(0, b1, 1.f);  tileWrite(true);  tileReadA();
  runL(1, b2, 1.f);  tileWrite(true);  tileReadA();
  runL(2, bh, 1.f);  tileWrite(true);  tileReadA();   // a0/a1 = hidden A-frags
  runL(3, bq, L2E);  tileWrite(false); storeBF(qb);   // q (bf16, L2E-scaled)
  runL(4, bk, 1.f);  tileWrite(false); storeBF(kb);   // k (bf16)
  runL(5, bv, 1.f);                                   // v
  {
    const int bi   = rowb >> 9;                  // batch
    const int key0 = (rowb & 511) + quad*4;
    #pragma unroll
    for (int nt = 0; nt < 4; ++nt) {
      #pragma unroll
      for (int r = 0; r < 4; ++r)
        feat[(size_t)(rowb + quad*4 + r)*128 + nt*16 + col] = acc[nt][r];
      uint32_t lo = (uint32_t)f2bf(acc[nt][0]) | ((uint32_t)f2bf(acc[nt][1]) << 16);
      uint32_t hi = (uint32_t)f2bf(acc[nt][2]) | ((uint32_t)f2bf(acc[nt][3]) << 16);
      uint2 pk; pk.x = lo; pk.y = hi;
      *(uint2*)(vt + ((size_t)bi*64 + nt*16 + col)*512 + key0) = pk;
    }
  }
}

// ---------------------------------------------------------------------------
// MFMA attention v4 = v3 with Wf staging dropped (frags from wg, bias direct).
// LDS 52.4 -> 43 KB; fused forecast epilogue unchanged otherwise.
__global__ __launch_bounds__(256) void attn_kernel(
    const unsigned short* __restrict__ qg, const unsigned short* __restrict__ kg,
    const unsigned short* __restrict__ vt,
    const uint32_t* __restrict__ bm, float* __restrict__ feat,
    const unsigned short* __restrict__ wg, const float* __restrict__ bfv,
    float* __restrict__ out)
{
  __shared__ short    Ks[128*72];      // 18.0 KB (reused as o-tile in epilogue)
  __shared__ short    Vt[64*136];      // 17.0 KB
  __shared__ short    Pl[4][16*32];    // 4 KB, per-wave
  __shared__ uint32_t Ms[4][256];      // 4 KB, per-wave mask words

  const int tid  = threadIdx.x;
  const int lane = tid & 63;
  const int wv   = tid >> 6;
  const int w16  = wv * 16;
  const int quad = lane >> 4;
  const int col  = lane & 15;

  const int b     = blockIdx.x >> 3;
  const int q0    = (blockIdx.x & 7) * 64;
  const int qbase = b*512 + q0 + wv*16;

  bf16x8 qa[2];
  qa[0] = *(const bf16x8*)(qg + (size_t)(qbase + col)*64 + quad*8);
  qa[1] = *(const bf16x8*)(qg + (size_t)(qbase + col)*64 + quad*8 + 32);

  #pragma unroll
  for (int w = 0; w < 4; ++w)
    Ms[wv][w*64 + lane] = bm[(size_t)qbase*16 + w*64 + lane];

  f32x4 o_acc[4];
  #pragma unroll
  for (int nt = 0; nt < 4; ++nt)
    #pragma unroll
    for (int r = 0; r < 4; ++r) o_acc[nt][r] = 0.f;
  float l_part[4] = {0.f, 0.f, 0.f, 0.f};

  const unsigned short* vtb = vt + (size_t)b*64*512;

  for (int c = 0; c < 4; ++c) {
    __syncthreads();
    {
      const int kb_ = b*512 + c*128;
      // K chunk: bf16 [key][dim] stride 72
      #pragma unroll
      for (int i = 0; i < 4; ++i) {
        int p = i*256 + tid;
        int key = p >> 3, c8 = p & 7;
        bf16x8 kv = *(const bf16x8*)(kg + (size_t)(kb_ + key)*64 + c8*8);
        *(bf16x8*)(Ks + key*72 + c8*8) = kv;
      }
      // V^T chunk: bf16 [dim][key] stride 136 — pure copies
      #pragma unroll
      for (int i = 0; i < 4; ++i) {
        int p = i*256 + tid;
        int dim = p >> 4, k8 = p & 15;
        bf16x8 vv = *(const bf16x8*)(vtb + (size_t)dim*512 + c*128 + k8*8);
        *(bf16x8*)(Vt + dim*136 + k8*8) = vv;
      }
    }
    __syncthreads();

    for (int kc = 0; kc < 4; ++kc) {
      #pragma unroll
      for (int t = 0; t < 2; ++t) {
        const int kt = kc*2 + t;
        f32x4 s_acc;
        #pragma unroll
        for (int r = 0; r < 4; ++r) s_acc[r] = 0.f;
        const short* kp = Ks + (kt*16 + col)*72 + quad*8;
        bf16x8 kb0 = *(const bf16x8*)(kp);
        bf16x8 kb1 = *(const bf16x8*)(kp + 32);
        s_acc = __builtin_amdgcn_mfma_f32_16x16x32_bf16(qa[0], kb0, s_acc, 0,0,0);
        s_acc = __builtin_amdgcn_mfma_f32_16x16x32_bf16(qa[1], kb1, s_acc, 0,0,0);
        const int kcol = ((t*16 + col) ^ (quad*8));
        #pragma unroll
        for (int r = 0; r < 4; ++r) {
          uint32_t mw = Ms[wv][(quad*4+r)*16 + c*4 + (kt>>1)];
          float p = ((mw >> ((kt&1)*16 + col)) & 1u)
                      ? exp2f_(fminf(s_acc[r], 43.f)) : 0.f;   // s pre-scaled
          l_part[r] += p;
          Pl[wv][(quad*4+r)*32 + kcol] = (short)f2bf(p);
        }
      }
      bf16x8 pa = *(const bf16x8*)(&Pl[wv][col*32 + ((quad*8) ^ (((col)>>2)*8))]);
      #pragma unroll
      for (int nt = 0; nt < 4; ++nt) {
        bf16x8 vb = *(const bf16x8*)(&Vt[(nt*16+col)*136 + kc*32 + quad*8]);
        o_acc[nt] = __builtin_amdgcn_mfma_f32_16x16x32_bf16(pa, vb, o_acc[nt], 0,0,0);
      }
    }
  }

  float inv[4];
  #pragma unroll
  for (int r = 0; r < 4; ++r) {
    float v = l_part[r];
    v += __shfl_xor(v, 1);
    v += __shfl_xor(v, 2);
    v += __shfl_xor(v, 4);
    v += __shfl_xor(v, 8);
    inv[r] = rcpf_(fmaxf(v, 1e-20f));
  }

  // feat attn-half write (required output)
  #pragma unroll
  for (int nt = 0; nt < 4; ++nt)
    #pragma unroll
    for (int r = 0; r < 4; ++r)
      feat[(size_t)(qbase + quad*4 + r)*128 + 64 + nt*16 + col] = o_acc[nt][r]*inv[r];

  // ---- fused forecast ----
  __syncthreads();   // all waves done reading Ks/Vt before Ks reuse

  // transpose o*inv (C-layout) into wave-private Ks slice (A-layout source)
  #pragma unroll
  for (int nt = 0; nt < 4; ++nt)
    #pragma unroll
    for (int r = 0; r < 4; ++r)
      Ks[(w16 + quad*4 + r)*72 + nt*16 + col] = (short)f2bf(o_acc[nt][r]*inv[r]);

  // A-frags: kc 0..1 from feat v-half (fp32, written by mlp); kc 2..3 from Ks
  bf16x8 af[4];
  const float* fr = feat + (size_t)(qbase + col)*128;
  #pragma unroll
  for (int kc = 0; kc < 2; ++kc) {
    float4 f0 = *(const float4*)(fr + kc*32 + quad*8);
    float4 f1 = *(const float4*)(fr + kc*32 + quad*8 + 4);
    af[kc][0]=(short)f2bf(f0.x); af[kc][1]=(short)f2bf(f0.y);
    af[kc][2]=(short)f2bf(f0.z); af[kc][3]=(short)f2bf(f0.w);
    af[kc][4]=(short)f2bf(f1.x); af[kc][5]=(short)f2bf(f1.y);
    af[kc][6]=(short)f2bf(f1.z); af[kc][7]=(short)f2bf(f1.w);
  }
  #pragma unroll
  for (int kc = 2; kc < 4; ++kc)
    af[kc] = *(const bf16x8*)(Ks + (w16 + col)*72 + (kc-2)*32 + quad*8);

  f32x4 facc[2];
  #pragma unroll
  for (int nt = 0; nt < 2; ++nt) {
    int n = nt*16 + col;
    float bb = (n < 24) ? bfv[n] : 0.f;
    facc[nt][0] = bb; facc[nt][1] = bb; facc[nt][2] = bb; facc[nt][3] = bb;
  }
  #pragma unroll
  for (int kc = 0; kc < 4; ++kc) {
    #pragma unroll
    for (int nt = 0; nt < 2; ++nt) {
      bf16x8 bfr = *(const bf16x8*)(wg + (size_t)6*4096 + (kc*2+nt)*512 + lane*8);
      facc[nt] = __builtin_amdgcn_mfma_f32_16x16x32_bf16(af[kc], bfr, facc[nt], 0,0,0);
    }
  }

  #pragma unroll
  for (int nt = 0; nt < 2; ++nt) {
    int n = nt*16 + col;
    if (n < 24) {
      #pragma unroll
      for (int r = 0; r < 4; ++r)
        out[(size_t)(qbase + quad*4 + r)*24 + n] = facc[nt][r];
    }
  }
}

// ---------------------------------------------------------------------------
extern "C" void kernel_launch(void* const* d_in, const int* in_sizes, int n_in,
                              void* d_out, int out_size, void* d_ws, size_t ws_size,
                              hipStream_t stream)
{
  const float* obs = (const float*)d_in[0];
  const int*   pm  = (const int*)  d_in[1];
  const float* nhm = (const float*)d_in[2];
  const float* Wih = (const float*)d_in[3];
  const float* Whh = (const float*)d_in[4];
  const float* bih = (const float*)d_in[5];
  const float* bhh = (const float*)d_in[6];
  const float* W1  = (const float*)d_in[7];
  const float* b1  = (const float*)d_in[8];
  const float* W2  = (const float*)d_in[9];
  const float* b2  = (const float*)d_in[10];
  const float* Wh  = (const float*)d_in[11];
  const float* bh  = (const float*)d_in[12];
  const float* Wq  = (const float*)d_in[13];
  const float* bq  = (const float*)d_in[14];
  const float* Wk  = (const float*)d_in[15];
  const float* bk  = (const float*)d_in[16];
  const float* Wv  = (const float*)d_in[17];
  const float* bv  = (const float*)d_in[18];
  const float* Wf  = (const float*)d_in[19];
  const float* bf  = (const float*)d_in[20];

  float* out  = (float*)d_out;                 // forecast: 65536*24
  float* feat = out + (size_t)M_*24;           // feat:     65536*128

  // workspace: he(8MB) | qb(8MB) | kb(8MB) | vt(8MB) | bitmask(4MB) | wg(56KB)
  char* ws = (char*)d_ws;
  unsigned short* he  = (unsigned short*)(ws);
  unsigned short* qbf = (unsigned short*)(ws + (size_t) 8*1024*1024);
  unsigned short* kbf = (unsigned short*)(ws + (size_t)16*1024*1024);
  unsigned short* vtb = (unsigned short*)(ws + (size_t)24*1024*1024);
  uint32_t*       bmw = (uint32_t*)      (ws + (size_t)32*1024*1024);
  unsigned short* wgb = (unsigned short*)(ws + (size_t)36*1024*1024);

  lstm_kernel<<<M_/128, 512, 0, stream>>>(obs, nhm, Wih, Whh, bih, bhh, he,
                                          (const int4*)pm, bmw,
                                          W1, W2, Wh, Wq, Wk, Wv, Wf, wgb);
  mlp_kernel<<<M_/64, 256, 0, stream>>>(he, wgb, b1, b2, bh, bq, bk, bv,
                                        qbf, kbf, vtb, feat);
  attn_kernel<<<M_/64, 256, 0, stream>>>(qbf, kbf, vtb, bmw, feat, wgb, bf, out);
}

// Round 10
// 297.318 us; speedup vs baseline: 1.2054x; 1.0188x over previous
//
#include <hip/hip_runtime.h>
#include <hip/hip_bf16.h>
#include <stdint.h>

#define B_ 128
#define N_ 512
#define S_ 8
#define H_ 64
#define M_ (B_*N_)          // 65536 rows
#define L2E 1.442695041f

typedef __attribute__((ext_vector_type(8))) short bf16x8;
typedef __attribute__((ext_vector_type(4))) float f32x4;

__device__ __forceinline__ float exp2f_(float x) { return __builtin_amdgcn_exp2f(x); }
__device__ __forceinline__ float rcpf_(float x)  { return __builtin_amdgcn_rcpf(x); }
// x pre-scaled by log2(e):  sig2(x) == sigmoid(x / L2E)   (v_exp + v_rcp only)
__device__ __forceinline__ float sig2(float x)  { return rcpf_(1.f + exp2f_(-x)); }
// x pre-scaled by 2*log2(e): tanh2(x) == tanh(x / (2*L2E))
__device__ __forceinline__ float tanh2(float x) { return 1.f - 2.f*rcpf_(exp2f_(x) + 1.f); }
// fp32 -> bf16 round-to-nearest-even
__device__ __forceinline__ unsigned short f2bf(float x) {
  unsigned int u = __float_as_uint(x);
  u += 0x7fffu + ((u >> 16) & 1u);
  return (unsigned short)(u >> 16);
}

// ---------------------------------------------------------------------------
// One-shot weight frag conversion (was inside lstm v10; hoisted so wg is
// stream-visible to the FUSED lstm+mlp kernel). 7 blocks x 512 threads,
// block m converts matrix m of {W1,W2,Wh,Wq,Wk,Wv,Wf} to bf16 B-frags.
// Wq pre-scaled by log2(e); Wf zero-padded to 32 cols. ~3 us.
__global__ __launch_bounds__(512) void wconv_kernel(
    const float* __restrict__ W1, const float* __restrict__ W2,
    const float* __restrict__ Wh, const float* __restrict__ Wq,
    const float* __restrict__ Wk, const float* __restrict__ Wv,
    const float* __restrict__ Wf, unsigned short* __restrict__ wg)
{
  const int m = blockIdx.x;
  const int p = threadIdx.x;
  const int f = p >> 6, l = p & 63;
  const int lq = l >> 4, lc = l & 15;
  bf16x8 v;
  #pragma unroll
  for (int j = 0; j < 8; ++j) v[j] = 0;
  if (m < 6) {
    const float* mats[6] = {W1, W2, Wh, Wq, Wk, Wv};
    const float sc = (m == 3) ? L2E : 1.f;       // Wq pre-scaled by log2(e)
    const int nt = f >> 1, s = f & 1;
    const float* src = mats[m] + (size_t)(nt*16 + lc)*64 + s*32 + lq*8;
    #pragma unroll
    for (int j = 0; j < 8; ++j) v[j] = (short)f2bf(src[j] * sc);
  } else {
    const int kc = f >> 1, nt = f & 1;
    const int n = nt*16 + lc;
    if (n < 24) {
      const float* src = Wf + (size_t)n*128 + kc*32 + lq*8;
      #pragma unroll
      for (int j = 0; j < 8; ++j) v[j] = (short)f2bf(src[j]);
    }
  }
  *(bf16x8*)(wg + (size_t)m*4096 + f*512 + l*8) = v;
}

// ---------------------------------------------------------------------------
// FUSED LSTM+MLP v11 = lstm v9 core + mlp v2 as a per-wave epilogue.
//  - t-loop unchanged: async-split pm pack, x/len in registers, h bf16 in
//    h_s (per-wave 16-row slice, stride 72), single barrier.
//  - Epilogue (NO barrier needed): each wave loads its OWN h rows from its
//    h_s slice applying the bf16 sign-mask relu (bit-identical to the old
//    he store/load), then runs the 6-stage MLP chain with B-frags from wg
//    (L2-resident) and bias inline. Atile relayout REUSES the wave's h_s
//    slice (stride 72; XOR swizzle domain [0,64) fits; per-wave in-order
//    read-before-write). he global buffer eliminated (-16MB traffic,
//    -1 launch; mlp work hides in lstm wave-completion skew).
__global__ __launch_bounds__(512, 4) void lstm_kernel(
    const float* __restrict__ obs, const float* __restrict__ nhm,
    const float* __restrict__ Wih, const float* __restrict__ Whh,
    const float* __restrict__ bih, const float* __restrict__ bhh,
    const int4* __restrict__ pm4, uint32_t* __restrict__ bm,
    const unsigned short* __restrict__ wg,
    const float* __restrict__ b1, const float* __restrict__ b2,
    const float* __restrict__ bh, const float* __restrict__ bq,
    const float* __restrict__ bk, const float* __restrict__ bv,
    unsigned short* __restrict__ qb, unsigned short* __restrict__ kb,
    unsigned short* __restrict__ vt, float* __restrict__ feat)
{
  __shared__ short    Wfrag[32*512];   // 32 KB  Whh B-frags (bf16, gate-scaled)
  __shared__ short    Wxc[1024];       // 2 KB   compact [Wih0,Wih1,bias,0] per n
  __shared__ short    h_s[128*72];     // 18 KB  bf16, stride 72 (reused as Atile)

  const int tid  = threadIdx.x;
  const int lane = tid & 63;
  const int wv   = tid >> 6;           // 0..7
  const int w16  = wv * 16;
  const int quad = lane >> 4;
  const int col  = lane & 15;
  const int row0 = blockIdx.x * 128;

  // pm strip for this wave: 256 words = 2048 int4
  const int     wb  = (blockIdx.x*8 + wv) * 256;       // word base
  const int4*   pw  = pm4 + (size_t)wb * 8;            // int4 base
  const int     shp = (lane & 7) * 4;                  // nibble shift

  // ---- stage Whh as bf16 B-fragments (gate-scaled), 2048 (frag,lane) entries
  #pragma unroll
  for (int i = 0; i < 4; ++i) {
    int p = i*512 + tid;
    int f = p >> 6, l = p & 63;
    int t16 = f >> 1, s = f & 1;
    int lq = l >> 4, lc = l & 15;
    const float sc = (t16 >= 8 && t16 < 12) ? (2.f*L2E) : L2E;
    const float* src = Whh + (size_t)(t16*16 + lc)*64 + s*32 + lq*8;
    short* dst = Wfrag + f*512 + l*8;
    #pragma unroll
    for (int j = 0; j < 8; ++j) dst[j] = (short)f2bf(src[j] * sc);
  }
  // ---- stage compact Wx: Wxc[t16*64 + cc*4 + k], k: 0=Wih0 1=Wih1 2=bias ----
  if (tid < 256) {
    int t16 = tid >> 4, cc = tid & 15;
    int n = t16*16 + cc;
    const float sc = (t16 >= 8 && t16 < 12) ? (2.f*L2E) : L2E;
    short* d = Wxc + t16*64 + cc*4;
    d[0] = (short)f2bf(Wih[2*n + 0] * sc);
    d[1] = (short)f2bf(Wih[2*n + 1] * sc);
    d[2] = (short)f2bf((bih[n] + bhh[n]) * sc);
    d[3] = 0;
  }

  // zero h_s (4608 dwords)
  #pragma unroll
  for (int i = 0; i < 9; ++i) ((uint32_t*)h_s)[i*512 + tid] = 0u;

  // ---- per-lane x prep for row (w16+col); all quads redundant, so each
  //      consumer lane already holds its own value. Registers, no LDS.
  uint32_t xq0, xq1, xq2, xq3, xq4, xq5, xq6, xq7;
  int len;
  {
    const int grow = row0 + w16 + col;
    float xv0[8], xv1[8];
    int lzi = -1;
    #pragma unroll
    for (int t = 0; t < 8; ++t) {
      float m = nhm[(size_t)grow*8 + t];
      float a = obs[((size_t)grow*8 + t)*2 + 0] * m;
      float b = obs[((size_t)grow*8 + t)*2 + 1] * m;
      xv0[t] = a; xv1[t] = b;
      if (a == 0.f) lzi = t;
    }
    uint32_t xr[8];
    #pragma unroll
    for (int t = 0; t < 8; ++t) {
      bool kill = (t < lzi);
      float a = kill ? 0.f : xv0[t];
      float b = kill ? 0.f : xv1[t];
      xr[t] = (uint32_t)f2bf(a) | ((uint32_t)f2bf(b) << 16);
    }
    xq0 = xr[0]; xq1 = xr[1]; xq2 = xr[2]; xq3 = xr[3];
    xq4 = xr[4]; xq5 = xr[5]; xq6 = xr[6]; xq7 = xr[7];
    len = 7 - lzi; if (len < 1) len = 1;
  }
  int lenr[4];
  #pragma unroll
  for (int r = 0; r < 4; ++r) lenr[r] = __shfl(len, quad*4 + r);

  __syncthreads();     // the ONLY barrier (covers Wfrag, Wxc, h_s zero)

  float c_[16];
  #pragma unroll
  for (int i = 0; i < 16; ++i) c_[i] = 0.f;

  const f32x4 zero4 = {0.f, 0.f, 0.f, 0.f};
  const bool q0 = (quad == 0);

  #pragma unroll 1
  for (int t = 0; t < 8; ++t) {
    // ---- ISSUE pm loads for this step early (consumed after cc-loop) ----
    const int4* ps = pw + t*256 + lane;
    int4 pv0 = ps[0];
    int4 pv1 = ps[64];
    int4 pv2 = ps[128];
    int4 pv3 = ps[192];
    __builtin_amdgcn_sched_barrier(0);   // loads stay issued before MFMA region

    // ---- A-frag for the x/bias MFMA: [x0, x1, 1, 0...] on quad 0 ----
    uint32_t xw = xq0;
    // rotate queue (static indices; stays in registers)
    xq0 = xq1; xq1 = xq2; xq2 = xq3; xq3 = xq4;
    xq4 = xq5; xq5 = xq6; xq6 = xq7;

    union { bf16x8 v; uint32_t u[4]; } ax;
    ax.u[0] = q0 ? xw : 0u;
    ax.u[1] = q0 ? 0x00003f80u : 0u;    // bf16(1.0) at k==2
    ax.u[2] = 0u; ax.u[3] = 0u;

    // A-frags of h (bf16, no converts)
    bf16x8 a0 = *(const bf16x8*)(h_s + (w16 + col)*72 + quad*8);
    bf16x8 a1 = *(const bf16x8*)(h_s + (w16 + col)*72 + 32 + quad*8);

    // 4 column-groups: tiles {cc, cc+4, cc+8, cc+12} = i,f,g,o for cells
    // n = cc*16+col. Only 4 accumulators live at a time.
    #pragma unroll
    for (int cc = 0; cc < 4; ++cc) {
      f32x4 acc[4];
      #pragma unroll
      for (int g = 0; g < 4; ++g) {
        const int t16 = g*4 + cc;
        union { bf16x8 v; uint32_t u[4]; } wx;
        uint2 d = *(const uint2*)(Wxc + t16*64 + col*4);  // always initialized
        wx.u[0] = q0 ? d.x : 0u;        // zero fragment on non-quad0 lanes
        wx.u[1] = q0 ? d.y : 0u;
        wx.u[2] = 0u; wx.u[3] = 0u;
        bf16x8 b0 = *(const bf16x8*)(Wfrag + (t16*2+0)*512 + lane*8);
        bf16x8 b1 = *(const bf16x8*)(Wfrag + (t16*2+1)*512 + lane*8);
        acc[g] = __builtin_amdgcn_mfma_f32_16x16x32_bf16(ax.v, wx.v, zero4, 0, 0, 0);
        acc[g] = __builtin_amdgcn_mfma_f32_16x16x32_bf16(a0, b0, acc[g], 0, 0, 0);
        acc[g] = __builtin_amdgcn_mfma_f32_16x16x32_bf16(a1, b1, acc[g], 0, 0, 0);
      }
      #pragma unroll
      for (int r = 0; r < 4; ++r) {
        if (t < lenr[r]) {
          float gi = acc[0][r];
          float gf = acc[1][r];
          float gg = acc[2][r];
          float go = acc[3][r];
          float cn = sig2(gf)*c_[cc*4+r] + sig2(gi)*tanh2(gg);
          c_[cc*4+r] = cn;
          h_s[(w16 + quad*4 + r)*72 + cc*16 + col] =
              (short)f2bf(sig2(go)*tanh2(cn*(2.f*L2E)));
        }
      }
      __builtin_amdgcn_sched_barrier(0);  // pin group: keep acc lifetime short
    }

    // ---- CONSUME pm loads (latency hidden under the cc-loop above) ----
    {
      int4 vv[4] = {pv0, pv1, pv2, pv3};
      #pragma unroll
      for (int jj = 0; jj < 4; ++jj) {
        int4 v = vv[jj];
        uint32_t nib = (v.x != 0 ? 1u : 0u)
                     | (v.y != 0 ? 2u : 0u)
                     | (v.z != 0 ? 4u : 0u)
                     | (v.w != 0 ? 8u : 0u);
        uint32_t x = nib << shp;
        x |= __shfl_xor(x, 1);
        x |= __shfl_xor(x, 2);
        x |= __shfl_xor(x, 4);
        if ((lane & 7) == 0)
          bm[wb + t*32 + jj*8 + (lane >> 3)] = x;
      }
      __builtin_amdgcn_sched_barrier(0);  // keep pm block out of next step's MFMA region
    }
    // no per-step barrier: each wave owns its 16 h rows
  }

  // ======================= fused MLP epilogue (per-wave) ====================
  // A-frags = relu(h) of this wave's own rows (same bits as old he path).
  short* At = h_s + w16*72;            // this wave's 16-row slice, stride 72
  const int grow16 = row0 + w16;       // row base for this wave

  auto reluv = [](bf16x8 v) {
    #pragma unroll
    for (int j = 0; j < 8; ++j) {
      short sv = v[j];
      v[j] = (sv & (short)0x8000) ? (short)0 : sv;
    }
    return v;
  };

  bf16x8 a0 = reluv(*(const bf16x8*)(At + col*72 + quad*8));
  bf16x8 a1 = reluv(*(const bf16x8*)(At + col*72 + 32 + quad*8));

  f32x4 acc[4];
  auto runL = [&](int m, const float* __restrict__ bs, float bsc) {
    bf16x8 bf[8];
    #pragma unroll
    for (int f = 0; f < 8; ++f)
      bf[f] = *(const bf16x8*)(wg + (size_t)m*4096 + f*512 + lane*8);
    #pragma unroll
    for (int nt = 0; nt < 4; ++nt) {
      float bb = bs[nt*16 + col] * bsc;
      acc[nt][0] = bb; acc[nt][1] = bb; acc[nt][2] = bb; acc[nt][3] = bb;
      acc[nt] = __builtin_amdgcn_mfma_f32_16x16x32_bf16(a0, bf[nt*2+0], acc[nt], 0,0,0);
      acc[nt] = __builtin_amdgcn_mfma_f32_16x16x32_bf16(a1, bf[nt*2+1], acc[nt], 0,0,0);
    }
  };
  auto tileWrite = [&](bool relu) {
    #pragma unroll
    for (int nt = 0; nt < 4; ++nt)
      #pragma unroll
      for (int r = 0; r < 4; ++r) {
        float v = relu ? fmaxf(acc[nt][r], 0.f) : acc[nt][r];
        At[(quad*4+r)*72 + ((nt*16+col) ^ (r*16))] = (short)f2bf(v);
      }
  };
  auto tileReadA = [&]() {
    int sw = (col & 3) * 16;
    a0 = *(const bf16x8*)(At + col*72 + ((quad*8     ) ^ sw));
    a1 = *(const bf16x8*)(At + col*72 + ((quad*8 + 32) ^ sw));
  };
  auto storeBF = [&](unsigned short* dst) {
    #pragma unroll
    for (int s = 0; s < 2; ++s) {
      int chunk = s*64 + lane;
      int r = chunk >> 3, c8 = chunk & 7;
      bf16x8 v = *(const bf16x8*)(At + r*72 + ((c8*8) ^ ((r&3)*16)));
      *(bf16x8*)(dst + (size_t)(grow16 + r)*64 + c8*8) = v;
    }
  };

  runL(0, b1, 1.f);  tileWrite(true);  tileReadA();
  runL(1, b2, 1.f);  tileWrite(true);  tileReadA();
  runL(2, bh, 1.f);  tileWrite(true);  tileReadA();   // a0/a1 = hidden A-frags
  runL(3, bq, L2E);  tileWrite(false); storeBF(qb);   // q (bf16, L2E-scaled)
  runL(4, bk, 1.f);  tileWrite(false); storeBF(kb);   // k (bf16)
  runL(5, bv, 1.f);                                   // v
  {
    const int bi   = grow16 >> 9;                // batch
    const int key0 = (grow16 & 511) + quad*4;
    #pragma unroll
    for (int nt = 0; nt < 4; ++nt) {
      #pragma unroll
      for (int r = 0; r < 4; ++r)
        feat[(size_t)(grow16 + quad*4 + r)*128 + nt*16 + col] = acc[nt][r];
      uint32_t lo = (uint32_t)f2bf(acc[nt][0]) | ((uint32_t)f2bf(acc[nt][1]) << 16);
      uint32_t hi = (uint32_t)f2bf(acc[nt][2]) | ((uint32_t)f2bf(acc[nt][3]) << 16);
      uint2 pk; pk.x = lo; pk.y = hi;
      *(uint2*)(vt + ((size_t)bi*64 + nt*16 + col)*512 + key0) = pk;
    }
  }
}

// ---------------------------------------------------------------------------
// MFMA attention v4 (unchanged): fused forecast epilogue, Wf frags from wg.
__global__ __launch_bounds__(256) void attn_kernel(
    const unsigned short* __restrict__ qg, const unsigned short* __restrict__ kg,
    const unsigned short* __restrict__ vt,
    const uint32_t* __restrict__ bm, float* __restrict__ feat,
    const unsigned short* __restrict__ wg, const float* __restrict__ bfv,
    float* __restrict__ out)
{
  __shared__ short    Ks[128*72];      // 18.0 KB (reused as o-tile in epilogue)
  __shared__ short    Vt[64*136];      // 17.0 KB
  __shared__ short    Pl[4][16*32];    // 4 KB, per-wave
  __shared__ uint32_t Ms[4][256];      // 4 KB, per-wave mask words

  const int tid  = threadIdx.x;
  const int lane = tid & 63;
  const int wv   = tid >> 6;
  const int w16  = wv * 16;
  const int quad = lane >> 4;
  const int col  = lane & 15;

  const int b     = blockIdx.x >> 3;
  const int q0    = (blockIdx.x & 7) * 64;
  const int qbase = b*512 + q0 + wv*16;

  bf16x8 qa[2];
  qa[0] = *(const bf16x8*)(qg + (size_t)(qbase + col)*64 + quad*8);
  qa[1] = *(const bf16x8*)(qg + (size_t)(qbase + col)*64 + quad*8 + 32);

  #pragma unroll
  for (int w = 0; w < 4; ++w)
    Ms[wv][w*64 + lane] = bm[(size_t)qbase*16 + w*64 + lane];

  f32x4 o_acc[4];
  #pragma unroll
  for (int nt = 0; nt < 4; ++nt)
    #pragma unroll
    for (int r = 0; r < 4; ++r) o_acc[nt][r] = 0.f;
  float l_part[4] = {0.f, 0.f, 0.f, 0.f};

  const unsigned short* vtb = vt + (size_t)b*64*512;

  for (int c = 0; c < 4; ++c) {
    __syncthreads();
    {
      const int kb_ = b*512 + c*128;
      // K chunk: bf16 [key][dim] stride 72
      #pragma unroll
      for (int i = 0; i < 4; ++i) {
        int p = i*256 + tid;
        int key = p >> 3, c8 = p & 7;
        bf16x8 kv = *(const bf16x8*)(kg + (size_t)(kb_ + key)*64 + c8*8);
        *(bf16x8*)(Ks + key*72 + c8*8) = kv;
      }
      // V^T chunk: bf16 [dim][key] stride 136 — pure copies
      #pragma unroll
      for (int i = 0; i < 4; ++i) {
        int p = i*256 + tid;
        int dim = p >> 4, k8 = p & 15;
        bf16x8 vv = *(const bf16x8*)(vtb + (size_t)dim*512 + c*128 + k8*8);
        *(bf16x8*)(Vt + dim*136 + k8*8) = vv;
      }
    }
    __syncthreads();

    for (int kc = 0; kc < 4; ++kc) {
      #pragma unroll
      for (int t = 0; t < 2; ++t) {
        const int kt = kc*2 + t;
        f32x4 s_acc;
        #pragma unroll
        for (int r = 0; r < 4; ++r) s_acc[r] = 0.f;
        const short* kp = Ks + (kt*16 + col)*72 + quad*8;
        bf16x8 kb0 = *(const bf16x8*)(kp);
        bf16x8 kb1 = *(const bf16x8*)(kp + 32);
        s_acc = __builtin_amdgcn_mfma_f32_16x16x32_bf16(qa[0], kb0, s_acc, 0,0,0);
        s_acc = __builtin_amdgcn_mfma_f32_16x16x32_bf16(qa[1], kb1, s_acc, 0,0,0);
        const int kcol = ((t*16 + col) ^ (quad*8));
        #pragma unroll
        for (int r = 0; r < 4; ++r) {
          uint32_t mw = Ms[wv][(quad*4+r)*16 + c*4 + (kt>>1)];
          float p = ((mw >> ((kt&1)*16 + col)) & 1u)
                      ? exp2f_(fminf(s_acc[r], 43.f)) : 0.f;   // s pre-scaled
          l_part[r] += p;
          Pl[wv][(quad*4+r)*32 + kcol] = (short)f2bf(p);
        }
      }
      bf16x8 pa = *(const bf16x8*)(&Pl[wv][col*32 + ((quad*8) ^ (((col)>>2)*8))]);
      #pragma unroll
      for (int nt = 0; nt < 4; ++nt) {
        bf16x8 vb = *(const bf16x8*)(&Vt[(nt*16+col)*136 + kc*32 + quad*8]);
        o_acc[nt] = __builtin_amdgcn_mfma_f32_16x16x32_bf16(pa, vb, o_acc[nt], 0,0,0);
      }
    }
  }

  float inv[4];
  #pragma unroll
  for (int r = 0; r < 4; ++r) {
    float v = l_part[r];
    v += __shfl_xor(v, 1);
    v += __shfl_xor(v, 2);
    v += __shfl_xor(v, 4);
    v += __shfl_xor(v, 8);
    inv[r] = rcpf_(fmaxf(v, 1e-20f));
  }

  // feat attn-half write (required output)
  #pragma unroll
  for (int nt = 0; nt < 4; ++nt)
    #pragma unroll
    for (int r = 0; r < 4; ++r)
      feat[(size_t)(qbase + quad*4 + r)*128 + 64 + nt*16 + col] = o_acc[nt][r]*inv[r];

  // ---- fused forecast ----
  __syncthreads();   // all waves done reading Ks/Vt before Ks reuse

  // transpose o*inv (C-layout) into wave-private Ks slice (A-layout source)
  #pragma unroll
  for (int nt = 0; nt < 4; ++nt)
    #pragma unroll
    for (int r = 0; r < 4; ++r)
      Ks[(w16 + quad*4 + r)*72 + nt*16 + col] = (short)f2bf(o_acc[nt][r]*inv[r]);

  // A-frags: kc 0..1 from feat v-half (fp32, written by lstm+mlp); kc 2..3 from Ks
  bf16x8 af[4];
  const float* fr = feat + (size_t)(qbase + col)*128;
  #pragma unroll
  for (int kc = 0; kc < 2; ++kc) {
    float4 f0 = *(const float4*)(fr + kc*32 + quad*8);
    float4 f1 = *(const float4*)(fr + kc*32 + quad*8 + 4);
    af[kc][0]=(short)f2bf(f0.x); af[kc][1]=(short)f2bf(f0.y);
    af[kc][2]=(short)f2bf(f0.z); af[kc][3]=(short)f2bf(f0.w);
    af[kc][4]=(short)f2bf(f1.x); af[kc][5]=(short)f2bf(f1.y);
    af[kc][6]=(short)f2bf(f1.z); af[kc][7]=(short)f2bf(f1.w);
  }
  #pragma unroll
  for (int kc = 2; kc < 4; ++kc)
    af[kc] = *(const bf16x8*)(Ks + (w16 + col)*72 + (kc-2)*32 + quad*8);

  f32x4 facc[2];
  #pragma unroll
  for (int nt = 0; nt < 2; ++nt) {
    int n = nt*16 + col;
    float bb = (n < 24) ? bfv[n] : 0.f;
    facc[nt][0] = bb; facc[nt][1] = bb; facc[nt][2] = bb; facc[nt][3] = bb;
  }
  #pragma unroll
  for (int kc = 0; kc < 4; ++kc) {
    #pragma unroll
    for (int nt = 0; nt < 2; ++nt) {
      bf16x8 bfr = *(const bf16x8*)(wg + (size_t)6*4096 + (kc*2+nt)*512 + lane*8);
      facc[nt] = __builtin_amdgcn_mfma_f32_16x16x32_bf16(af[kc], bfr, facc[nt], 0,0,0);
    }
  }

  #pragma unroll
  for (int nt = 0; nt < 2; ++nt) {
    int n = nt*16 + col;
    if (n < 24) {
      #pragma unroll
      for (int r = 0; r < 4; ++r)
        out[(size_t)(qbase + quad*4 + r)*24 + n] = facc[nt][r];
    }
  }
}

// ---------------------------------------------------------------------------
extern "C" void kernel_launch(void* const* d_in, const int* in_sizes, int n_in,
                              void* d_out, int out_size, void* d_ws, size_t ws_size,
                              hipStream_t stream)
{
  const float* obs = (const float*)d_in[0];
  const int*   pm  = (const int*)  d_in[1];
  const float* nhm = (const float*)d_in[2];
  const float* Wih = (const float*)d_in[3];
  const float* Whh = (const float*)d_in[4];
  const float* bih = (const float*)d_in[5];
  const float* bhh = (const float*)d_in[6];
  const float* W1  = (const float*)d_in[7];
  const float* b1  = (const float*)d_in[8];
  const float* W2  = (const float*)d_in[9];
  const float* b2  = (const float*)d_in[10];
  const float* Wh  = (const float*)d_in[11];
  const float* bh  = (const float*)d_in[12];
  const float* Wq  = (const float*)d_in[13];
  const float* bq  = (const float*)d_in[14];
  const float* Wk  = (const float*)d_in[15];
  const float* bk  = (const float*)d_in[16];
  const float* Wv  = (const float*)d_in[17];
  const float* bv  = (const float*)d_in[18];
  const float* Wf  = (const float*)d_in[19];
  const float* bf  = (const float*)d_in[20];

  float* out  = (float*)d_out;                 // forecast: 65536*24
  float* feat = out + (size_t)M_*24;           // feat:     65536*128

  // workspace: qb(8MB) | kb(8MB) | vt(8MB) | bitmask(4MB) | wg(56KB)
  char* ws = (char*)d_ws;
  unsigned short* qbf = (unsigned short*)(ws);
  unsigned short* kbf = (unsigned short*)(ws + (size_t) 8*1024*1024);
  unsigned short* vtb = (unsigned short*)(ws + (size_t)16*1024*1024);
  uint32_t*       bmw = (uint32_t*)      (ws + (size_t)24*1024*1024);
  unsigned short* wgb = (unsigned short*)(ws + (size_t)28*1024*1024);

  wconv_kernel<<<7, 512, 0, stream>>>(W1, W2, Wh, Wq, Wk, Wv, Wf, wgb);
  lstm_kernel<<<M_/128, 512, 0, stream>>>(obs, nhm, Wih, Whh, bih, bhh,
                                          (const int4*)pm, bmw, wgb,
                                          b1, b2, bh, bq, bk, bv,
                                          qbf, kbf, vtb, feat);
  attn_kernel<<<M_/64, 256, 0, stream>>>(qbf, kbf, vtb, bmw, feat, wgb, bf, out);
}

// Round 11
// 293.647 us; speedup vs baseline: 1.2205x; 1.0125x over previous
//
#include <hip/hip_runtime.h>
#include <hip/hip_bf16.h>
#include <stdint.h>

#define B_ 128
#define N_ 512
#define S_ 8
#define H_ 64
#define M_ (B_*N_)          // 65536 rows
#define L2E 1.442695041f

// wg layout (shorts): 7 matrices x 4096 | Whh frags 16384 | Wxc 1024
#define WHH_OFF 28672
#define WXC_OFF 45056

typedef __attribute__((ext_vector_type(8))) short bf16x8;
typedef __attribute__((ext_vector_type(4))) float f32x4;

__device__ __forceinline__ float exp2f_(float x) { return __builtin_amdgcn_exp2f(x); }
__device__ __forceinline__ float rcpf_(float x)  { return __builtin_amdgcn_rcpf(x); }
// x pre-scaled by log2(e):  sig2(x) == sigmoid(x / L2E)   (v_exp + v_rcp only)
__device__ __forceinline__ float sig2(float x)  { return rcpf_(1.f + exp2f_(-x)); }
// x pre-scaled by 2*log2(e): tanh2(x) == tanh(x / (2*L2E))
__device__ __forceinline__ float tanh2(float x) { return 1.f - 2.f*rcpf_(exp2f_(x) + 1.f); }
// fp32 -> bf16 round-to-nearest-even
__device__ __forceinline__ unsigned short f2bf(float x) {
  unsigned int u = __float_as_uint(x);
  u += 0x7fffu + ((u >> 16) & 1u);
  return (unsigned short)(u >> 16);
}

// ---------------------------------------------------------------------------
// One-shot weight conversion, 12 blocks x 512 threads (~4 us):
//  blocks 0..5 : {W1,W2,Wh,Wq,Wk,Wv} bf16 B-frags (Wq pre-scaled by log2(e))
//  block  6    : Wf B-frags, zero-padded to 32 cols
//  blocks 7..10: Whh gate-scaled B-frags (2048 (f,l) entries, bit-identical
//                to the math previously run per-block inside lstm)
//  block  11   : compact Wxc [Wih0,Wih1,bias,0] per n
// Removes the per-block uncoalesced convert storm from lstm's prologue.
__global__ __launch_bounds__(512) void wconv_kernel(
    const float* __restrict__ W1, const float* __restrict__ W2,
    const float* __restrict__ Wh, const float* __restrict__ Wq,
    const float* __restrict__ Wk, const float* __restrict__ Wv,
    const float* __restrict__ Wf, const float* __restrict__ Wih,
    const float* __restrict__ Whh, const float* __restrict__ bih,
    const float* __restrict__ bhh, unsigned short* __restrict__ wg)
{
  const int m = blockIdx.x;
  const int tid = threadIdx.x;
  if (m < 6) {
    const int f = tid >> 6, l = tid & 63;
    const int lq = l >> 4, lc = l & 15;
    const float* mats[6] = {W1, W2, Wh, Wq, Wk, Wv};
    const float sc = (m == 3) ? L2E : 1.f;       // Wq pre-scaled by log2(e)
    const int nt = f >> 1, s = f & 1;
    const float* src = mats[m] + (size_t)(nt*16 + lc)*64 + s*32 + lq*8;
    bf16x8 v;
    #pragma unroll
    for (int j = 0; j < 8; ++j) v[j] = (short)f2bf(src[j] * sc);
    *(bf16x8*)(wg + (size_t)m*4096 + f*512 + l*8) = v;
  } else if (m == 6) {
    const int f = tid >> 6, l = tid & 63;
    const int lq = l >> 4, lc = l & 15;
    const int kc = f >> 1, nt = f & 1;
    const int n = nt*16 + lc;
    bf16x8 v;
    #pragma unroll
    for (int j = 0; j < 8; ++j) v[j] = 0;
    if (n < 24) {
      const float* src = Wf + (size_t)n*128 + kc*32 + lq*8;
      #pragma unroll
      for (int j = 0; j < 8; ++j) v[j] = (short)f2bf(src[j]);
    }
    *(bf16x8*)(wg + (size_t)6*4096 + f*512 + l*8) = v;
  } else if (m < 11) {
    // Whh gate-scaled B-frags
    const int p = (m - 7)*512 + tid;             // 0..2047
    const int f = p >> 6, l = p & 63;
    const int t16 = f >> 1, s = f & 1;
    const int lq = l >> 4, lc = l & 15;
    const float sc = (t16 >= 8 && t16 < 12) ? (2.f*L2E) : L2E;
    const float* src = Whh + (size_t)(t16*16 + lc)*64 + s*32 + lq*8;
    bf16x8 v;
    #pragma unroll
    for (int j = 0; j < 8; ++j) v[j] = (short)f2bf(src[j] * sc);
    *(bf16x8*)(wg + WHH_OFF + (size_t)p*8) = v;
  } else {
    // compact Wx: [t16*64 + cc*4 + k], k: 0=Wih0 1=Wih1 2=bias 3=0
    if (tid < 256) {
      const int t16 = tid >> 4, cc = tid & 15;
      const int n = t16*16 + cc;
      const float sc = (t16 >= 8 && t16 < 12) ? (2.f*L2E) : L2E;
      unsigned short* d = wg + WXC_OFF + t16*64 + cc*4;
      d[0] = f2bf(Wih[2*n + 0] * sc);
      d[1] = f2bf(Wih[2*n + 1] * sc);
      d[2] = f2bf((bih[n] + bhh[n]) * sc);
      d[3] = 0;
    }
  }
}

// ---------------------------------------------------------------------------
// FUSED LSTM+MLP v12 = v11 with the prologue convert storm removed.
//  - Wfrag/Wxc now COPIED coalesced (b128) from pre-converted wg (L2-hot,
//    same 34KB for all blocks) — no scalar loads, no f2bf in the prologue.
//  - t-loop and per-wave MLP epilogue unchanged from v11.
__global__ __launch_bounds__(512, 4) void lstm_kernel(
    const float* __restrict__ obs, const float* __restrict__ nhm,
    const int4* __restrict__ pm4, uint32_t* __restrict__ bm,
    const unsigned short* __restrict__ wg,
    const float* __restrict__ b1, const float* __restrict__ b2,
    const float* __restrict__ bh, const float* __restrict__ bq,
    const float* __restrict__ bk, const float* __restrict__ bv,
    unsigned short* __restrict__ qb, unsigned short* __restrict__ kb,
    unsigned short* __restrict__ vt, float* __restrict__ feat)
{
  __shared__ short    Wfrag[32*512];   // 32 KB  Whh B-frags (bf16, gate-scaled)
  __shared__ short    Wxc[1024];       // 2 KB   compact [Wih0,Wih1,bias,0] per n
  __shared__ short    h_s[128*72];     // 18 KB  bf16, stride 72 (reused as Atile)

  const int tid  = threadIdx.x;
  const int lane = tid & 63;
  const int wv   = tid >> 6;           // 0..7
  const int w16  = wv * 16;
  const int quad = lane >> 4;
  const int col  = lane & 15;
  const int row0 = blockIdx.x * 128;

  // pm strip for this wave: 256 words = 2048 int4
  const int     wb  = (blockIdx.x*8 + wv) * 256;       // word base
  const int4*   pw  = pm4 + (size_t)wb * 8;            // int4 base
  const int     shp = (lane & 7) * 4;                  // nibble shift

  // ---- prologue: coalesced copies from pre-converted wg ----
  #pragma unroll
  for (int i = 0; i < 4; ++i) {
    int p = i*512 + tid;               // (f*64+l) entry index; dst off = p*8
    *(bf16x8*)(Wfrag + (size_t)p*8) =
        *(const bf16x8*)(wg + WHH_OFF + (size_t)p*8);
  }
  ((uint32_t*)Wxc)[tid] = ((const uint32_t*)(wg + WXC_OFF))[tid];

  // zero h_s (4608 dwords)
  #pragma unroll
  for (int i = 0; i < 9; ++i) ((uint32_t*)h_s)[i*512 + tid] = 0u;

  // ---- per-lane x prep for row (w16+col); all quads redundant, so each
  //      consumer lane already holds its own value. Registers, no LDS.
  uint32_t xq0, xq1, xq2, xq3, xq4, xq5, xq6, xq7;
  int len;
  {
    const int grow = row0 + w16 + col;
    float xv0[8], xv1[8];
    int lzi = -1;
    #pragma unroll
    for (int t = 0; t < 8; ++t) {
      float m = nhm[(size_t)grow*8 + t];
      float a = obs[((size_t)grow*8 + t)*2 + 0] * m;
      float b = obs[((size_t)grow*8 + t)*2 + 1] * m;
      xv0[t] = a; xv1[t] = b;
      if (a == 0.f) lzi = t;
    }
    uint32_t xr[8];
    #pragma unroll
    for (int t = 0; t < 8; ++t) {
      bool kill = (t < lzi);
      float a = kill ? 0.f : xv0[t];
      float b = kill ? 0.f : xv1[t];
      xr[t] = (uint32_t)f2bf(a) | ((uint32_t)f2bf(b) << 16);
    }
    xq0 = xr[0]; xq1 = xr[1]; xq2 = xr[2]; xq3 = xr[3];
    xq4 = xr[4]; xq5 = xr[5]; xq6 = xr[6]; xq7 = xr[7];
    len = 7 - lzi; if (len < 1) len = 1;
  }
  int lenr[4];
  #pragma unroll
  for (int r = 0; r < 4; ++r) lenr[r] = __shfl(len, quad*4 + r);

  __syncthreads();     // the ONLY barrier (covers Wfrag, Wxc, h_s zero)

  float c_[16];
  #pragma unroll
  for (int i = 0; i < 16; ++i) c_[i] = 0.f;

  const f32x4 zero4 = {0.f, 0.f, 0.f, 0.f};
  const bool q0 = (quad == 0);

  #pragma unroll 1
  for (int t = 0; t < 8; ++t) {
    // ---- ISSUE pm loads for this step early (consumed after cc-loop) ----
    const int4* ps = pw + t*256 + lane;
    int4 pv0 = ps[0];
    int4 pv1 = ps[64];
    int4 pv2 = ps[128];
    int4 pv3 = ps[192];
    __builtin_amdgcn_sched_barrier(0);   // loads stay issued before MFMA region

    // ---- A-frag for the x/bias MFMA: [x0, x1, 1, 0...] on quad 0 ----
    uint32_t xw = xq0;
    // rotate queue (static indices; stays in registers)
    xq0 = xq1; xq1 = xq2; xq2 = xq3; xq3 = xq4;
    xq4 = xq5; xq5 = xq6; xq6 = xq7;

    union { bf16x8 v; uint32_t u[4]; } ax;
    ax.u[0] = q0 ? xw : 0u;
    ax.u[1] = q0 ? 0x00003f80u : 0u;    // bf16(1.0) at k==2
    ax.u[2] = 0u; ax.u[3] = 0u;

    // A-frags of h (bf16, no converts)
    bf16x8 a0 = *(const bf16x8*)(h_s + (w16 + col)*72 + quad*8);
    bf16x8 a1 = *(const bf16x8*)(h_s + (w16 + col)*72 + 32 + quad*8);

    // 4 column-groups: tiles {cc, cc+4, cc+8, cc+12} = i,f,g,o for cells
    // n = cc*16+col. Only 4 accumulators live at a time.
    #pragma unroll
    for (int cc = 0; cc < 4; ++cc) {
      f32x4 acc[4];
      #pragma unroll
      for (int g = 0; g < 4; ++g) {
        const int t16 = g*4 + cc;
        union { bf16x8 v; uint32_t u[4]; } wx;
        uint2 d = *(const uint2*)(Wxc + t16*64 + col*4);  // always initialized
        wx.u[0] = q0 ? d.x : 0u;        // zero fragment on non-quad0 lanes
        wx.u[1] = q0 ? d.y : 0u;
        wx.u[2] = 0u; wx.u[3] = 0u;
        bf16x8 b0 = *(const bf16x8*)(Wfrag + (t16*2+0)*512 + lane*8);
        bf16x8 b1 = *(const bf16x8*)(Wfrag + (t16*2+1)*512 + lane*8);
        acc[g] = __builtin_amdgcn_mfma_f32_16x16x32_bf16(ax.v, wx.v, zero4, 0, 0, 0);
        acc[g] = __builtin_amdgcn_mfma_f32_16x16x32_bf16(a0, b0, acc[g], 0, 0, 0);
        acc[g] = __builtin_amdgcn_mfma_f32_16x16x32_bf16(a1, b1, acc[g], 0, 0, 0);
      }
      #pragma unroll
      for (int r = 0; r < 4; ++r) {
        if (t < lenr[r]) {
          float gi = acc[0][r];
          float gf = acc[1][r];
          float gg = acc[2][r];
          float go = acc[3][r];
          float cn = sig2(gf)*c_[cc*4+r] + sig2(gi)*tanh2(gg);
          c_[cc*4+r] = cn;
          h_s[(w16 + quad*4 + r)*72 + cc*16 + col] =
              (short)f2bf(sig2(go)*tanh2(cn*(2.f*L2E)));
        }
      }
      __builtin_amdgcn_sched_barrier(0);  // pin group: keep acc lifetime short
    }

    // ---- CONSUME pm loads (latency hidden under the cc-loop above) ----
    {
      int4 vv[4] = {pv0, pv1, pv2, pv3};
      #pragma unroll
      for (int jj = 0; jj < 4; ++jj) {
        int4 v = vv[jj];
        uint32_t nib = (v.x != 0 ? 1u : 0u)
                     | (v.y != 0 ? 2u : 0u)
                     | (v.z != 0 ? 4u : 0u)
                     | (v.w != 0 ? 8u : 0u);
        uint32_t x = nib << shp;
        x |= __shfl_xor(x, 1);
        x |= __shfl_xor(x, 2);
        x |= __shfl_xor(x, 4);
        if ((lane & 7) == 0)
          bm[wb + t*32 + jj*8 + (lane >> 3)] = x;
      }
      __builtin_amdgcn_sched_barrier(0);  // keep pm block out of next step's MFMA region
    }
    // no per-step barrier: each wave owns its 16 h rows
  }

  // ======================= fused MLP epilogue (per-wave) ====================
  // A-frags = relu(h) of this wave's own rows (same bits as old he path).
  short* At = h_s + w16*72;            // this wave's 16-row slice, stride 72
  const int grow16 = row0 + w16;       // row base for this wave

  auto reluv = [](bf16x8 v) {
    #pragma unroll
    for (int j = 0; j < 8; ++j) {
      short sv = v[j];
      v[j] = (sv & (short)0x8000) ? (short)0 : sv;
    }
    return v;
  };

  bf16x8 a0 = reluv(*(const bf16x8*)(At + col*72 + quad*8));
  bf16x8 a1 = reluv(*(const bf16x8*)(At + col*72 + 32 + quad*8));

  f32x4 acc[4];
  auto runL = [&](int m, const float* __restrict__ bs, float bsc) {
    bf16x8 bf[8];
    #pragma unroll
    for (int f = 0; f < 8; ++f)
      bf[f] = *(const bf16x8*)(wg + (size_t)m*4096 + f*512 + lane*8);
    #pragma unroll
    for (int nt = 0; nt < 4; ++nt) {
      float bb = bs[nt*16 + col] * bsc;
      acc[nt][0] = bb; acc[nt][1] = bb; acc[nt][2] = bb; acc[nt][3] = bb;
      acc[nt] = __builtin_amdgcn_mfma_f32_16x16x32_bf16(a0, bf[nt*2+0], acc[nt], 0,0,0);
      acc[nt] = __builtin_amdgcn_mfma_f32_16x16x32_bf16(a1, bf[nt*2+1], acc[nt], 0,0,0);
    }
  };
  auto tileWrite = [&](bool relu) {
    #pragma unroll
    for (int nt = 0; nt < 4; ++nt)
      #pragma unroll
      for (int r = 0; r < 4; ++r) {
        float v = relu ? fmaxf(acc[nt][r], 0.f) : acc[nt][r];
        At[(quad*4+r)*72 + ((nt*16+col) ^ (r*16))] = (short)f2bf(v);
      }
  };
  auto tileReadA = [&]() {
    int sw = (col & 3) * 16;
    a0 = *(const bf16x8*)(At + col*72 + ((quad*8     ) ^ sw));
    a1 = *(const bf16x8*)(At + col*72 + ((quad*8 + 32) ^ sw));
  };
  auto storeBF = [&](unsigned short* dst) {
    #pragma unroll
    for (int s = 0; s < 2; ++s) {
      int chunk = s*64 + lane;
      int r = chunk >> 3, c8 = chunk & 7;
      bf16x8 v = *(const bf16x8*)(At + r*72 + ((c8*8) ^ ((r&3)*16)));
      *(bf16x8*)(dst + (size_t)(grow16 + r)*64 + c8*8) = v;
    }
  };

  runL(0, b1, 1.f);  tileWrite(true);  tileReadA();
  runL(1, b2, 1.f);  tileWrite(true);  tileReadA();
  runL(2, bh, 1.f);  tileWrite(true);  tileReadA();   // a0/a1 = hidden A-frags
  runL(3, bq, L2E);  tileWrite(false); storeBF(qb);   // q (bf16, L2E-scaled)
  runL(4, bk, 1.f);  tileWrite(false); storeBF(kb);   // k (bf16)
  runL(5, bv, 1.f);                                   // v
  {
    const int bi   = grow16 >> 9;                // batch
    const int key0 = (grow16 & 511) + quad*4;
    #pragma unroll
    for (int nt = 0; nt < 4; ++nt) {
      #pragma unroll
      for (int r = 0; r < 4; ++r)
        feat[(size_t)(grow16 + quad*4 + r)*128 + nt*16 + col] = acc[nt][r];
      uint32_t lo = (uint32_t)f2bf(acc[nt][0]) | ((uint32_t)f2bf(acc[nt][1]) << 16);
      uint32_t hi = (uint32_t)f2bf(acc[nt][2]) | ((uint32_t)f2bf(acc[nt][3]) << 16);
      uint2 pk; pk.x = lo; pk.y = hi;
      *(uint2*)(vt + ((size_t)bi*64 + nt*16 + col)*512 + key0) = pk;
    }
  }
}

// ---------------------------------------------------------------------------
// MFMA attention v4 (unchanged): fused forecast epilogue, Wf frags from wg.
__global__ __launch_bounds__(256) void attn_kernel(
    const unsigned short* __restrict__ qg, const unsigned short* __restrict__ kg,
    const unsigned short* __restrict__ vt,
    const uint32_t* __restrict__ bm, float* __restrict__ feat,
    const unsigned short* __restrict__ wg, const float* __restrict__ bfv,
    float* __restrict__ out)
{
  __shared__ short    Ks[128*72];      // 18.0 KB (reused as o-tile in epilogue)
  __shared__ short    Vt[64*136];      // 17.0 KB
  __shared__ short    Pl[4][16*32];    // 4 KB, per-wave
  __shared__ uint32_t Ms[4][256];      // 4 KB, per-wave mask words

  const int tid  = threadIdx.x;
  const int lane = tid & 63;
  const int wv   = tid >> 6;
  const int w16  = wv * 16;
  const int quad = lane >> 4;
  const int col  = lane & 15;

  const int b     = blockIdx.x >> 3;
  const int q0    = (blockIdx.x & 7) * 64;
  const int qbase = b*512 + q0 + wv*16;

  bf16x8 qa[2];
  qa[0] = *(const bf16x8*)(qg + (size_t)(qbase + col)*64 + quad*8);
  qa[1] = *(const bf16x8*)(qg + (size_t)(qbase + col)*64 + quad*8 + 32);

  #pragma unroll
  for (int w = 0; w < 4; ++w)
    Ms[wv][w*64 + lane] = bm[(size_t)qbase*16 + w*64 + lane];

  f32x4 o_acc[4];
  #pragma unroll
  for (int nt = 0; nt < 4; ++nt)
    #pragma unroll
    for (int r = 0; r < 4; ++r) o_acc[nt][r] = 0.f;
  float l_part[4] = {0.f, 0.f, 0.f, 0.f};

  const unsigned short* vtb = vt + (size_t)b*64*512;

  for (int c = 0; c < 4; ++c) {
    __syncthreads();
    {
      const int kb_ = b*512 + c*128;
      // K chunk: bf16 [key][dim] stride 72
      #pragma unroll
      for (int i = 0; i < 4; ++i) {
        int p = i*256 + tid;
        int key = p >> 3, c8 = p & 7;
        bf16x8 kv = *(const bf16x8*)(kg + (size_t)(kb_ + key)*64 + c8*8);
        *(bf16x8*)(Ks + key*72 + c8*8) = kv;
      }
      // V^T chunk: bf16 [dim][key] stride 136 — pure copies
      #pragma unroll
      for (int i = 0; i < 4; ++i) {
        int p = i*256 + tid;
        int dim = p >> 4, k8 = p & 15;
        bf16x8 vv = *(const bf16x8*)(vtb + (size_t)dim*512 + c*128 + k8*8);
        *(bf16x8*)(Vt + dim*136 + k8*8) = vv;
      }
    }
    __syncthreads();

    for (int kc = 0; kc < 4; ++kc) {
      #pragma unroll
      for (int t = 0; t < 2; ++t) {
        const int kt = kc*2 + t;
        f32x4 s_acc;
        #pragma unroll
        for (int r = 0; r < 4; ++r) s_acc[r] = 0.f;
        const short* kp = Ks + (kt*16 + col)*72 + quad*8;
        bf16x8 kb0 = *(const bf16x8*)(kp);
        bf16x8 kb1 = *(const bf16x8*)(kp + 32);
        s_acc = __builtin_amdgcn_mfma_f32_16x16x32_bf16(qa[0], kb0, s_acc, 0,0,0);
        s_acc = __builtin_amdgcn_mfma_f32_16x16x32_bf16(qa[1], kb1, s_acc, 0,0,0);
        const int kcol = ((t*16 + col) ^ (quad*8));
        #pragma unroll
        for (int r = 0; r < 4; ++r) {
          uint32_t mw = Ms[wv][(quad*4+r)*16 + c*4 + (kt>>1)];
          float p = ((mw >> ((kt&1)*16 + col)) & 1u)
                      ? exp2f_(fminf(s_acc[r], 43.f)) : 0.f;   // s pre-scaled
          l_part[r] += p;
          Pl[wv][(quad*4+r)*32 + kcol] = (short)f2bf(p);
        }
      }
      bf16x8 pa = *(const bf16x8*)(&Pl[wv][col*32 + ((quad*8) ^ (((col)>>2)*8))]);
      #pragma unroll
      for (int nt = 0; nt < 4; ++nt) {
        bf16x8 vb = *(const bf16x8*)(&Vt[(nt*16+col)*136 + kc*32 + quad*8]);
        o_acc[nt] = __builtin_amdgcn_mfma_f32_16x16x32_bf16(pa, vb, o_acc[nt], 0,0,0);
      }
    }
  }

  float inv[4];
  #pragma unroll
  for (int r = 0; r < 4; ++r) {
    float v = l_part[r];
    v += __shfl_xor(v, 1);
    v += __shfl_xor(v, 2);
    v += __shfl_xor(v, 4);
    v += __shfl_xor(v, 8);
    inv[r] = rcpf_(fmaxf(v, 1e-20f));
  }

  // feat attn-half write (required output)
  #pragma unroll
  for (int nt = 0; nt < 4; ++nt)
    #pragma unroll
    for (int r = 0; r < 4; ++r)
      feat[(size_t)(qbase + quad*4 + r)*128 + 64 + nt*16 + col] = o_acc[nt][r]*inv[r];

  // ---- fused forecast ----
  __syncthreads();   // all waves done reading Ks/Vt before Ks reuse

  // transpose o*inv (C-layout) into wave-private Ks slice (A-layout source)
  #pragma unroll
  for (int nt = 0; nt < 4; ++nt)
    #pragma unroll
    for (int r = 0; r < 4; ++r)
      Ks[(w16 + quad*4 + r)*72 + nt*16 + col] = (short)f2bf(o_acc[nt][r]*inv[r]);

  // A-frags: kc 0..1 from feat v-half (fp32, written by lstm+mlp); kc 2..3 from Ks
  bf16x8 af[4];
  const float* fr = feat + (size_t)(qbase + col)*128;
  #pragma unroll
  for (int kc = 0; kc < 2; ++kc) {
    float4 f0 = *(const float4*)(fr + kc*32 + quad*8);
    float4 f1 = *(const float4*)(fr + kc*32 + quad*8 + 4);
    af[kc][0]=(short)f2bf(f0.x); af[kc][1]=(short)f2bf(f0.y);
    af[kc][2]=(short)f2bf(f0.z); af[kc][3]=(short)f2bf(f0.w);
    af[kc][4]=(short)f2bf(f1.x); af[kc][5]=(short)f2bf(f1.y);
    af[kc][6]=(short)f2bf(f1.z); af[kc][7]=(short)f2bf(f1.w);
  }
  #pragma unroll
  for (int kc = 2; kc < 4; ++kc)
    af[kc] = *(const bf16x8*)(Ks + (w16 + col)*72 + (kc-2)*32 + quad*8);

  f32x4 facc[2];
  #pragma unroll
  for (int nt = 0; nt < 2; ++nt) {
    int n = nt*16 + col;
    float bb = (n < 24) ? bfv[n] : 0.f;
    facc[nt][0] = bb; facc[nt][1] = bb; facc[nt][2] = bb; facc[nt][3] = bb;
  }
  #pragma unroll
  for (int kc = 0; kc < 4; ++kc) {
    #pragma unroll
    for (int nt = 0; nt < 2; ++nt) {
      bf16x8 bfr = *(const bf16x8*)(wg + (size_t)6*4096 + (kc*2+nt)*512 + lane*8);
      facc[nt] = __builtin_amdgcn_mfma_f32_16x16x32_bf16(af[kc], bfr, facc[nt], 0,0,0);
    }
  }

  #pragma unroll
  for (int nt = 0; nt < 2; ++nt) {
    int n = nt*16 + col;
    if (n < 24) {
      #pragma unroll
      for (int r = 0; r < 4; ++r)
        out[(size_t)(qbase + quad*4 + r)*24 + n] = facc[nt][r];
    }
  }
}

// ---------------------------------------------------------------------------
extern "C" void kernel_launch(void* const* d_in, const int* in_sizes, int n_in,
                              void* d_out, int out_size, void* d_ws, size_t ws_size,
                              hipStream_t stream)
{
  const float* obs = (const float*)d_in[0];
  const int*   pm  = (const int*)  d_in[1];
  const float* nhm = (const float*)d_in[2];
  const float* Wih = (const float*)d_in[3];
  const float* Whh = (const float*)d_in[4];
  const float* bih = (const float*)d_in[5];
  const float* bhh = (const float*)d_in[6];
  const float* W1  = (const float*)d_in[7];
  const float* b1  = (const float*)d_in[8];
  const float* W2  = (const float*)d_in[9];
  const float* b2  = (const float*)d_in[10];
  const float* Wh  = (const float*)d_in[11];
  const float* bh  = (const float*)d_in[12];
  const float* Wq  = (const float*)d_in[13];
  const float* bq  = (const float*)d_in[14];
  const float* Wk  = (const float*)d_in[15];
  const float* bk  = (const float*)d_in[16];
  const float* Wv  = (const float*)d_in[17];
  const float* bv  = (const float*)d_in[18];
  const float* Wf  = (const float*)d_in[19];
  const float* bf  = (const float*)d_in[20];

  float* out  = (float*)d_out;                 // forecast: 65536*24
  float* feat = out + (size_t)M_*24;           // feat:     65536*128

  // workspace: qb(8MB) | kb(8MB) | vt(8MB) | bitmask(4MB) | wg(92KB)
  char* ws = (char*)d_ws;
  unsigned short* qbf = (unsigned short*)(ws);
  unsigned short* kbf = (unsigned short*)(ws + (size_t) 8*1024*1024);
  unsigned short* vtb = (unsigned short*)(ws + (size_t)16*1024*1024);
  uint32_t*       bmw = (uint32_t*)      (ws + (size_t)24*1024*1024);
  unsigned short* wgb = (unsigned short*)(ws + (size_t)28*1024*1024);

  wconv_kernel<<<12, 512, 0, stream>>>(W1, W2, Wh, Wq, Wk, Wv, Wf,
                                       Wih, Whh, bih, bhh, wgb);
  lstm_kernel<<<M_/128, 512, 0, stream>>>(obs, nhm, (const int4*)pm, bmw, wgb,
                                          b1, b2, bh, bq, bk, bv,
                                          qbf, kbf, vtb, feat);
  attn_kernel<<<M_/64, 256, 0, stream>>>(qbf, kbf, vtb, bmw, feat, wgb, bf, out);
}